// Round 2
// baseline (2233.351 us; speedup 1.0000x reference)
//
#include <hip/hip_runtime.h>
#include <hip/hip_bf16.h>
#include <math.h>

typedef __hip_bfloat16 bf16;

#define T_SEQ   256
#define C_EMB   384
#define NH      6
#define HS      4
#define NB      128
#define NTOK    (NB * T_SEQ)   // 32768
#define VOC     65
#define FFDIM   1536

__device__ __forceinline__ float b2f(bf16 x) { return __bfloat162float(x); }
__device__ __forceinline__ bf16  f2b(float x) { return __float2bfloat16(x); }

// ---------------- embedding: x[token,c] = tok_emb[idx[token],c] + pos_emb[t,c]
// inputs f32, intermediate x stored bf16
__global__ void embed_kernel(const int* __restrict__ idx,
                             const float* __restrict__ tok_emb,
                             const float* __restrict__ pos_emb,
                             bf16* __restrict__ x) {
    int token = blockIdx.x;
    int c = threadIdx.x;           // 384 threads
    int t = token & (T_SEQ - 1);
    int id = idx[token];
    float v = tok_emb[id * C_EMB + c] + pos_emb[t * C_EMB + c];
    x[token * C_EMB + c] = f2b(v);
}

// ---------------- qkv: q/k/v[b,h,t,d] = sum_c x[b,t,c] * W[h,c,d]
__global__ void qkv_kernel(const bf16* __restrict__ x,
                           const float* __restrict__ Wq,
                           const float* __restrict__ Wk,
                           const float* __restrict__ Wv,
                           float* __restrict__ q, float* __restrict__ k, float* __restrict__ v) {
    __shared__ float xs[C_EMB];
    int token = blockIdx.x;
    int tid = threadIdx.x;         // 128 threads
    for (int i = tid; i < C_EMB; i += 128) xs[i] = b2f(x[token * C_EMB + i]);
    __syncthreads();
    if (tid < 72) {
        int h = tid / 12;
        int r = tid % 12;
        int sel = r >> 2;          // 0=q 1=k 2=v
        int d = r & 3;
        const float* W = (sel == 0) ? Wq : (sel == 1) ? Wk : Wv;
        const float* Wp = W + h * C_EMB * HS + d;
        float acc = 0.f;
        #pragma unroll 8
        for (int c = 0; c < C_EMB; ++c) acc += xs[c] * Wp[c * HS];
        int b = token >> 8, t = token & (T_SEQ - 1);
        int o = ((b * NH + h) * T_SEQ + t) * HS + d;
        float* dst = (sel == 0) ? q : (sel == 1) ? k : v;
        dst[o] = acc;
    }
}

// ---------------- causal softmax attention, one block per (b,h), thread = query t
// writes attnT[b, t, h*4+d]  (the transpose+reshape for free)
__global__ void attn_kernel(const float* __restrict__ q,
                            const float* __restrict__ k,
                            const float* __restrict__ v,
                            float* __restrict__ attnT) {
    int bh = blockIdx.x;
    int b = bh / NH, h = bh % NH;
    int t = threadIdx.x;           // 256 threads
    __shared__ float ks[T_SEQ][HS];
    __shared__ float vs[T_SEQ][HS];
    const float* kb = k + bh * T_SEQ * HS;
    const float* vb = v + bh * T_SEQ * HS;
    #pragma unroll
    for (int d = 0; d < HS; ++d) { ks[t][d] = kb[t * HS + d]; vs[t][d] = vb[t * HS + d]; }
    __syncthreads();
    const float* qb = q + bh * T_SEQ * HS + t * HS;
    float q0 = qb[0], q1 = qb[1], q2 = qb[2], q3 = qb[3];
    const float scale = 0.05103103630798288f;   // 384^-0.5 (n_embed, per source)
    float m = -1e30f;
    for (int s = 0; s <= t; ++s) {
        float sc = (q0 * ks[s][0] + q1 * ks[s][1] + q2 * ks[s][2] + q3 * ks[s][3]) * scale;
        m = fmaxf(m, sc);
    }
    float sum = 0.f, o0 = 0.f, o1 = 0.f, o2 = 0.f, o3 = 0.f;
    for (int s = 0; s <= t; ++s) {
        float sc = (q0 * ks[s][0] + q1 * ks[s][1] + q2 * ks[s][2] + q3 * ks[s][3]) * scale;
        float p = __expf(sc - m);
        sum += p;
        o0 += p * vs[s][0]; o1 += p * vs[s][1]; o2 += p * vs[s][2]; o3 += p * vs[s][3];
    }
    float inv = 1.f / sum;
    float* out = attnT + (b * T_SEQ + t) * (NH * HS) + h * HS;
    out[0] = o0 * inv; out[1] = o1 * inv; out[2] = o2 * inv; out[3] = o3 * inv;
}

// ---------------- proj: x2[token,c] = sum_j attnT[token,j]*Wproj[j,c] + bproj[c]
__global__ void proj_kernel(const float* __restrict__ attnT,
                            const float* __restrict__ Wproj,
                            const float* __restrict__ bproj,
                            bf16* __restrict__ x2) {
    __shared__ float as[NH * HS];
    int token = blockIdx.x;
    int c = threadIdx.x;           // 384 threads
    if (c < NH * HS) as[c] = attnT[token * (NH * HS) + c];
    __syncthreads();
    float acc = bproj[c];
    #pragma unroll
    for (int j = 0; j < NH * HS; ++j) acc += as[j] * Wproj[j * C_EMB + c];
    x2[token * C_EMB + c] = f2b(acc);
}

// ---------------- generic tiled GEMM: out = [relu](A[M,K] @ B[K,N] + bias[N])
// A is bf16 (intermediate), B/bias are f32 (model weights).
// BM=BN=64, BK=16, 256 threads, 4x4 per thread, f32 accumulate.
__global__ __launch_bounds__(256)
void gemm_kernel(const bf16* __restrict__ A, const float* __restrict__ B,
                 const float* __restrict__ bias,
                 bf16* __restrict__ outb, float* __restrict__ outf,
                 int M, int N, int K, int relu) {
    __shared__ float As[16][65];
    __shared__ float Bs[16][65];
    int bm = blockIdx.y * 64;
    int bn = blockIdx.x * 64;
    int tid = threadIdx.x;
    int tx = tid & 15, ty = tid >> 4;
    float acc[4][4] = {};
    for (int k0 = 0; k0 < K; k0 += 16) {
        #pragma unroll
        for (int i = 0; i < 4; ++i) {      // A tile: 64 rows x 16 k
            int li = tid + i * 256;
            int m = li >> 4;
            int kk = li & 15;
            As[kk][m] = b2f(A[(size_t)(bm + m) * K + k0 + kk]);
        }
        #pragma unroll
        for (int i = 0; i < 4; ++i) {      // B tile: 16 k x 64 n (coalesced over n)
            int li = tid + i * 256;
            int kk = li >> 6;
            int n = li & 63;
            int gn = bn + n;
            Bs[kk][n] = (gn < N) ? B[(size_t)(k0 + kk) * N + gn] : 0.f;
        }
        __syncthreads();
        #pragma unroll
        for (int kk = 0; kk < 16; ++kk) {
            float a0 = As[kk][ty * 4 + 0], a1 = As[kk][ty * 4 + 1];
            float a2 = As[kk][ty * 4 + 2], a3 = As[kk][ty * 4 + 3];
            float c0 = Bs[kk][tx * 4 + 0], c1 = Bs[kk][tx * 4 + 1];
            float c2 = Bs[kk][tx * 4 + 2], c3 = Bs[kk][tx * 4 + 3];
            acc[0][0] += a0 * c0; acc[0][1] += a0 * c1; acc[0][2] += a0 * c2; acc[0][3] += a0 * c3;
            acc[1][0] += a1 * c0; acc[1][1] += a1 * c1; acc[1][2] += a1 * c2; acc[1][3] += a1 * c3;
            acc[2][0] += a2 * c0; acc[2][1] += a2 * c1; acc[2][2] += a2 * c2; acc[2][3] += a2 * c3;
            acc[3][0] += a3 * c0; acc[3][1] += a3 * c1; acc[3][2] += a3 * c2; acc[3][3] += a3 * c3;
        }
        __syncthreads();
    }
    #pragma unroll
    for (int i = 0; i < 4; ++i) {
        int gm = bm + ty * 4 + i;
        #pragma unroll
        for (int j = 0; j < 4; ++j) {
            int gn = bn + tx * 4 + j;
            if (gn < N) {
                float vv = acc[i][j] + bias[gn];
                if (relu) vv = fmaxf(vv, 0.f);
                if (outf) outf[(size_t)gm * N + gn] = vv;
                else      outb[(size_t)gm * N + gn] = f2b(vv);
            }
        }
    }
}

// ---------------- per-token CE loss (reads f32 logits already in d_out)
__global__ void loss_kernel(const float* __restrict__ logits,
                            const int* __restrict__ targets,
                            float* __restrict__ lossbuf) {
    int token = blockIdx.x;
    int v = threadIdx.x;           // 128 threads
    __shared__ float red[128];
    const float* lr = logits + (size_t)token * VOC;
    float val = (v < VOC) ? lr[v] : -1e30f;
    red[v] = val; __syncthreads();
    for (int s = 64; s > 0; s >>= 1) { if (v < s) red[v] = fmaxf(red[v], red[v + s]); __syncthreads(); }
    float mx = red[0]; __syncthreads();
    red[v] = (v < VOC) ? __expf(val - mx) : 0.f; __syncthreads();
    for (int s = 64; s > 0; s >>= 1) { if (v < s) red[v] += red[v + s]; __syncthreads(); }
    if (v == 0) {
        float lse = mx + logf(red[0]);
        lossbuf[token] = lse - lr[targets[token]];
    }
}

__global__ void loss_reduce_kernel(const float* __restrict__ lossbuf, float* __restrict__ out_loss) {
    __shared__ float red[256];
    int tid = threadIdx.x;
    float s = 0.f;
    for (int i = tid; i < NTOK; i += 256) s += lossbuf[i];
    red[tid] = s; __syncthreads();
    for (int st = 128; st > 0; st >>= 1) { if (tid < st) red[tid] += red[tid + st]; __syncthreads(); }
    if (tid == 0) out_loss[0] = red[0] / (float)NTOK;
}

extern "C" void kernel_launch(void* const* d_in, const int* in_sizes, int n_in,
                              void* d_out, int out_size, void* d_ws, size_t ws_size,
                              hipStream_t stream) {
    const int*   idx     = (const int*)  d_in[0];
    const int*   targets = (const int*)  d_in[1];
    const float* tok_emb = (const float*)d_in[2];
    const float* pos_emb = (const float*)d_in[3];
    const float* Wq      = (const float*)d_in[4];
    const float* Wk      = (const float*)d_in[5];
    const float* Wv      = (const float*)d_in[6];
    const float* Wproj   = (const float*)d_in[7];
    const float* bproj   = (const float*)d_in[8];
    const float* W1      = (const float*)d_in[9];
    const float* b1      = (const float*)d_in[10];
    const float* W2      = (const float*)d_in[11];
    const float* b2      = (const float*)d_in[12];
    const float* Wlm     = (const float*)d_in[13];
    const float* blm     = (const float*)d_in[14];

    char* ws = (char*)d_ws;
    // ws layout (bytes); intermediates bf16 to bound footprint (~189 MB)
    bf16*  x      = (bf16*) (ws + 0);                       // 32768*384 bf16  = 25165824
    float* q      = (float*)(ws + 25165824);                // 786432 f32      = 3145728
    float* k      = (float*)(ws + 28311552);
    float* v      = (float*)(ws + 31457280);
    float* attnT  = (float*)(ws + 34603008);                // 32768*24 f32    = 3145728
    bf16*  x2     = (bf16*) (ws + 37748736);                // 25165824
    bf16*  h1     = (bf16*) (ws + 62914560);                // 32768*1536 bf16 = 100663296
    bf16*  x3     = (bf16*) (ws + 163577856);               // 25165824
    float* lossbuf= (float*)(ws + 188743680);               // 32768 f32

    float* out_logits = (float*)d_out;                      // [32768*65] f32
    float* out_loss   = out_logits + (size_t)NTOK * VOC;    // [1] f32

    embed_kernel<<<NTOK, C_EMB, 0, stream>>>(idx, tok_emb, pos_emb, x);
    qkv_kernel<<<NTOK, 128, 0, stream>>>(x, Wq, Wk, Wv, q, k, v);
    attn_kernel<<<NB * NH, T_SEQ, 0, stream>>>(q, k, v, attnT);
    proj_kernel<<<NTOK, C_EMB, 0, stream>>>(attnT, Wproj, bproj, x2);

    // FF1: [32768,384] @ [384,1536] + b1, relu -> h1 (bf16)
    gemm_kernel<<<dim3(FFDIM / 64, NTOK / 64), 256, 0, stream>>>(x2, W1, b1, h1, nullptr,
                                                                 NTOK, FFDIM, C_EMB, 1);
    // FF2: [32768,1536] @ [1536,384] + b2 -> x3 (bf16)
    gemm_kernel<<<dim3(C_EMB / 64, NTOK / 64), 256, 0, stream>>>(h1, W2, b2, x3, nullptr,
                                                                 NTOK, C_EMB, FFDIM, 0);
    // LM head: [32768,384] @ [384,65] + blm -> f32 logits straight into d_out
    gemm_kernel<<<dim3((VOC + 63) / 64, NTOK / 64), 256, 0, stream>>>(x3, Wlm, blm, nullptr, out_logits,
                                                                      NTOK, VOC, C_EMB, 0);

    loss_kernel<<<NTOK, 128, 0, stream>>>(out_logits, targets, lossbuf);
    loss_reduce_kernel<<<1, 256, 0, stream>>>(lossbuf, out_loss);
}

// Round 3
// 899.562 us; speedup vs baseline: 2.4827x; 2.4827x over previous
//
#include <hip/hip_runtime.h>
#include <hip/hip_bf16.h>
#include <math.h>

typedef __hip_bfloat16 bf16;
typedef __attribute__((ext_vector_type(8))) short bf16x8;
typedef __attribute__((ext_vector_type(4))) float f32x4;

#define T_SEQ   256
#define C_EMB   384
#define NH      6
#define HS      4
#define NB      128
#define NTOK    (NB * T_SEQ)   // 32768
#define VOC     65
#define FFDIM   1536

__device__ __forceinline__ float b2f(bf16 x) { return __bfloat162float(x); }
__device__ __forceinline__ bf16  f2b(float x) { return __float2bfloat16(x); }

// ---------------- embedding
__global__ void embed_kernel(const int* __restrict__ idx,
                             const float* __restrict__ tok_emb,
                             const float* __restrict__ pos_emb,
                             bf16* __restrict__ x) {
    int token = blockIdx.x;
    int c = threadIdx.x;           // 384 threads
    int t = token & (T_SEQ - 1);
    int id = idx[token];
    float v = tok_emb[id * C_EMB + c] + pos_emb[t * C_EMB + c];
    x[token * C_EMB + c] = f2b(v);
}

// ---------------- qkv
__global__ void qkv_kernel(const bf16* __restrict__ x,
                           const float* __restrict__ Wq,
                           const float* __restrict__ Wk,
                           const float* __restrict__ Wv,
                           float* __restrict__ q, float* __restrict__ k, float* __restrict__ v) {
    __shared__ float xs[C_EMB];
    int token = blockIdx.x;
    int tid = threadIdx.x;         // 128 threads
    for (int i = tid; i < C_EMB; i += 128) xs[i] = b2f(x[token * C_EMB + i]);
    __syncthreads();
    if (tid < 72) {
        int h = tid / 12;
        int r = tid % 12;
        int sel = r >> 2;          // 0=q 1=k 2=v
        int d = r & 3;
        const float* W = (sel == 0) ? Wq : (sel == 1) ? Wk : Wv;
        const float* Wp = W + h * C_EMB * HS + d;
        float acc = 0.f;
        #pragma unroll 8
        for (int c = 0; c < C_EMB; ++c) acc += xs[c] * Wp[c * HS];
        int b = token >> 8, t = token & (T_SEQ - 1);
        int o = ((b * NH + h) * T_SEQ + t) * HS + d;
        float* dst = (sel == 0) ? q : (sel == 1) ? k : v;
        dst[o] = acc;
    }
}

// ---------------- causal softmax attention
__global__ void attn_kernel(const float* __restrict__ q,
                            const float* __restrict__ k,
                            const float* __restrict__ v,
                            float* __restrict__ attnT) {
    int bh = blockIdx.x;
    int b = bh / NH, h = bh % NH;
    int t = threadIdx.x;           // 256 threads
    __shared__ float ks[T_SEQ][HS];
    __shared__ float vs[T_SEQ][HS];
    const float* kb = k + bh * T_SEQ * HS;
    const float* vb = v + bh * T_SEQ * HS;
    #pragma unroll
    for (int d = 0; d < HS; ++d) { ks[t][d] = kb[t * HS + d]; vs[t][d] = vb[t * HS + d]; }
    __syncthreads();
    const float* qb = q + bh * T_SEQ * HS + t * HS;
    float q0 = qb[0], q1 = qb[1], q2 = qb[2], q3 = qb[3];
    const float scale = 0.05103103630798288f;   // 384^-0.5
    float m = -1e30f;
    for (int s = 0; s <= t; ++s) {
        float sc = (q0 * ks[s][0] + q1 * ks[s][1] + q2 * ks[s][2] + q3 * ks[s][3]) * scale;
        m = fmaxf(m, sc);
    }
    float sum = 0.f, o0 = 0.f, o1 = 0.f, o2 = 0.f, o3 = 0.f;
    for (int s = 0; s <= t; ++s) {
        float sc = (q0 * ks[s][0] + q1 * ks[s][1] + q2 * ks[s][2] + q3 * ks[s][3]) * scale;
        float p = __expf(sc - m);
        sum += p;
        o0 += p * vs[s][0]; o1 += p * vs[s][1]; o2 += p * vs[s][2]; o3 += p * vs[s][3];
    }
    float inv = 1.f / sum;
    float* out = attnT + (b * T_SEQ + t) * (NH * HS) + h * HS;
    out[0] = o0 * inv; out[1] = o1 * inv; out[2] = o2 * inv; out[3] = o3 * inv;
}

// ---------------- proj
__global__ void proj_kernel(const float* __restrict__ attnT,
                            const float* __restrict__ Wproj,
                            const float* __restrict__ bproj,
                            bf16* __restrict__ x2) {
    __shared__ float as[NH * HS];
    int token = blockIdx.x;
    int c = threadIdx.x;           // 384 threads
    if (c < NH * HS) as[c] = attnT[token * (NH * HS) + c];
    __syncthreads();
    float acc = bproj[c];
    #pragma unroll
    for (int j = 0; j < NH * HS; ++j) acc += as[j] * Wproj[j * C_EMB + c];
    x2[token * C_EMB + c] = f2b(acc);
}

// ---------------- W [K,N] f32 -> W^T [N,K] bf16 (once per launch, small)
__global__ void convT_kernel(const float* __restrict__ in, bf16* __restrict__ out, int K, int N) {
    int n = blockIdx.x;
    for (int k = threadIdx.x; k < K; k += 256)
        out[(size_t)n * K + k] = f2b(in[(size_t)k * N + n]);
}

// ---------------- MFMA GEMM: out[M,N] = [relu](A[M,K] @ Bt[N,K]^T + bias[N]), bf16 in/out
// 128x128 tile, BK=32, 4 waves, each wave 64x64 via 4x4 of 16x16x32 MFMA.
// Requires M%128==0, N%128==0, K%32==0.
__global__ __launch_bounds__(256)
void gemm_mfma_kernel(const bf16* __restrict__ A, const bf16* __restrict__ Bt,
                      const float* __restrict__ bias, bf16* __restrict__ out,
                      int M, int N, int K, int relu) {
    __shared__ short As[128][40];   // pitch 40 shorts = 80B: 16B-aligned rows, 2-way bank alias max
    __shared__ short Bs[128][40];
    int tid  = threadIdx.x;
    int lane = tid & 63;
    int wave = tid >> 6;
    int bm = blockIdx.y * 128;
    int bn = blockIdx.x * 128;
    int wm = (wave & 1) * 64;
    int wn = (wave >> 1) * 64;
    int lrow  = lane & 15;
    int khalf = lane >> 4;

    f32x4 acc[4][4] = {};

    // staging: chunk id c in [0,512): row=c>>2, 16B chunk (c&3)*8 shorts. thread does c=tid, c=tid+256.
    int ar = tid >> 2, ach = (tid & 3) * 8;

    for (int k0 = 0; k0 < K; k0 += 32) {
        const bf16* Ab = A  + (size_t)(bm + ar) * K + k0 + ach;
        const bf16* Bb = Bt + (size_t)(bn + ar) * K + k0 + ach;
        uint4 a0 = *(const uint4*)Ab;
        uint4 a1 = *(const uint4*)(Ab + (size_t)64 * K);
        uint4 b0 = *(const uint4*)Bb;
        uint4 b1 = *(const uint4*)(Bb + (size_t)64 * K);
        *(uint4*)&As[ar][ach]      = a0;
        *(uint4*)&As[64 + ar][ach] = a1;
        *(uint4*)&Bs[ar][ach]      = b0;
        *(uint4*)&Bs[64 + ar][ach] = b1;
        __syncthreads();

        bf16x8 af[4], bf[4];
        #pragma unroll
        for (int i = 0; i < 4; ++i) {
            af[i] = *(const bf16x8*)&As[wm + i * 16 + lrow][khalf * 8];
            bf[i] = *(const bf16x8*)&Bs[wn + i * 16 + lrow][khalf * 8];
        }
        #pragma unroll
        for (int mi = 0; mi < 4; ++mi)
            #pragma unroll
            for (int ni = 0; ni < 4; ++ni)
                acc[mi][ni] = __builtin_amdgcn_mfma_f32_16x16x32_bf16(af[mi], bf[ni], acc[mi][ni], 0, 0, 0);
        __syncthreads();
    }

    // epilogue: C/D layout col=lane&15, row=(lane>>4)*4+r  [m89-verified]
    #pragma unroll
    for (int ni = 0; ni < 4; ++ni) {
        int col = bn + wn + ni * 16 + lrow;
        float bv = bias[col];
        #pragma unroll
        for (int mi = 0; mi < 4; ++mi) {
            int row = bm + wm + mi * 16 + khalf * 4;
            #pragma unroll
            for (int r = 0; r < 4; ++r) {
                float v = acc[mi][ni][r] + bv;
                if (relu) v = fmaxf(v, 0.f);
                out[(size_t)(row + r) * N + col] = f2b(v);
            }
        }
    }
}

// ---------------- SIMT GEMM (LM head only: N=65): out f32 = A[M,K]bf16 @ B[K,N]f32 + bias
__global__ __launch_bounds__(256)
void gemm_kernel(const bf16* __restrict__ A, const float* __restrict__ B,
                 const float* __restrict__ bias, float* __restrict__ outf,
                 int M, int N, int K) {
    __shared__ float As[16][65];
    __shared__ float Bs[16][65];
    int bm = blockIdx.y * 64;
    int bn = blockIdx.x * 64;
    int tid = threadIdx.x;
    int tx = tid & 15, ty = tid >> 4;
    float acc[4][4] = {};
    for (int k0 = 0; k0 < K; k0 += 16) {
        #pragma unroll
        for (int i = 0; i < 4; ++i) {
            int li = tid + i * 256;
            int m = li >> 4;
            int kk = li & 15;
            As[kk][m] = b2f(A[(size_t)(bm + m) * K + k0 + kk]);
        }
        #pragma unroll
        for (int i = 0; i < 4; ++i) {
            int li = tid + i * 256;
            int kk = li >> 6;
            int n = li & 63;
            int gn = bn + n;
            Bs[kk][n] = (gn < N) ? B[(size_t)(k0 + kk) * N + gn] : 0.f;
        }
        __syncthreads();
        #pragma unroll
        for (int kk = 0; kk < 16; ++kk) {
            float a0 = As[kk][ty * 4 + 0], a1 = As[kk][ty * 4 + 1];
            float a2 = As[kk][ty * 4 + 2], a3 = As[kk][ty * 4 + 3];
            float c0 = Bs[kk][tx * 4 + 0], c1 = Bs[kk][tx * 4 + 1];
            float c2 = Bs[kk][tx * 4 + 2], c3 = Bs[kk][tx * 4 + 3];
            acc[0][0] += a0 * c0; acc[0][1] += a0 * c1; acc[0][2] += a0 * c2; acc[0][3] += a0 * c3;
            acc[1][0] += a1 * c0; acc[1][1] += a1 * c1; acc[1][2] += a1 * c2; acc[1][3] += a1 * c3;
            acc[2][0] += a2 * c0; acc[2][1] += a2 * c1; acc[2][2] += a2 * c2; acc[2][3] += a2 * c3;
            acc[3][0] += a3 * c0; acc[3][1] += a3 * c1; acc[3][2] += a3 * c2; acc[3][3] += a3 * c3;
        }
        __syncthreads();
    }
    #pragma unroll
    for (int i = 0; i < 4; ++i) {
        int gm = bm + ty * 4 + i;
        #pragma unroll
        for (int j = 0; j < 4; ++j) {
            int gn = bn + tx * 4 + j;
            if (gn < N) outf[(size_t)gm * N + gn] = acc[i][j] + bias[gn];
        }
    }
}

// ---------------- per-token CE loss
__global__ void loss_kernel(const float* __restrict__ logits,
                            const int* __restrict__ targets,
                            float* __restrict__ lossbuf) {
    int token = blockIdx.x;
    int v = threadIdx.x;           // 128 threads
    __shared__ float red[128];
    const float* lr = logits + (size_t)token * VOC;
    float val = (v < VOC) ? lr[v] : -1e30f;
    red[v] = val; __syncthreads();
    for (int s = 64; s > 0; s >>= 1) { if (v < s) red[v] = fmaxf(red[v], red[v + s]); __syncthreads(); }
    float mx = red[0]; __syncthreads();
    red[v] = (v < VOC) ? __expf(val - mx) : 0.f; __syncthreads();
    for (int s = 64; s > 0; s >>= 1) { if (v < s) red[v] += red[v + s]; __syncthreads(); }
    if (v == 0) {
        float lse = mx + logf(red[0]);
        lossbuf[token] = lse - lr[targets[token]];
    }
}

__global__ void loss_reduce_kernel(const float* __restrict__ lossbuf, float* __restrict__ out_loss) {
    __shared__ float red[256];
    int tid = threadIdx.x;
    float s = 0.f;
    for (int i = tid; i < NTOK; i += 256) s += lossbuf[i];
    red[tid] = s; __syncthreads();
    for (int st = 128; st > 0; st >>= 1) { if (tid < st) red[tid] += red[tid + st]; __syncthreads(); }
    if (tid == 0) out_loss[0] = red[0] / (float)NTOK;
}

extern "C" void kernel_launch(void* const* d_in, const int* in_sizes, int n_in,
                              void* d_out, int out_size, void* d_ws, size_t ws_size,
                              hipStream_t stream) {
    const int*   idx     = (const int*)  d_in[0];
    const int*   targets = (const int*)  d_in[1];
    const float* tok_emb = (const float*)d_in[2];
    const float* pos_emb = (const float*)d_in[3];
    const float* Wq      = (const float*)d_in[4];
    const float* Wk      = (const float*)d_in[5];
    const float* Wv      = (const float*)d_in[6];
    const float* Wproj   = (const float*)d_in[7];
    const float* bproj   = (const float*)d_in[8];
    const float* W1      = (const float*)d_in[9];
    const float* b1      = (const float*)d_in[10];
    const float* W2      = (const float*)d_in[11];
    const float* b2      = (const float*)d_in[12];
    const float* Wlm     = (const float*)d_in[13];
    const float* blm     = (const float*)d_in[14];

    char* ws = (char*)d_ws;
    bf16*  x      = (bf16*) (ws + 0);                       // 25165824 B
    float* q      = (float*)(ws + 25165824);                // 3145728 B
    float* k      = (float*)(ws + 28311552);
    float* v      = (float*)(ws + 31457280);
    float* attnT  = (float*)(ws + 34603008);                // 3145728 B
    bf16*  x2     = (bf16*) (ws + 37748736);                // 25165824 B
    bf16*  h1     = (bf16*) (ws + 62914560);                // 100663296 B
    bf16*  x3     = (bf16*) (ws + 163577856);               // 25165824 B
    float* lossbuf= (float*)(ws + 188743680);               // 131072 B
    bf16*  W1t    = (bf16*) (ws + 188874752);               // [1536,384] bf16 = 1179648 B
    bf16*  W2t    = (bf16*) (ws + 190054400);               // [384,1536] bf16 = 1179648 B

    float* out_logits = (float*)d_out;                      // [32768*65] f32
    float* out_loss   = out_logits + (size_t)NTOK * VOC;    // [1]

    // weight transposes (tiny) first — independent of activations
    convT_kernel<<<FFDIM, 256, 0, stream>>>(W1, W1t, C_EMB, FFDIM);   // [384,1536] -> [1536,384]
    convT_kernel<<<C_EMB, 256, 0, stream>>>(W2, W2t, FFDIM, C_EMB);   // [1536,384] -> [384,1536]

    embed_kernel<<<NTOK, C_EMB, 0, stream>>>(idx, tok_emb, pos_emb, x);
    qkv_kernel<<<NTOK, 128, 0, stream>>>(x, Wq, Wk, Wv, q, k, v);
    attn_kernel<<<NB * NH, T_SEQ, 0, stream>>>(q, k, v, attnT);
    proj_kernel<<<NTOK, C_EMB, 0, stream>>>(attnT, Wproj, bproj, x2);

    // FF1: [32768,384] @ [384,1536] + b1, relu -> h1 (bf16), MFMA
    gemm_mfma_kernel<<<dim3(FFDIM / 128, NTOK / 128), 256, 0, stream>>>(x2, W1t, b1, h1,
                                                                        NTOK, FFDIM, C_EMB, 1);
    // FF2: [32768,1536] @ [1536,384] + b2 -> x3 (bf16), MFMA
    gemm_mfma_kernel<<<dim3(C_EMB / 128, NTOK / 128), 256, 0, stream>>>(h1, W2t, b2, x3,
                                                                        NTOK, C_EMB, FFDIM, 0);
    // LM head: [32768,384] @ [384,65] + blm -> f32 logits into d_out (SIMT)
    gemm_kernel<<<dim3((VOC + 63) / 64, NTOK / 64), 256, 0, stream>>>(x3, Wlm, blm, out_logits,
                                                                     NTOK, VOC, C_EMB);

    loss_kernel<<<NTOK, 128, 0, stream>>>(out_logits, targets, lossbuf);
    loss_reduce_kernel<<<1, 256, 0, stream>>>(lossbuf, out_loss);
}

// Round 4
// 436.494 us; speedup vs baseline: 5.1166x; 2.0609x over previous
//
#include <hip/hip_runtime.h>
#include <hip/hip_bf16.h>
#include <math.h>

typedef __hip_bfloat16 bf16;
typedef __attribute__((ext_vector_type(8))) short bf16x8;
typedef __attribute__((ext_vector_type(4))) float f32x4;

#define T_SEQ   256
#define C_EMB   384
#define NH      6
#define HS      4
#define NB      128
#define NTOK    (NB * T_SEQ)   // 32768
#define VOC     65
#define FFDIM   1536
#define QKVW    72             // 3*NH*HS packed width

__device__ __forceinline__ float b2f(bf16 x) { return __bfloat162float(x); }
__device__ __forceinline__ bf16  f2b(float x) { return __float2bfloat16(x); }

// ---------------- embedding
__global__ void embed_kernel(const int* __restrict__ idx,
                             const float* __restrict__ tok_emb,
                             const float* __restrict__ pos_emb,
                             bf16* __restrict__ x) {
    int token = blockIdx.x;
    int c = threadIdx.x;           // 384 threads
    int t = token & (T_SEQ - 1);
    int id = idx[token];
    float v = tok_emb[id * C_EMB + c] + pos_emb[t * C_EMB + c];
    x[token * C_EMB + c] = f2b(v);
}

// ---------------- pack Wq|Wk|Wv [NH,C,HS] f32 -> WqkvT [128,384] bf16 (row n = out col, zero-pad n>=72)
__global__ void pack_qkv_kernel(const float* __restrict__ Wq, const float* __restrict__ Wk,
                                const float* __restrict__ Wv, bf16* __restrict__ Wt) {
    int n = blockIdx.x;            // 128
    for (int c = threadIdx.x; c < C_EMB; c += 256) {
        float v = 0.f;
        if (n < QKVW) {
            int sel = n / 24, r = n % 24, h = r >> 2, d = r & 3;
            const float* W = (sel == 0) ? Wq : (sel == 1) ? Wk : Wv;
            v = W[(h * C_EMB + c) * HS + d];
        }
        Wt[(size_t)n * C_EMB + c] = f2b(v);
    }
}

// ---------------- pack Wlm [C,VOC] f32 -> WlmT [128,384] bf16 (zero-pad n>=65)
__global__ void pack_lm_kernel(const float* __restrict__ Wlm, bf16* __restrict__ Wt) {
    int n = blockIdx.x;            // 128
    for (int c = threadIdx.x; c < C_EMB; c += 256)
        Wt[(size_t)n * C_EMB + c] = f2b(n < VOC ? Wlm[(size_t)c * VOC + n] : 0.f);
}

// ---------------- W [K,N] f32 -> W^T [N,K] bf16
__global__ void convT_kernel(const float* __restrict__ in, bf16* __restrict__ out, int K, int N) {
    int n = blockIdx.x;
    for (int k = threadIdx.x; k < K; k += 256)
        out[(size_t)n * K + k] = f2b(in[(size_t)k * N + n]);
}

// ---------------- causal softmax attention; q/k/v packed as qkv[token,72] f32
__global__ void attn_kernel(const float* __restrict__ qkv,
                            float* __restrict__ attnT) {
    int bh = blockIdx.x;
    int b = bh / NH, h = bh % NH;
    int t = threadIdx.x;           // 256 threads
    __shared__ float ks[T_SEQ][HS];
    __shared__ float vs[T_SEQ][HS];
    const float* base = qkv + (size_t)(b * T_SEQ) * QKVW;
    #pragma unroll
    for (int d = 0; d < HS; ++d) {
        ks[t][d] = base[t * QKVW + 24 + h * HS + d];
        vs[t][d] = base[t * QKVW + 48 + h * HS + d];
    }
    __syncthreads();
    const float* qp = base + t * QKVW + h * HS;
    float q0 = qp[0], q1 = qp[1], q2 = qp[2], q3 = qp[3];
    const float scale = 0.05103103630798288f;   // 384^-0.5
    float m = -1e30f;
    for (int s = 0; s <= t; ++s) {
        float sc = (q0 * ks[s][0] + q1 * ks[s][1] + q2 * ks[s][2] + q3 * ks[s][3]) * scale;
        m = fmaxf(m, sc);
    }
    float sum = 0.f, o0 = 0.f, o1 = 0.f, o2 = 0.f, o3 = 0.f;
    for (int s = 0; s <= t; ++s) {
        float sc = (q0 * ks[s][0] + q1 * ks[s][1] + q2 * ks[s][2] + q3 * ks[s][3]) * scale;
        float p = __expf(sc - m);
        sum += p;
        o0 += p * vs[s][0]; o1 += p * vs[s][1]; o2 += p * vs[s][2]; o3 += p * vs[s][3];
    }
    float inv = 1.f / sum;
    float* out = attnT + (size_t)(b * T_SEQ + t) * (NH * HS) + h * HS;
    out[0] = o0 * inv; out[1] = o1 * inv; out[2] = o2 * inv; out[3] = o3 * inv;
}

// ---------------- proj
__global__ void proj_kernel(const float* __restrict__ attnT,
                            const float* __restrict__ Wproj,
                            const float* __restrict__ bproj,
                            bf16* __restrict__ x2) {
    __shared__ float as[NH * HS];
    int token = blockIdx.x;
    int c = threadIdx.x;           // 384 threads
    if (c < NH * HS) as[c] = attnT[(size_t)token * (NH * HS) + c];
    __syncthreads();
    float acc = bproj[c];
    #pragma unroll
    for (int j = 0; j < NH * HS; ++j) acc += as[j] * Wproj[j * C_EMB + c];
    x2[(size_t)token * C_EMB + c] = f2b(acc);
}

// ---------------- MFMA GEMM: out[M,Nout] = [relu](A[M,K] @ Bt[Npad,K]^T + bias)
// A,Bt bf16; out bf16 (outb) or f32 (outf). 128x128 tile, BK=32, 4 waves.
// Requires M%128==0, Npad%128==0, K%32==0. Writes only cols < Nout, stride Nout.
__global__ __launch_bounds__(256)
void gemm_mfma_kernel(const bf16* __restrict__ A, const bf16* __restrict__ Bt,
                      const float* __restrict__ bias,
                      bf16* __restrict__ outb, float* __restrict__ outf,
                      int M, int Npad, int K, int Nout, int relu) {
    __shared__ short As[128][40];   // pitch 40 shorts: 16B rows aligned, <=2-way bank alias (free)
    __shared__ short Bs[128][40];
    int tid  = threadIdx.x;
    int lane = tid & 63;
    int wave = tid >> 6;
    int bm = blockIdx.y * 128;
    int bn = blockIdx.x * 128;
    int wm = (wave & 1) * 64;
    int wn = (wave >> 1) * 64;
    int lrow  = lane & 15;
    int khalf = lane >> 4;

    f32x4 acc[4][4] = {};
    int ar = tid >> 2, ach = (tid & 3) * 8;

    for (int k0 = 0; k0 < K; k0 += 32) {
        const bf16* Ab = A  + (size_t)(bm + ar) * K + k0 + ach;
        const bf16* Bb = Bt + (size_t)(bn + ar) * K + k0 + ach;
        uint4 a0 = *(const uint4*)Ab;
        uint4 a1 = *(const uint4*)(Ab + (size_t)64 * K);
        uint4 b0 = *(const uint4*)Bb;
        uint4 b1 = *(const uint4*)(Bb + (size_t)64 * K);
        *(uint4*)&As[ar][ach]      = a0;
        *(uint4*)&As[64 + ar][ach] = a1;
        *(uint4*)&Bs[ar][ach]      = b0;
        *(uint4*)&Bs[64 + ar][ach] = b1;
        __syncthreads();

        bf16x8 af[4], bff[4];
        #pragma unroll
        for (int i = 0; i < 4; ++i) {
            af[i]  = *(const bf16x8*)&As[wm + i * 16 + lrow][khalf * 8];
            bff[i] = *(const bf16x8*)&Bs[wn + i * 16 + lrow][khalf * 8];
        }
        #pragma unroll
        for (int mi = 0; mi < 4; ++mi)
            #pragma unroll
            for (int ni = 0; ni < 4; ++ni)
                acc[mi][ni] = __builtin_amdgcn_mfma_f32_16x16x32_bf16(af[mi], bff[ni], acc[mi][ni], 0, 0, 0);
        __syncthreads();
    }

    // epilogue: C/D layout col=lane&15, row=(lane>>4)*4+r  [m89-verified]
    #pragma unroll
    for (int ni = 0; ni < 4; ++ni) {
        int col = bn + wn + ni * 16 + lrow;
        if (col >= Nout) continue;
        float bv = bias ? bias[col] : 0.f;
        #pragma unroll
        for (int mi = 0; mi < 4; ++mi) {
            int row = bm + wm + mi * 16 + khalf * 4;
            #pragma unroll
            for (int r = 0; r < 4; ++r) {
                float v = acc[mi][ni][r] + bv;
                if (relu) v = fmaxf(v, 0.f);
                if (outf) outf[(size_t)(row + r) * Nout + col] = v;
                else      outb[(size_t)(row + r) * Nout + col] = f2b(v);
            }
        }
    }
}

// ---------------- per-token CE loss
__global__ void loss_kernel(const float* __restrict__ logits,
                            const int* __restrict__ targets,
                            float* __restrict__ lossbuf) {
    int token = blockIdx.x;
    int v = threadIdx.x;           // 128 threads
    __shared__ float red[128];
    const float* lr = logits + (size_t)token * VOC;
    float val = (v < VOC) ? lr[v] : -1e30f;
    red[v] = val; __syncthreads();
    for (int s = 64; s > 0; s >>= 1) { if (v < s) red[v] = fmaxf(red[v], red[v + s]); __syncthreads(); }
    float mx = red[0]; __syncthreads();
    red[v] = (v < VOC) ? __expf(val - mx) : 0.f; __syncthreads();
    for (int s = 64; s > 0; s >>= 1) { if (v < s) red[v] += red[v + s]; __syncthreads(); }
    if (v == 0) {
        float lse = mx + logf(red[0]);
        lossbuf[token] = lse - lr[targets[token]];
    }
}

__global__ void loss_reduce_kernel(const float* __restrict__ lossbuf, float* __restrict__ out_loss) {
    __shared__ float red[256];
    int tid = threadIdx.x;
    float s = 0.f;
    for (int i = tid; i < NTOK; i += 256) s += lossbuf[i];
    red[tid] = s; __syncthreads();
    for (int st = 128; st > 0; st >>= 1) { if (tid < st) red[tid] += red[tid + st]; __syncthreads(); }
    if (tid == 0) out_loss[0] = red[0] / (float)NTOK;
}

extern "C" void kernel_launch(void* const* d_in, const int* in_sizes, int n_in,
                              void* d_out, int out_size, void* d_ws, size_t ws_size,
                              hipStream_t stream) {
    const int*   idx     = (const int*)  d_in[0];
    const int*   targets = (const int*)  d_in[1];
    const float* tok_emb = (const float*)d_in[2];
    const float* pos_emb = (const float*)d_in[3];
    const float* Wq      = (const float*)d_in[4];
    const float* Wk      = (const float*)d_in[5];
    const float* Wv      = (const float*)d_in[6];
    const float* Wproj   = (const float*)d_in[7];
    const float* bproj   = (const float*)d_in[8];
    const float* W1      = (const float*)d_in[9];
    const float* b1      = (const float*)d_in[10];
    const float* W2      = (const float*)d_in[11];
    const float* b2      = (const float*)d_in[12];
    const float* Wlm     = (const float*)d_in[13];
    const float* blm     = (const float*)d_in[14];

    char* ws = (char*)d_ws;
    bf16*  x      = (bf16*) (ws + 0);                       // 25165824 B
    float* qkvbuf = (float*)(ws + 25165824);                // 32768*72 f32 = 9437184 B
    float* attnT  = (float*)(ws + 34603008);                // 3145728 B
    bf16*  x2     = (bf16*) (ws + 37748736);                // 25165824 B
    bf16*  h1     = (bf16*) (ws + 62914560);                // 100663296 B
    bf16*  x3     = (bf16*) (ws + 163577856);               // 25165824 B
    float* lossbuf= (float*)(ws + 188743680);               // 131072 B
    bf16*  W1t    = (bf16*) (ws + 188874752);               // 1179648 B
    bf16*  W2t    = (bf16*) (ws + 190054400);               // 1179648 B
    bf16*  WqkvT  = (bf16*) (ws + 191234048);               // 128*384*2 = 98304 B
    bf16*  WlmT   = (bf16*) (ws + 191332352);               // 98304 B

    float* out_logits = (float*)d_out;                      // [32768*65] f32
    float* out_loss   = out_logits + (size_t)NTOK * VOC;    // [1]

    // weight packing (tiny, independent of activations)
    pack_qkv_kernel<<<128, 256, 0, stream>>>(Wq, Wk, Wv, WqkvT);
    pack_lm_kernel<<<128, 256, 0, stream>>>(Wlm, WlmT);
    convT_kernel<<<FFDIM, 256, 0, stream>>>(W1, W1t, C_EMB, FFDIM);   // [384,1536] -> [1536,384]
    convT_kernel<<<C_EMB, 256, 0, stream>>>(W2, W2t, FFDIM, C_EMB);   // [1536,384] -> [384,1536]

    embed_kernel<<<NTOK, C_EMB, 0, stream>>>(idx, tok_emb, pos_emb, x);

    // QKV: [32768,384] @ [384,72pad128] -> qkvbuf f32 [32768,72]
    gemm_mfma_kernel<<<dim3(1, NTOK / 128), 256, 0, stream>>>(x, WqkvT, nullptr, nullptr, qkvbuf,
                                                              NTOK, 128, C_EMB, QKVW, 0);
    attn_kernel<<<NB * NH, T_SEQ, 0, stream>>>(qkvbuf, attnT);
    proj_kernel<<<NTOK, C_EMB, 0, stream>>>(attnT, Wproj, bproj, x2);

    // FF1: [32768,384] @ [384,1536] + b1, relu -> h1 (bf16)
    gemm_mfma_kernel<<<dim3(FFDIM / 128, NTOK / 128), 256, 0, stream>>>(x2, W1t, b1, h1, nullptr,
                                                                        NTOK, FFDIM, C_EMB, FFDIM, 1);
    // FF2: [32768,1536] @ [1536,384] + b2 -> x3 (bf16)
    gemm_mfma_kernel<<<dim3(C_EMB / 128, NTOK / 128), 256, 0, stream>>>(h1, W2t, b2, x3, nullptr,
                                                                        NTOK, C_EMB, FFDIM, C_EMB, 0);
    // LM head: [32768,384] @ [384,65pad128] + blm -> f32 logits into d_out
    gemm_mfma_kernel<<<dim3(1, NTOK / 128), 256, 0, stream>>>(x3, WlmT, blm, nullptr, out_logits,
                                                              NTOK, 128, C_EMB, VOC, 0);

    loss_kernel<<<NTOK, 128, 0, stream>>>(out_logits, targets, lossbuf);
    loss_reduce_kernel<<<1, 256, 0, stream>>>(lossbuf, out_loss);
}

// Round 5
// 414.013 us; speedup vs baseline: 5.3944x; 1.0543x over previous
//
#include <hip/hip_runtime.h>
#include <hip/hip_bf16.h>
#include <math.h>

typedef __hip_bfloat16 bf16;
typedef __attribute__((ext_vector_type(8))) short bf16x8;
typedef __attribute__((ext_vector_type(4))) float f32x4;

#define T_SEQ   256
#define C_EMB   384
#define NH      6
#define HS      4
#define NB      128
#define NTOK    (NB * T_SEQ)   // 32768
#define VOC     65
#define FFDIM   1536
#define QKVW    72             // 3*NH*HS packed width

__device__ __forceinline__ float b2f(bf16 x) { return __bfloat162float(x); }
__device__ __forceinline__ bf16  f2b(float x) { return __float2bfloat16(x); }
__device__ __forceinline__ short f2s(float x) { bf16 b = __float2bfloat16(x); return *reinterpret_cast<short*>(&b); }

// async 16B global->LDS (m97 path). Per-lane lds ptr = wave base + lane*16 (contiguous).
__device__ __forceinline__ void glds16(const void* g, short* l) {
    __builtin_amdgcn_global_load_lds((const __attribute__((address_space(1))) void*)g,
                                     (__attribute__((address_space(3))) void*)l, 16, 0, 0);
}

// ---------------- pack Wq|Wk|Wv [NH,C,HS] f32 -> WqkvT [128,384] bf16 (row n = out col, zero-pad n>=72)
__global__ void pack_qkv_kernel(const float* __restrict__ Wq, const float* __restrict__ Wk,
                                const float* __restrict__ Wv, bf16* __restrict__ Wt) {
    int n = blockIdx.x;            // 128
    for (int c = threadIdx.x; c < C_EMB; c += 256) {
        float v = 0.f;
        if (n < QKVW) {
            int sel = n / 24, r = n % 24, h = r >> 2, d = r & 3;
            const float* W = (sel == 0) ? Wq : (sel == 1) ? Wk : Wv;
            v = W[(h * C_EMB + c) * HS + d];
        }
        Wt[(size_t)n * C_EMB + c] = f2b(v);
    }
}

// ---------------- pack Wlm [C,VOC] f32 -> WlmT [128,384] bf16 (zero-pad n>=65)
__global__ void pack_lm_kernel(const float* __restrict__ Wlm, bf16* __restrict__ Wt) {
    int n = blockIdx.x;            // 128
    for (int c = threadIdx.x; c < C_EMB; c += 256)
        Wt[(size_t)n * C_EMB + c] = f2b(n < VOC ? Wlm[(size_t)c * VOC + n] : 0.f);
}

// ---------------- W [K,N] f32 -> W^T [N,K] bf16
__global__ void convT_kernel(const float* __restrict__ in, bf16* __restrict__ out, int K, int N) {
    int n = blockIdx.x;
    for (int k = threadIdx.x; k < K; k += 256)
        out[(size_t)n * K + k] = f2b(in[(size_t)k * N + n]);
}

// ---------------- fused embed + QKV GEMM: qkv[token,72] = (tok_emb[idx]+pos_emb) @ WqkvT^T
// one block per 128 tokens; A staged in registers (gather), B via global_load_lds.
__global__ __launch_bounds__(256)
void qkv_embed_mfma_kernel(const int* __restrict__ idx,
                           const float* __restrict__ tok_emb,
                           const float* __restrict__ pos_emb,
                           const bf16* __restrict__ Bt,
                           float* __restrict__ outf) {
    __shared__ short As[128][32];
    __shared__ short Bs[128][32];
    __shared__ int ids[128];
    int tid = threadIdx.x, lane = tid & 63, wave = tid >> 6;
    int bm = blockIdx.x * 128;
    int wm = (wave & 1) * 64, wn = (wave >> 1) * 64;
    int lrow = lane & 15, khalf = lane >> 4;
    if (tid < 128) ids[tid] = idx[bm + tid];
    __syncthreads();
    int tbase = bm & (T_SEQ - 1);

    f32x4 acc[4][4] = {};
    for (int k0 = 0; k0 < C_EMB; k0 += 32) {
        #pragma unroll
        for (int h = 0; h < 2; ++h) {
            int c = tid + h * 256;
            int row = c >> 2, colc = k0 + (c & 3) * 8;
            const float* te = tok_emb + (size_t)ids[row] * C_EMB + colc;
            const float* pe = pos_emb + (size_t)(tbase + row) * C_EMB + colc;
            float4 t0 = *(const float4*)te, t1 = *(const float4*)(te + 4);
            float4 p0 = *(const float4*)pe, p1 = *(const float4*)(pe + 4);
            union { short s[8]; uint4 u; } r;
            r.s[0] = f2s(t0.x + p0.x); r.s[1] = f2s(t0.y + p0.y);
            r.s[2] = f2s(t0.z + p0.z); r.s[3] = f2s(t0.w + p0.w);
            r.s[4] = f2s(t1.x + p1.x); r.s[5] = f2s(t1.y + p1.y);
            r.s[6] = f2s(t1.z + p1.z); r.s[7] = f2s(t1.w + p1.w);
            *(uint4*)((short*)As + (size_t)c * 8) = r.u;
        }
        int c = tid;
        glds16(Bt + (size_t)(c >> 2) * C_EMB + k0 + (c & 3) * 8, (short*)Bs + (size_t)c * 8);
        c = tid + 256;
        glds16(Bt + (size_t)(c >> 2) * C_EMB + k0 + (c & 3) * 8, (short*)Bs + (size_t)c * 8);
        __syncthreads();

        bf16x8 af[4], bff[4];
        #pragma unroll
        for (int i = 0; i < 4; ++i) {
            af[i]  = *(const bf16x8*)&As[wm + i * 16 + lrow][khalf * 8];
            bff[i] = *(const bf16x8*)&Bs[wn + i * 16 + lrow][khalf * 8];
        }
        #pragma unroll
        for (int mi = 0; mi < 4; ++mi)
            #pragma unroll
            for (int ni = 0; ni < 4; ++ni)
                acc[mi][ni] = __builtin_amdgcn_mfma_f32_16x16x32_bf16(af[mi], bff[ni], acc[mi][ni], 0, 0, 0);
        __syncthreads();
    }

    #pragma unroll
    for (int ni = 0; ni < 4; ++ni) {
        int col = wn + ni * 16 + lrow;
        if (col >= QKVW) continue;
        #pragma unroll
        for (int mi = 0; mi < 4; ++mi) {
            int row = bm + wm + mi * 16 + khalf * 4;
            #pragma unroll
            for (int r = 0; r < 4; ++r)
                outf[(size_t)(row + r) * QKVW + col] = acc[mi][ni][r];
        }
    }
}

// ---------------- causal softmax attention; q/k/v packed as qkv[token,72] f32
__global__ void attn_kernel(const float* __restrict__ qkv,
                            float* __restrict__ attnT) {
    int bh = blockIdx.x;
    int b = bh / NH, h = bh % NH;
    int t = threadIdx.x;           // 256 threads
    __shared__ float ks[T_SEQ][HS];
    __shared__ float vs[T_SEQ][HS];
    const float* base = qkv + (size_t)(b * T_SEQ) * QKVW;
    #pragma unroll
    for (int d = 0; d < HS; ++d) {
        ks[t][d] = base[t * QKVW + 24 + h * HS + d];
        vs[t][d] = base[t * QKVW + 48 + h * HS + d];
    }
    __syncthreads();
    const float* qp = base + t * QKVW + h * HS;
    float q0 = qp[0], q1 = qp[1], q2 = qp[2], q3 = qp[3];
    const float scale = 0.05103103630798288f;   // 384^-0.5
    float m = -1e30f;
    for (int s = 0; s <= t; ++s) {
        float sc = (q0 * ks[s][0] + q1 * ks[s][1] + q2 * ks[s][2] + q3 * ks[s][3]) * scale;
        m = fmaxf(m, sc);
    }
    float sum = 0.f, o0 = 0.f, o1 = 0.f, o2 = 0.f, o3 = 0.f;
    for (int s = 0; s <= t; ++s) {
        float sc = (q0 * ks[s][0] + q1 * ks[s][1] + q2 * ks[s][2] + q3 * ks[s][3]) * scale;
        float p = __expf(sc - m);
        sum += p;
        o0 += p * vs[s][0]; o1 += p * vs[s][1]; o2 += p * vs[s][2]; o3 += p * vs[s][3];
    }
    float inv = 1.f / sum;
    float* out = attnT + (size_t)(b * T_SEQ + t) * (NH * HS) + h * HS;
    out[0] = o0 * inv; out[1] = o1 * inv; out[2] = o2 * inv; out[3] = o3 * inv;
}

// ---------------- proj
__global__ void proj_kernel(const float* __restrict__ attnT,
                            const float* __restrict__ Wproj,
                            const float* __restrict__ bproj,
                            bf16* __restrict__ x2) {
    __shared__ float as[NH * HS];
    int token = blockIdx.x;
    int c = threadIdx.x;           // 384 threads
    if (c < NH * HS) as[c] = attnT[(size_t)token * (NH * HS) + c];
    __syncthreads();
    float acc = bproj[c];
    #pragma unroll
    for (int j = 0; j < NH * HS; ++j) acc += as[j] * Wproj[j * C_EMB + c];
    x2[(size_t)token * C_EMB + c] = f2b(acc);
}

// ---------------- MFMA GEMM (m97-style): out[M,Nout] = [relu](A[M,K] @ Bt[Npad,K]^T + bias)
// global_load_lds 16B staging, unpadded [128][32] tiles. M%128==0, Npad%128==0, K%32==0.
__global__ __launch_bounds__(256)
void gemm_mfma_kernel(const bf16* __restrict__ A, const bf16* __restrict__ Bt,
                      const float* __restrict__ bias,
                      bf16* __restrict__ outb, float* __restrict__ outf,
                      int M, int Npad, int K, int Nout, int relu) {
    __shared__ short As[128][32];
    __shared__ short Bs[128][32];
    int tid  = threadIdx.x;
    int lane = tid & 63;
    int wave = tid >> 6;
    int bm = blockIdx.y * 128;
    int bn = blockIdx.x * 128;
    int wm = (wave & 1) * 64;
    int wn = (wave >> 1) * 64;
    int lrow  = lane & 15;
    int khalf = lane >> 4;

    f32x4 acc[4][4] = {};

    for (int k0 = 0; k0 < K; k0 += 32) {
        int c = tid;
        glds16(A  + (size_t)(bm + (c >> 2)) * K + k0 + (c & 3) * 8, (short*)As + (size_t)c * 8);
        glds16(Bt + (size_t)(bn + (c >> 2)) * K + k0 + (c & 3) * 8, (short*)Bs + (size_t)c * 8);
        c = tid + 256;
        glds16(A  + (size_t)(bm + (c >> 2)) * K + k0 + (c & 3) * 8, (short*)As + (size_t)c * 8);
        glds16(Bt + (size_t)(bn + (c >> 2)) * K + k0 + (c & 3) * 8, (short*)Bs + (size_t)c * 8);
        __syncthreads();

        bf16x8 af[4], bff[4];
        #pragma unroll
        for (int i = 0; i < 4; ++i) {
            af[i]  = *(const bf16x8*)&As[wm + i * 16 + lrow][khalf * 8];
            bff[i] = *(const bf16x8*)&Bs[wn + i * 16 + lrow][khalf * 8];
        }
        #pragma unroll
        for (int mi = 0; mi < 4; ++mi)
            #pragma unroll
            for (int ni = 0; ni < 4; ++ni)
                acc[mi][ni] = __builtin_amdgcn_mfma_f32_16x16x32_bf16(af[mi], bff[ni], acc[mi][ni], 0, 0, 0);
        __syncthreads();
    }

    // epilogue: C/D layout col=lane&15, row=(lane>>4)*4+r  [m89-verified]
    #pragma unroll
    for (int ni = 0; ni < 4; ++ni) {
        int col = bn + wn + ni * 16 + lrow;
        if (col >= Nout) continue;
        float bv = bias ? bias[col] : 0.f;
        #pragma unroll
        for (int mi = 0; mi < 4; ++mi) {
            int row = bm + wm + mi * 16 + khalf * 4;
            #pragma unroll
            for (int r = 0; r < 4; ++r) {
                float v = acc[mi][ni][r] + bv;
                if (relu) v = fmaxf(v, 0.f);
                if (outf) outf[(size_t)(row + r) * Nout + col] = v;
                else      outb[(size_t)(row + r) * Nout + col] = f2b(v);
            }
        }
    }
}

// ---------------- per-token CE loss
__global__ void loss_kernel(const float* __restrict__ logits,
                            const int* __restrict__ targets,
                            float* __restrict__ lossbuf) {
    int token = blockIdx.x;
    int v = threadIdx.x;           // 128 threads
    __shared__ float red[128];
    const float* lr = logits + (size_t)token * VOC;
    float val = (v < VOC) ? lr[v] : -1e30f;
    red[v] = val; __syncthreads();
    for (int s = 64; s > 0; s >>= 1) { if (v < s) red[v] = fmaxf(red[v], red[v + s]); __syncthreads(); }
    float mx = red[0]; __syncthreads();
    red[v] = (v < VOC) ? __expf(val - mx) : 0.f; __syncthreads();
    for (int s = 64; s > 0; s >>= 1) { if (v < s) red[v] += red[v + s]; __syncthreads(); }
    if (v == 0) {
        float lse = mx + logf(red[0]);
        lossbuf[token] = lse - lr[targets[token]];
    }
}

__global__ void loss_reduce_kernel(const float* __restrict__ lossbuf, float* __restrict__ out_loss) {
    __shared__ float red[256];
    int tid = threadIdx.x;
    float s = 0.f;
    for (int i = tid; i < NTOK; i += 256) s += lossbuf[i];
    red[tid] = s; __syncthreads();
    for (int st = 128; st > 0; st >>= 1) { if (tid < st) red[tid] += red[tid + st]; __syncthreads(); }
    if (tid == 0) out_loss[0] = red[0] / (float)NTOK;
}

extern "C" void kernel_launch(void* const* d_in, const int* in_sizes, int n_in,
                              void* d_out, int out_size, void* d_ws, size_t ws_size,
                              hipStream_t stream) {
    const int*   idx     = (const int*)  d_in[0];
    const int*   targets = (const int*)  d_in[1];
    const float* tok_emb = (const float*)d_in[2];
    const float* pos_emb = (const float*)d_in[3];
    const float* Wq      = (const float*)d_in[4];
    const float* Wk      = (const float*)d_in[5];
    const float* Wv      = (const float*)d_in[6];
    const float* Wproj   = (const float*)d_in[7];
    const float* bproj   = (const float*)d_in[8];
    const float* W1      = (const float*)d_in[9];
    const float* b1      = (const float*)d_in[10];
    const float* W2      = (const float*)d_in[11];
    const float* b2      = (const float*)d_in[12];
    const float* Wlm     = (const float*)d_in[13];
    const float* blm     = (const float*)d_in[14];

    char* ws = (char*)d_ws;
    float* qkvbuf = (float*)(ws + 25165824);                // 32768*72 f32 = 9437184 B
    float* attnT  = (float*)(ws + 34603008);                // 3145728 B
    bf16*  x2     = (bf16*) (ws + 37748736);                // 25165824 B
    bf16*  h1     = (bf16*) (ws + 62914560);                // 100663296 B
    bf16*  x3     = (bf16*) (ws + 163577856);               // 25165824 B
    float* lossbuf= (float*)(ws + 188743680);               // 131072 B
    bf16*  W1t    = (bf16*) (ws + 188874752);               // 1179648 B
    bf16*  W2t    = (bf16*) (ws + 190054400);               // 1179648 B
    bf16*  WqkvT  = (bf16*) (ws + 191234048);               // 98304 B
    bf16*  WlmT   = (bf16*) (ws + 191332352);               // 98304 B

    float* out_logits = (float*)d_out;                      // [32768*65] f32
    float* out_loss   = out_logits + (size_t)NTOK * VOC;    // [1]

    // weight packing (tiny, independent of activations)
    pack_qkv_kernel<<<128, 256, 0, stream>>>(Wq, Wk, Wv, WqkvT);
    pack_lm_kernel<<<128, 256, 0, stream>>>(Wlm, WlmT);
    convT_kernel<<<FFDIM, 256, 0, stream>>>(W1, W1t, C_EMB, FFDIM);   // [384,1536] -> [1536,384]
    convT_kernel<<<C_EMB, 256, 0, stream>>>(W2, W2t, FFDIM, C_EMB);   // [1536,384] -> [384,1536]

    // fused embed + QKV: -> qkvbuf f32 [32768,72]
    qkv_embed_mfma_kernel<<<NTOK / 128, 256, 0, stream>>>(idx, tok_emb, pos_emb, WqkvT, qkvbuf);
    attn_kernel<<<NB * NH, T_SEQ, 0, stream>>>(qkvbuf, attnT);
    proj_kernel<<<NTOK, C_EMB, 0, stream>>>(attnT, Wproj, bproj, x2);

    // FF1: [32768,384] @ [384,1536] + b1, relu -> h1 (bf16)
    gemm_mfma_kernel<<<dim3(FFDIM / 128, NTOK / 128), 256, 0, stream>>>(x2, W1t, b1, h1, nullptr,
                                                                        NTOK, FFDIM, C_EMB, FFDIM, 1);
    // FF2: [32768,1536] @ [1536,384] + b2 -> x3 (bf16)
    gemm_mfma_kernel<<<dim3(C_EMB / 128, NTOK / 128), 256, 0, stream>>>(h1, W2t, b2, x3, nullptr,
                                                                        NTOK, C_EMB, FFDIM, C_EMB, 0);
    // LM head: [32768,384] @ [384,65pad128] + blm -> f32 logits into d_out
    gemm_mfma_kernel<<<dim3(1, NTOK / 128), 256, 0, stream>>>(x3, WlmT, blm, nullptr, out_logits,
                                                              NTOK, 128, C_EMB, VOC, 0);

    loss_kernel<<<NTOK, 128, 0, stream>>>(out_logits, targets, lossbuf);
    loss_reduce_kernel<<<1, 256, 0, stream>>>(lossbuf, out_loss);
}

// Round 6
// 359.910 us; speedup vs baseline: 6.2053x; 1.1503x over previous
//
#include <hip/hip_runtime.h>
#include <hip/hip_bf16.h>
#include <math.h>

typedef __hip_bfloat16 bf16;
typedef __attribute__((ext_vector_type(8))) short bf16x8;
typedef __attribute__((ext_vector_type(4))) float f32x4;

#define T_SEQ   256
#define C_EMB   384
#define NH      6
#define HS      4
#define NB      128
#define NTOK    (NB * T_SEQ)   // 32768
#define VOC     65
#define FFDIM   1536
#define QKVW    72             // 3*NH*HS packed width
#define PROJK   32             // 24 padded to 32

__device__ __forceinline__ float b2f(bf16 x) { return __bfloat162float(x); }
__device__ __forceinline__ bf16  f2b(float x) { return __float2bfloat16(x); }
__device__ __forceinline__ short f2s(float x) { bf16 b = __float2bfloat16(x); return *reinterpret_cast<short*>(&b); }

// async 16B global->LDS (m97 path). Per-lane lds ptr = wave base + lane*16 (contiguous).
__device__ __forceinline__ void glds16(const void* g, short* l) {
    __builtin_amdgcn_global_load_lds((const __attribute__((address_space(1))) void*)g,
                                     (__attribute__((address_space(3))) void*)l, 16, 0, 0);
}

// ---------------- pack Wq|Wk|Wv [NH,C,HS] f32 -> WqkvT [128,384] bf16 (zero-pad n>=72)
__global__ void pack_qkv_kernel(const float* __restrict__ Wq, const float* __restrict__ Wk,
                                const float* __restrict__ Wv, bf16* __restrict__ Wt) {
    int n = blockIdx.x;            // 128
    for (int c = threadIdx.x; c < C_EMB; c += 256) {
        float v = 0.f;
        if (n < QKVW) {
            int sel = n / 24, r = n % 24, h = r >> 2, d = r & 3;
            const float* W = (sel == 0) ? Wq : (sel == 1) ? Wk : Wv;
            v = W[(h * C_EMB + c) * HS + d];
        }
        Wt[(size_t)n * C_EMB + c] = f2b(v);
    }
}

// ---------------- pack Wlm [C,VOC] f32 -> WlmT [128,384] bf16 (zero-pad n>=65)
__global__ void pack_lm_kernel(const float* __restrict__ Wlm, bf16* __restrict__ Wt) {
    int n = blockIdx.x;            // 128
    for (int c = threadIdx.x; c < C_EMB; c += 256)
        Wt[(size_t)n * C_EMB + c] = f2b(n < VOC ? Wlm[(size_t)c * VOC + n] : 0.f);
}

// ---------------- pack Wproj [24,384] f32 -> WprojT [384,32] bf16 (zero-pad k>=24)
__global__ void pack_proj_kernel(const float* __restrict__ Wproj, bf16* __restrict__ Wt) {
    int n = blockIdx.x;            // 384
    int k = threadIdx.x;           // 32
    Wt[(size_t)n * PROJK + k] = f2b(k < 24 ? Wproj[(size_t)k * C_EMB + n] : 0.f);
}

// ---------------- W [K,N] f32 -> W^T [N,K] bf16
__global__ void convT_kernel(const float* __restrict__ in, bf16* __restrict__ out, int K, int N) {
    int n = blockIdx.x;
    for (int k = threadIdx.x; k < K; k += 256)
        out[(size_t)n * K + k] = f2b(in[(size_t)k * N + n]);
}

// ---------------- fused embed + QKV GEMM: qkv[token,72] = (tok_emb[idx]+pos_emb) @ WqkvT^T
__global__ __launch_bounds__(256)
void qkv_embed_mfma_kernel(const int* __restrict__ idx,
                           const float* __restrict__ tok_emb,
                           const float* __restrict__ pos_emb,
                           const bf16* __restrict__ Bt,
                           float* __restrict__ outf) {
    __shared__ short As[128][32];
    __shared__ short Bs[128][32];
    __shared__ int ids[128];
    int tid = threadIdx.x, lane = tid & 63, wave = tid >> 6;
    int bm = blockIdx.x * 128;
    int wm = (wave & 1) * 64, wn = (wave >> 1) * 64;
    int lrow = lane & 15, khalf = lane >> 4;
    if (tid < 128) ids[tid] = idx[bm + tid];
    __syncthreads();
    int tbase = bm & (T_SEQ - 1);

    f32x4 acc[4][4] = {};
    for (int k0 = 0; k0 < C_EMB; k0 += 32) {
        #pragma unroll
        for (int h = 0; h < 2; ++h) {
            int c = tid + h * 256;
            int row = c >> 2, colc = k0 + (c & 3) * 8;
            const float* te = tok_emb + (size_t)ids[row] * C_EMB + colc;
            const float* pe = pos_emb + (size_t)(tbase + row) * C_EMB + colc;
            float4 t0 = *(const float4*)te, t1 = *(const float4*)(te + 4);
            float4 p0 = *(const float4*)pe, p1 = *(const float4*)(pe + 4);
            union { short s[8]; uint4 u; } r;
            r.s[0] = f2s(t0.x + p0.x); r.s[1] = f2s(t0.y + p0.y);
            r.s[2] = f2s(t0.z + p0.z); r.s[3] = f2s(t0.w + p0.w);
            r.s[4] = f2s(t1.x + p1.x); r.s[5] = f2s(t1.y + p1.y);
            r.s[6] = f2s(t1.z + p1.z); r.s[7] = f2s(t1.w + p1.w);
            *(uint4*)((short*)As + (size_t)c * 8) = r.u;
        }
        int c = tid;
        glds16(Bt + (size_t)(c >> 2) * C_EMB + k0 + (c & 3) * 8, (short*)Bs + (size_t)c * 8);
        c = tid + 256;
        glds16(Bt + (size_t)(c >> 2) * C_EMB + k0 + (c & 3) * 8, (short*)Bs + (size_t)c * 8);
        __syncthreads();

        bf16x8 af[4], bff[4];
        #pragma unroll
        for (int i = 0; i < 4; ++i) {
            af[i]  = *(const bf16x8*)&As[wm + i * 16 + lrow][khalf * 8];
            bff[i] = *(const bf16x8*)&Bs[wn + i * 16 + lrow][khalf * 8];
        }
        #pragma unroll
        for (int mi = 0; mi < 4; ++mi)
            #pragma unroll
            for (int ni = 0; ni < 4; ++ni)
                acc[mi][ni] = __builtin_amdgcn_mfma_f32_16x16x32_bf16(af[mi], bff[ni], acc[mi][ni], 0, 0, 0);
        __syncthreads();
    }

    #pragma unroll
    for (int ni = 0; ni < 4; ++ni) {
        int col = wn + ni * 16 + lrow;
        if (col >= QKVW) continue;
        #pragma unroll
        for (int mi = 0; mi < 4; ++mi) {
            int row = bm + wm + mi * 16 + khalf * 4;
            #pragma unroll
            for (int r = 0; r < 4; ++r)
                outf[(size_t)(row + r) * QKVW + col] = acc[mi][ni][r];
        }
    }
}

// ---------------- causal softmax attention (single-pass online); writes bf16 attnT[token][32]
__global__ void attn_kernel(const float* __restrict__ qkv,
                            bf16* __restrict__ attnT) {
    int bh = blockIdx.x;
    int b = bh / NH, h = bh % NH;
    int t = threadIdx.x;           // 256 threads
    __shared__ float ks[T_SEQ][HS];
    __shared__ float vs[T_SEQ][HS];
    const float* base = qkv + (size_t)(b * T_SEQ) * QKVW;
    #pragma unroll
    for (int d = 0; d < HS; ++d) {
        ks[t][d] = base[t * QKVW + 24 + h * HS + d];
        vs[t][d] = base[t * QKVW + 48 + h * HS + d];
    }
    __syncthreads();
    const float* qp = base + t * QKVW + h * HS;
    float q0 = qp[0], q1 = qp[1], q2 = qp[2], q3 = qp[3];
    const float scale = 0.05103103630798288f;   // 384^-0.5
    float m = -1e30f, sum = 0.f, o0 = 0.f, o1 = 0.f, o2 = 0.f, o3 = 0.f;
    for (int s = 0; s <= t; ++s) {
        float sc = (q0 * ks[s][0] + q1 * ks[s][1] + q2 * ks[s][2] + q3 * ks[s][3]) * scale;
        float mn = fmaxf(m, sc);
        float alpha = __expf(m - mn);
        float p = __expf(sc - mn);
        sum = sum * alpha + p;
        o0 = o0 * alpha + p * vs[s][0];
        o1 = o1 * alpha + p * vs[s][1];
        o2 = o2 * alpha + p * vs[s][2];
        o3 = o3 * alpha + p * vs[s][3];
        m = mn;
    }
    float inv = 1.f / sum;
    bf16* out = attnT + (size_t)(b * T_SEQ + t) * PROJK + h * HS;
    out[0] = f2b(o0 * inv); out[1] = f2b(o1 * inv); out[2] = f2b(o2 * inv); out[3] = f2b(o3 * inv);
    if (h == 0) {   // zero-pad cols 24..31 once per token
        bf16* pad = attnT + (size_t)(b * T_SEQ + t) * PROJK + 24;
        *(uint4*)pad = uint4{0, 0, 0, 0};
    }
}

// ---------------- MFMA GEMM, BK=32 (for K%32==0, small K): out = [relu](A @ Bt^T + bias)
__global__ __launch_bounds__(256)
void gemm_mfma32_kernel(const bf16* __restrict__ A, const bf16* __restrict__ Bt,
                        const float* __restrict__ bias,
                        bf16* __restrict__ outb, float* __restrict__ outf,
                        int M, int Npad, int K, int Nout, int relu) {
    __shared__ short As[128][32];
    __shared__ short Bs[128][32];
    int tid  = threadIdx.x;
    int lane = tid & 63;
    int wave = tid >> 6;
    int bm = blockIdx.y * 128;
    int bn = blockIdx.x * 128;
    int wm = (wave & 1) * 64;
    int wn = (wave >> 1) * 64;
    int lrow  = lane & 15;
    int khalf = lane >> 4;

    f32x4 acc[4][4] = {};
    for (int k0 = 0; k0 < K; k0 += 32) {
        int c = tid;
        glds16(A  + (size_t)(bm + (c >> 2)) * K + k0 + (c & 3) * 8, (short*)As + (size_t)c * 8);
        glds16(Bt + (size_t)(bn + (c >> 2)) * K + k0 + (c & 3) * 8, (short*)Bs + (size_t)c * 8);
        c = tid + 256;
        glds16(A  + (size_t)(bm + (c >> 2)) * K + k0 + (c & 3) * 8, (short*)As + (size_t)c * 8);
        glds16(Bt + (size_t)(bn + (c >> 2)) * K + k0 + (c & 3) * 8, (short*)Bs + (size_t)c * 8);
        __syncthreads();

        bf16x8 af[4], bff[4];
        #pragma unroll
        for (int i = 0; i < 4; ++i) {
            af[i]  = *(const bf16x8*)&As[wm + i * 16 + lrow][khalf * 8];
            bff[i] = *(const bf16x8*)&Bs[wn + i * 16 + lrow][khalf * 8];
        }
        #pragma unroll
        for (int mi = 0; mi < 4; ++mi)
            #pragma unroll
            for (int ni = 0; ni < 4; ++ni)
                acc[mi][ni] = __builtin_amdgcn_mfma_f32_16x16x32_bf16(af[mi], bff[ni], acc[mi][ni], 0, 0, 0);
        __syncthreads();
    }

    #pragma unroll
    for (int ni = 0; ni < 4; ++ni) {
        int col = bn + wn + ni * 16 + lrow;
        if (col >= Nout) continue;
        float bv = bias ? bias[col] : 0.f;
        #pragma unroll
        for (int mi = 0; mi < 4; ++mi) {
            int row = bm + wm + mi * 16 + khalf * 4;
            #pragma unroll
            for (int r = 0; r < 4; ++r) {
                float v = acc[mi][ni][r] + bv;
                if (relu) v = fmaxf(v, 0.f);
                if (outf) outf[(size_t)(row + r) * Nout + col] = v;
                else      outb[(size_t)(row + r) * Nout + col] = f2b(v);
            }
        }
    }
}

// ---------------- MFMA GEMM, BK=64: 32 MFMA per barrier pair (halved barrier drains). K%64==0.
__global__ __launch_bounds__(256)
void gemm_mfma64_kernel(const bf16* __restrict__ A, const bf16* __restrict__ Bt,
                        const float* __restrict__ bias,
                        bf16* __restrict__ outb, float* __restrict__ outf,
                        int M, int Npad, int K, int Nout, int relu) {
    __shared__ short As[2][128][32];   // [step][row][k] -- step = k-halves of the 64-wide slab
    __shared__ short Bs[2][128][32];
    int tid  = threadIdx.x;
    int lane = tid & 63;
    int wave = tid >> 6;
    int bm = blockIdx.y * 128;
    int bn = blockIdx.x * 128;
    int wm = (wave & 1) * 64;
    int wn = (wave >> 1) * 64;
    int lrow  = lane & 15;
    int khalf = lane >> 4;

    f32x4 acc[4][4] = {};
    for (int k0 = 0; k0 < K; k0 += 64) {
        #pragma unroll
        for (int st = 0; st < 2; ++st) {
            #pragma unroll
            for (int i = 0; i < 2; ++i) {
                int c = tid + i * 256;
                const bf16* Ag = A  + (size_t)(bm + (c >> 2)) * K + k0 + st * 32 + (c & 3) * 8;
                const bf16* Bg = Bt + (size_t)(bn + (c >> 2)) * K + k0 + st * 32 + (c & 3) * 8;
                glds16(Ag, (short*)As[st] + (size_t)c * 8);
                glds16(Bg, (short*)Bs[st] + (size_t)c * 8);
            }
        }
        __syncthreads();

        #pragma unroll
        for (int st = 0; st < 2; ++st) {
            bf16x8 af[4], bff[4];
            #pragma unroll
            for (int i = 0; i < 4; ++i) {
                af[i]  = *(const bf16x8*)&As[st][wm + i * 16 + lrow][khalf * 8];
                bff[i] = *(const bf16x8*)&Bs[st][wn + i * 16 + lrow][khalf * 8];
            }
            #pragma unroll
            for (int mi = 0; mi < 4; ++mi)
                #pragma unroll
                for (int ni = 0; ni < 4; ++ni)
                    acc[mi][ni] = __builtin_amdgcn_mfma_f32_16x16x32_bf16(af[mi], bff[ni], acc[mi][ni], 0, 0, 0);
        }
        __syncthreads();
    }

    #pragma unroll
    for (int ni = 0; ni < 4; ++ni) {
        int col = bn + wn + ni * 16 + lrow;
        if (col >= Nout) continue;
        float bv = bias ? bias[col] : 0.f;
        #pragma unroll
        for (int mi = 0; mi < 4; ++mi) {
            int row = bm + wm + mi * 16 + khalf * 4;
            #pragma unroll
            for (int r = 0; r < 4; ++r) {
                float v = acc[mi][ni][r] + bv;
                if (relu) v = fmaxf(v, 0.f);
                if (outf) outf[(size_t)(row + r) * Nout + col] = v;
                else      outb[(size_t)(row + r) * Nout + col] = f2b(v);
            }
        }
    }
}

// ---------------- per-token CE loss: one wave per token, shuffle-only
__global__ __launch_bounds__(256)
void loss_kernel(const float* __restrict__ logits,
                 const int* __restrict__ targets,
                 float* __restrict__ lossbuf) {
    int lane = threadIdx.x & 63;
    int token = blockIdx.x * 4 + (threadIdx.x >> 6);
    const float* lr = logits + (size_t)token * VOC;
    float v0 = lr[lane];
    float v64 = (lane == 0) ? lr[64] : -1e30f;
    float m = fmaxf(v0, v64);
    #pragma unroll
    for (int s = 32; s > 0; s >>= 1) m = fmaxf(m, __shfl_xor(m, s));
    int t = targets[token];
    float sum = __expf(v0 - m) + ((lane == 0) ? __expf(v64 - m) : 0.f);
    float tv  = (lane == t) ? v0 : ((lane == 0 && t == 64) ? v64 : 0.f);
    #pragma unroll
    for (int s = 32; s > 0; s >>= 1) { sum += __shfl_xor(sum, s); tv += __shfl_xor(tv, s); }
    if (lane == 0) lossbuf[token] = m + logf(sum) - tv;
}

__global__ void loss_reduce_kernel(const float* __restrict__ lossbuf, float* __restrict__ out_loss) {
    __shared__ float red[256];
    int tid = threadIdx.x;
    float s = 0.f;
    for (int i = tid; i < NTOK; i += 256) s += lossbuf[i];
    red[tid] = s; __syncthreads();
    for (int st = 128; st > 0; st >>= 1) { if (tid < st) red[tid] += red[tid + st]; __syncthreads(); }
    if (tid == 0) out_loss[0] = red[0] / (float)NTOK;
}

extern "C" void kernel_launch(void* const* d_in, const int* in_sizes, int n_in,
                              void* d_out, int out_size, void* d_ws, size_t ws_size,
                              hipStream_t stream) {
    const int*   idx     = (const int*)  d_in[0];
    const int*   targets = (const int*)  d_in[1];
    const float* tok_emb = (const float*)d_in[2];
    const float* pos_emb = (const float*)d_in[3];
    const float* Wq      = (const float*)d_in[4];
    const float* Wk      = (const float*)d_in[5];
    const float* Wv      = (const float*)d_in[6];
    const float* Wproj   = (const float*)d_in[7];
    const float* bproj   = (const float*)d_in[8];
    const float* W1      = (const float*)d_in[9];
    const float* b1      = (const float*)d_in[10];
    const float* W2      = (const float*)d_in[11];
    const float* b2      = (const float*)d_in[12];
    const float* Wlm     = (const float*)d_in[13];
    const float* blm     = (const float*)d_in[14];

    char* ws = (char*)d_ws;
    bf16*  WprojT = (bf16*) (ws + 0);                       // 384*32*2 = 24576 B (reuses old x slot)
    float* qkvbuf = (float*)(ws + 25165824);                // 32768*72 f32 = 9437184 B
    bf16*  attnT  = (bf16*) (ws + 34603008);                // 32768*32 bf16 = 2097152 B
    bf16*  x2     = (bf16*) (ws + 37748736);                // 25165824 B
    bf16*  h1     = (bf16*) (ws + 62914560);                // 100663296 B
    bf16*  x3     = (bf16*) (ws + 163577856);               // 25165824 B
    float* lossbuf= (float*)(ws + 188743680);               // 131072 B
    bf16*  W1t    = (bf16*) (ws + 188874752);               // 1179648 B
    bf16*  W2t    = (bf16*) (ws + 190054400);               // 1179648 B
    bf16*  WqkvT  = (bf16*) (ws + 191234048);               // 98304 B
    bf16*  WlmT   = (bf16*) (ws + 191332352);               // 98304 B

    float* out_logits = (float*)d_out;                      // [32768*65] f32
    float* out_loss   = out_logits + (size_t)NTOK * VOC;    // [1]

    // weight packing (tiny, independent of activations)
    pack_qkv_kernel<<<128, 256, 0, stream>>>(Wq, Wk, Wv, WqkvT);
    pack_lm_kernel<<<128, 256, 0, stream>>>(Wlm, WlmT);
    pack_proj_kernel<<<384, 32, 0, stream>>>(Wproj, WprojT);
    convT_kernel<<<FFDIM, 256, 0, stream>>>(W1, W1t, C_EMB, FFDIM);   // [384,1536] -> [1536,384]
    convT_kernel<<<C_EMB, 256, 0, stream>>>(W2, W2t, FFDIM, C_EMB);   // [1536,384] -> [384,1536]

    // fused embed + QKV: -> qkvbuf f32 [32768,72]
    qkv_embed_mfma_kernel<<<NTOK / 128, 256, 0, stream>>>(idx, tok_emb, pos_emb, WqkvT, qkvbuf);
    attn_kernel<<<NB * NH, T_SEQ, 0, stream>>>(qkvbuf, attnT);

    // proj: [32768,32] @ [32,384pad] + bproj -> x2 (bf16), 1 K-iter MFMA
    gemm_mfma32_kernel<<<dim3(C_EMB / 128, NTOK / 128), 256, 0, stream>>>(attnT, WprojT, bproj,
                                                                          x2, nullptr,
                                                                          NTOK, C_EMB, PROJK, C_EMB, 0);
    // FF1: [32768,384] @ [384,1536] + b1, relu -> h1 (bf16)
    gemm_mfma64_kernel<<<dim3(FFDIM / 128, NTOK / 128), 256, 0, stream>>>(x2, W1t, b1, h1, nullptr,
                                                                          NTOK, FFDIM, C_EMB, FFDIM, 1);
    // FF2: [32768,1536] @ [1536,384] + b2 -> x3 (bf16)
    gemm_mfma64_kernel<<<dim3(C_EMB / 128, NTOK / 128), 256, 0, stream>>>(h1, W2t, b2, x3, nullptr,
                                                                          NTOK, C_EMB, FFDIM, C_EMB, 0);
    // LM head: [32768,384] @ [384,65pad128] + blm -> f32 logits into d_out
    gemm_mfma64_kernel<<<dim3(1, NTOK / 128), 256, 0, stream>>>(x3, WlmT, blm, nullptr, out_logits,
                                                                NTOK, 128, C_EMB, VOC, 0);

    loss_kernel<<<NTOK / 4, 256, 0, stream>>>(out_logits, targets, lossbuf);
    loss_reduce_kernel<<<1, 256, 0, stream>>>(lossbuf, out_loss);
}

// Round 7
// 335.095 us; speedup vs baseline: 6.6648x; 1.0741x over previous
//
#include <hip/hip_runtime.h>
#include <hip/hip_bf16.h>
#include <math.h>

typedef __hip_bfloat16 bf16;
typedef __attribute__((ext_vector_type(8))) short bf16x8;
typedef __attribute__((ext_vector_type(4))) float f32x4;

#define T_SEQ   256
#define C_EMB   384
#define NH      6
#define HS      4
#define NB      128
#define NTOK    (NB * T_SEQ)   // 32768
#define VOC     65
#define FFDIM   1536
#define QKVW    72             // 3*NH*HS packed width
#define PROJK   32             // 24 padded to 32

__device__ __forceinline__ float b2f(bf16 x) { return __bfloat162float(x); }
__device__ __forceinline__ bf16  f2b(float x) { return __float2bfloat16(x); }
__device__ __forceinline__ short f2s(float x) { bf16 b = __float2bfloat16(x); return *reinterpret_cast<short*>(&b); }

// async 16B global->LDS (m97 path). Per-lane lds ptr = wave base + lane*16 (contiguous).
__device__ __forceinline__ void glds16(const void* g, short* l) {
    __builtin_amdgcn_global_load_lds((const __attribute__((address_space(1))) void*)g,
                                     (__attribute__((address_space(3))) void*)l, 16, 0, 0);
}

// ---------------- all weight packing in ONE dispatch (2560 blocks x 256)
__global__ void pack_all_kernel(const float* __restrict__ Wq, const float* __restrict__ Wk,
                                const float* __restrict__ Wv, const float* __restrict__ Wlm,
                                const float* __restrict__ Wproj,
                                const float* __restrict__ W1, const float* __restrict__ W2,
                                bf16* __restrict__ WqkvT, bf16* __restrict__ WlmT,
                                bf16* __restrict__ WprojT, bf16* __restrict__ W1t,
                                bf16* __restrict__ W2t) {
    int blk = blockIdx.x;
    if (blk < 128) {                                   // WqkvT [128,384]
        int n = blk;
        for (int c = threadIdx.x; c < C_EMB; c += 256) {
            float v = 0.f;
            if (n < QKVW) {
                int sel = n / 24, r = n % 24, h = r >> 2, d = r & 3;
                const float* W = (sel == 0) ? Wq : (sel == 1) ? Wk : Wv;
                v = W[(h * C_EMB + c) * HS + d];
            }
            WqkvT[(size_t)n * C_EMB + c] = f2b(v);
        }
    } else if (blk < 256) {                            // WlmT [128,384]
        int n = blk - 128;
        for (int c = threadIdx.x; c < C_EMB; c += 256)
            WlmT[(size_t)n * C_EMB + c] = f2b(n < VOC ? Wlm[(size_t)c * VOC + n] : 0.f);
    } else if (blk < 640) {                            // WprojT [384,32]
        int n = blk - 256;
        int k = threadIdx.x;
        if (k < PROJK)
            WprojT[(size_t)n * PROJK + k] = f2b(k < 24 ? Wproj[(size_t)k * C_EMB + n] : 0.f);
    } else if (blk < 640 + FFDIM) {                    // W1t [1536,384]
        int n = blk - 640;
        for (int k = threadIdx.x; k < C_EMB; k += 256)
            W1t[(size_t)n * C_EMB + k] = f2b(W1[(size_t)k * FFDIM + n]);
    } else {                                           // W2t [384,1536]
        int n = blk - 640 - FFDIM;
        for (int k = threadIdx.x; k < FFDIM; k += 256)
            W2t[(size_t)n * FFDIM + k] = f2b(W2[(size_t)k * C_EMB + n]);
    }
}

// ---------------- fused embed + QKV GEMM: qkv[token,72] = (tok_emb[idx]+pos_emb) @ WqkvT^T
__global__ __launch_bounds__(256)
void qkv_embed_mfma_kernel(const int* __restrict__ idx,
                           const float* __restrict__ tok_emb,
                           const float* __restrict__ pos_emb,
                           const bf16* __restrict__ Bt,
                           float* __restrict__ outf) {
    __shared__ short As[128][32];
    __shared__ short Bs[128][32];
    __shared__ int ids[128];
    int tid = threadIdx.x, lane = tid & 63, wave = tid >> 6;
    int bm = blockIdx.x * 128;
    int wm = (wave & 1) * 64, wn = (wave >> 1) * 64;
    int lrow = lane & 15, khalf = lane >> 4;
    if (tid < 128) ids[tid] = idx[bm + tid];
    __syncthreads();
    int tbase = bm & (T_SEQ - 1);

    f32x4 acc[4][4] = {};
    for (int k0 = 0; k0 < C_EMB; k0 += 32) {
        #pragma unroll
        for (int h = 0; h < 2; ++h) {
            int c = tid + h * 256;
            int row = c >> 2, colc = k0 + (c & 3) * 8;
            const float* te = tok_emb + (size_t)ids[row] * C_EMB + colc;
            const float* pe = pos_emb + (size_t)(tbase + row) * C_EMB + colc;
            float4 t0 = *(const float4*)te, t1 = *(const float4*)(te + 4);
            float4 p0 = *(const float4*)pe, p1 = *(const float4*)(pe + 4);
            union { short s[8]; uint4 u; } r;
            r.s[0] = f2s(t0.x + p0.x); r.s[1] = f2s(t0.y + p0.y);
            r.s[2] = f2s(t0.z + p0.z); r.s[3] = f2s(t0.w + p0.w);
            r.s[4] = f2s(t1.x + p1.x); r.s[5] = f2s(t1.y + p1.y);
            r.s[6] = f2s(t1.z + p1.z); r.s[7] = f2s(t1.w + p1.w);
            *(uint4*)((short*)As + (size_t)c * 8) = r.u;
        }
        int c = tid;
        glds16(Bt + (size_t)(c >> 2) * C_EMB + k0 + (c & 3) * 8, (short*)Bs + (size_t)c * 8);
        c = tid + 256;
        glds16(Bt + (size_t)(c >> 2) * C_EMB + k0 + (c & 3) * 8, (short*)Bs + (size_t)c * 8);
        __syncthreads();

        bf16x8 af[4], bff[4];
        #pragma unroll
        for (int i = 0; i < 4; ++i) {
            af[i]  = *(const bf16x8*)&As[wm + i * 16 + lrow][khalf * 8];
            bff[i] = *(const bf16x8*)&Bs[wn + i * 16 + lrow][khalf * 8];
        }
        #pragma unroll
        for (int mi = 0; mi < 4; ++mi)
            #pragma unroll
            for (int ni = 0; ni < 4; ++ni)
                acc[mi][ni] = __builtin_amdgcn_mfma_f32_16x16x32_bf16(af[mi], bff[ni], acc[mi][ni], 0, 0, 0);
        __syncthreads();
    }

    #pragma unroll
    for (int ni = 0; ni < 4; ++ni) {
        int col = wn + ni * 16 + lrow;
        if (col >= QKVW) continue;
        #pragma unroll
        for (int mi = 0; mi < 4; ++mi) {
            int row = bm + wm + mi * 16 + khalf * 4;
            #pragma unroll
            for (int r = 0; r < 4; ++r)
                outf[(size_t)(row + r) * QKVW + col] = acc[mi][ni][r];
        }
    }
}

// ---------------- causal softmax attention (single-pass online); writes bf16 attnT[token][32]
__global__ void attn_kernel(const float* __restrict__ qkv,
                            bf16* __restrict__ attnT) {
    int bh = blockIdx.x;
    int b = bh / NH, h = bh % NH;
    int t = threadIdx.x;           // 256 threads
    __shared__ float ks[T_SEQ][HS];
    __shared__ float vs[T_SEQ][HS];
    const float* base = qkv + (size_t)(b * T_SEQ) * QKVW;
    #pragma unroll
    for (int d = 0; d < HS; ++d) {
        ks[t][d] = base[t * QKVW + 24 + h * HS + d];
        vs[t][d] = base[t * QKVW + 48 + h * HS + d];
    }
    __syncthreads();
    const float* qp = base + t * QKVW + h * HS;
    float q0 = qp[0], q1 = qp[1], q2 = qp[2], q3 = qp[3];
    const float scale = 0.05103103630798288f;   // 384^-0.5
    float m = -1e30f, sum = 0.f, o0 = 0.f, o1 = 0.f, o2 = 0.f, o3 = 0.f;
    for (int s = 0; s <= t; ++s) {
        float sc = (q0 * ks[s][0] + q1 * ks[s][1] + q2 * ks[s][2] + q3 * ks[s][3]) * scale;
        float mn = fmaxf(m, sc);
        float alpha = __expf(m - mn);
        float p = __expf(sc - mn);
        sum = sum * alpha + p;
        o0 = o0 * alpha + p * vs[s][0];
        o1 = o1 * alpha + p * vs[s][1];
        o2 = o2 * alpha + p * vs[s][2];
        o3 = o3 * alpha + p * vs[s][3];
        m = mn;
    }
    float inv = 1.f / sum;
    bf16* out = attnT + (size_t)(b * T_SEQ + t) * PROJK + h * HS;
    out[0] = f2b(o0 * inv); out[1] = f2b(o1 * inv); out[2] = f2b(o2 * inv); out[3] = f2b(o3 * inv);
    if (h == 0) {   // zero-pad cols 24..31 once per token
        bf16* pad = attnT + (size_t)(b * T_SEQ + t) * PROJK + 24;
        *(uint4*)pad = uint4{0, 0, 0, 0};
    }
}

// ---------------- MFMA GEMM, BK=32, 256 threads (proj: K=32, 1 iter)
__global__ __launch_bounds__(256)
void gemm_mfma32_kernel(const bf16* __restrict__ A, const bf16* __restrict__ Bt,
                        const float* __restrict__ bias,
                        bf16* __restrict__ outb, float* __restrict__ outf,
                        int M, int Npad, int K, int Nout, int relu) {
    __shared__ short As[128][32];
    __shared__ short Bs[128][32];
    int tid  = threadIdx.x;
    int lane = tid & 63;
    int wave = tid >> 6;
    int bm = blockIdx.y * 128;
    int bn = blockIdx.x * 128;
    int wm = (wave & 1) * 64;
    int wn = (wave >> 1) * 64;
    int lrow  = lane & 15;
    int khalf = lane >> 4;

    f32x4 acc[4][4] = {};
    for (int k0 = 0; k0 < K; k0 += 32) {
        int c = tid;
        glds16(A  + (size_t)(bm + (c >> 2)) * K + k0 + (c & 3) * 8, (short*)As + (size_t)c * 8);
        glds16(Bt + (size_t)(bn + (c >> 2)) * K + k0 + (c & 3) * 8, (short*)Bs + (size_t)c * 8);
        c = tid + 256;
        glds16(A  + (size_t)(bm + (c >> 2)) * K + k0 + (c & 3) * 8, (short*)As + (size_t)c * 8);
        glds16(Bt + (size_t)(bn + (c >> 2)) * K + k0 + (c & 3) * 8, (short*)Bs + (size_t)c * 8);
        __syncthreads();

        bf16x8 af[4], bff[4];
        #pragma unroll
        for (int i = 0; i < 4; ++i) {
            af[i]  = *(const bf16x8*)&As[wm + i * 16 + lrow][khalf * 8];
            bff[i] = *(const bf16x8*)&Bs[wn + i * 16 + lrow][khalf * 8];
        }
        #pragma unroll
        for (int mi = 0; mi < 4; ++mi)
            #pragma unroll
            for (int ni = 0; ni < 4; ++ni)
                acc[mi][ni] = __builtin_amdgcn_mfma_f32_16x16x32_bf16(af[mi], bff[ni], acc[mi][ni], 0, 0, 0);
        __syncthreads();
    }

    #pragma unroll
    for (int ni = 0; ni < 4; ++ni) {
        int col = bn + wn + ni * 16 + lrow;
        if (col >= Nout) continue;
        float bv = bias ? bias[col] : 0.f;
        #pragma unroll
        for (int mi = 0; mi < 4; ++mi) {
            int row = bm + wm + mi * 16 + khalf * 4;
            #pragma unroll
            for (int r = 0; r < 4; ++r) {
                float v = acc[mi][ni][r] + bv;
                if (relu) v = fmaxf(v, 0.f);
                if (outf) outf[(size_t)(row + r) * Nout + col] = v;
                else      outb[(size_t)(row + r) * Nout + col] = f2b(v);
            }
        }
    }
}

// ---------------- MFMA GEMM, BK=64, 512 threads / 8 waves (occupancy: ~24 waves/CU).
// Each wave: 64x32 output = 4x2 tiles of 16x16 (32 AGPR). K%64==0.
__global__ __launch_bounds__(512)
void gemm_mfma512_kernel(const bf16* __restrict__ A, const bf16* __restrict__ Bt,
                         const float* __restrict__ bias,
                         bf16* __restrict__ outb, float* __restrict__ outf,
                         int M, int Npad, int K, int Nout, int relu) {
    __shared__ short As[2][128][32];   // [k-half][row][k32]
    __shared__ short Bs[2][128][32];
    int tid  = threadIdx.x;
    int lane = tid & 63;
    int wave = tid >> 6;               // 0..7
    int bm = blockIdx.y * 128;
    int bn = blockIdx.x * 128;
    int wm = (wave & 1) * 64;
    int wn = (wave >> 1) * 32;         // 0,32,64,96
    int lrow  = lane & 15;
    int khalf = lane >> 4;

    f32x4 acc[4][2] = {};
    int row = tid >> 2, off = (tid & 3) * 8;   // 512 threads = one full [128][32] plane

    for (int k0 = 0; k0 < K; k0 += 64) {
        const bf16* Ag = A  + (size_t)(bm + row) * K + k0 + off;
        const bf16* Bg = Bt + (size_t)(bn + row) * K + k0 + off;
        glds16(Ag,      (short*)As[0] + (size_t)tid * 8);
        glds16(Ag + 32, (short*)As[1] + (size_t)tid * 8);
        glds16(Bg,      (short*)Bs[0] + (size_t)tid * 8);
        glds16(Bg + 32, (short*)Bs[1] + (size_t)tid * 8);
        __syncthreads();

        #pragma unroll
        for (int st = 0; st < 2; ++st) {
            bf16x8 af[4], bff[2];
            #pragma unroll
            for (int i = 0; i < 4; ++i)
                af[i] = *(const bf16x8*)&As[st][wm + i * 16 + lrow][khalf * 8];
            #pragma unroll
            for (int i = 0; i < 2; ++i)
                bff[i] = *(const bf16x8*)&Bs[st][wn + i * 16 + lrow][khalf * 8];
            #pragma unroll
            for (int mi = 0; mi < 4; ++mi)
                #pragma unroll
                for (int ni = 0; ni < 2; ++ni)
                    acc[mi][ni] = __builtin_amdgcn_mfma_f32_16x16x32_bf16(af[mi], bff[ni], acc[mi][ni], 0, 0, 0);
        }
        __syncthreads();
    }

    #pragma unroll
    for (int ni = 0; ni < 2; ++ni) {
        int col = bn + wn + ni * 16 + lrow;
        if (col >= Nout) continue;
        float bv = bias ? bias[col] : 0.f;
        #pragma unroll
        for (int mi = 0; mi < 4; ++mi) {
            int orow = bm + wm + mi * 16 + khalf * 4;
            #pragma unroll
            for (int r = 0; r < 4; ++r) {
                float v = acc[mi][ni][r] + bv;
                if (relu) v = fmaxf(v, 0.f);
                if (outf) outf[(size_t)(orow + r) * Nout + col] = v;
                else      outb[(size_t)(orow + r) * Nout + col] = f2b(v);
            }
        }
    }
}

// ---------------- per-token CE loss: one wave per token, shuffle-only
__global__ __launch_bounds__(256)
void loss_kernel(const float* __restrict__ logits,
                 const int* __restrict__ targets,
                 float* __restrict__ lossbuf) {
    int lane = threadIdx.x & 63;
    int token = blockIdx.x * 4 + (threadIdx.x >> 6);
    const float* lr = logits + (size_t)token * VOC;
    float v0 = lr[lane];
    float v64 = (lane == 0) ? lr[64] : -1e30f;
    float m = fmaxf(v0, v64);
    #pragma unroll
    for (int s = 32; s > 0; s >>= 1) m = fmaxf(m, __shfl_xor(m, s));
    int t = targets[token];
    float sum = __expf(v0 - m) + ((lane == 0) ? __expf(v64 - m) : 0.f);
    float tv  = (lane == t) ? v0 : ((lane == 0 && t == 64) ? v64 : 0.f);
    #pragma unroll
    for (int s = 32; s > 0; s >>= 1) { sum += __shfl_xor(sum, s); tv += __shfl_xor(tv, s); }
    if (lane == 0) lossbuf[token] = m + logf(sum) - tv;
}

__global__ void loss_reduce_kernel(const float* __restrict__ lossbuf, float* __restrict__ out_loss) {
    __shared__ float red[256];
    int tid = threadIdx.x;
    float s = 0.f;
    for (int i = tid; i < NTOK; i += 256) s += lossbuf[i];
    red[tid] = s; __syncthreads();
    for (int st = 128; st > 0; st >>= 1) { if (tid < st) red[tid] += red[tid + st]; __syncthreads(); }
    if (tid == 0) out_loss[0] = red[0] / (float)NTOK;
}

extern "C" void kernel_launch(void* const* d_in, const int* in_sizes, int n_in,
                              void* d_out, int out_size, void* d_ws, size_t ws_size,
                              hipStream_t stream) {
    const int*   idx     = (const int*)  d_in[0];
    const int*   targets = (const int*)  d_in[1];
    const float* tok_emb = (const float*)d_in[2];
    const float* pos_emb = (const float*)d_in[3];
    const float* Wq      = (const float*)d_in[4];
    const float* Wk      = (const float*)d_in[5];
    const float* Wv      = (const float*)d_in[6];
    const float* Wproj   = (const float*)d_in[7];
    const float* bproj   = (const float*)d_in[8];
    const float* W1      = (const float*)d_in[9];
    const float* b1      = (const float*)d_in[10];
    const float* W2      = (const float*)d_in[11];
    const float* b2      = (const float*)d_in[12];
    const float* Wlm     = (const float*)d_in[13];
    const float* blm     = (const float*)d_in[14];

    char* ws = (char*)d_ws;
    bf16*  WprojT = (bf16*) (ws + 0);                       // 24576 B
    float* qkvbuf = (float*)(ws + 25165824);                // 9437184 B
    bf16*  attnT  = (bf16*) (ws + 34603008);                // 2097152 B
    bf16*  x2     = (bf16*) (ws + 37748736);                // 25165824 B
    bf16*  h1     = (bf16*) (ws + 62914560);                // 100663296 B
    bf16*  x3     = (bf16*) (ws + 163577856);               // 25165824 B
    float* lossbuf= (float*)(ws + 188743680);               // 131072 B
    bf16*  W1t    = (bf16*) (ws + 188874752);               // 1179648 B
    bf16*  W2t    = (bf16*) (ws + 190054400);               // 1179648 B
    bf16*  WqkvT  = (bf16*) (ws + 191234048);               // 98304 B
    bf16*  WlmT   = (bf16*) (ws + 191332352);               // 98304 B

    float* out_logits = (float*)d_out;                      // [32768*65] f32
    float* out_loss   = out_logits + (size_t)NTOK * VOC;    // [1]

    // all weight packing in one dispatch
    pack_all_kernel<<<640 + FFDIM + C_EMB, 256, 0, stream>>>(Wq, Wk, Wv, Wlm, Wproj, W1, W2,
                                                             WqkvT, WlmT, WprojT, W1t, W2t);

    // fused embed + QKV: -> qkvbuf f32 [32768,72]
    qkv_embed_mfma_kernel<<<NTOK / 128, 256, 0, stream>>>(idx, tok_emb, pos_emb, WqkvT, qkvbuf);
    attn_kernel<<<NB * NH, T_SEQ, 0, stream>>>(qkvbuf, attnT);

    // proj: [32768,32] @ [32,384pad] + bproj -> x2 (bf16), 1 K-iter MFMA
    gemm_mfma32_kernel<<<dim3(C_EMB / 128, NTOK / 128), 256, 0, stream>>>(attnT, WprojT, bproj,
                                                                          x2, nullptr,
                                                                          NTOK, C_EMB, PROJK, C_EMB, 0);
    // FF1: [32768,384] @ [384,1536] + b1, relu -> h1 (bf16)
    gemm_mfma512_kernel<<<dim3(FFDIM / 128, NTOK / 128), 512, 0, stream>>>(x2, W1t, b1, h1, nullptr,
                                                                           NTOK, FFDIM, C_EMB, FFDIM, 1);
    // FF2: [32768,1536] @ [1536,384] + b2 -> x3 (bf16)
    gemm_mfma512_kernel<<<dim3(C_EMB / 128, NTOK / 128), 512, 0, stream>>>(h1, W2t, b2, x3, nullptr,
                                                                           NTOK, C_EMB, FFDIM, C_EMB, 0);
    // LM head: [32768,384] @ [384,65pad128] + blm -> f32 logits into d_out
    gemm_mfma512_kernel<<<dim3(1, NTOK / 128), 512, 0, stream>>>(x3, WlmT, blm, nullptr, out_logits,
                                                                 NTOK, 128, C_EMB, VOC, 0);

    loss_kernel<<<NTOK / 4, 256, 0, stream>>>(out_logits, targets, lossbuf);
    loss_reduce_kernel<<<1, 256, 0, stream>>>(lossbuf, out_loss);
}

// Round 8
// 297.205 us; speedup vs baseline: 7.5145x; 1.1275x over previous
//
#include <hip/hip_runtime.h>
#include <hip/hip_bf16.h>
#include <math.h>

typedef __hip_bfloat16 bf16;
typedef __attribute__((ext_vector_type(8))) short bf16x8;
typedef __attribute__((ext_vector_type(4))) float f32x4;
typedef unsigned char u8;

#define T_SEQ   256
#define C_EMB   384
#define NH      6
#define HS      4
#define NB      128
#define NTOK    (NB * T_SEQ)   // 32768
#define VOC     65
#define FFDIM   1536
#define QKVW    72             // 3*NH*HS packed width
#define PROJK   32             // 24 padded to 32

#define H1_SCALE   512.0f      // h1 fp8 scale (typ |h1|~0.003 -> ~1.5; max << 448)
#define W2_SCALE   128.0f      // W2 fp8 scale (max |W2|~0.1 -> ~13)
#define FF2_DESCALE (1.0f / (512.0f * 128.0f))

__device__ __forceinline__ float b2f(bf16 x) { return __bfloat162float(x); }
__device__ __forceinline__ bf16  f2b(float x) { return __float2bfloat16(x); }
__device__ __forceinline__ short f2s(float x) { bf16 b = __float2bfloat16(x); return *reinterpret_cast<short*>(&b); }
__device__ __forceinline__ u8 f2fp8(float x) {
    return (u8)(__builtin_amdgcn_cvt_pk_fp8_f32(x, x, 0, false) & 0xff);
}

// async 16B global->LDS (m97 path). Per-lane lds ptr = wave base + lane*16 (contiguous).
__device__ __forceinline__ void glds16(const void* g, void* l) {
    __builtin_amdgcn_global_load_lds((const __attribute__((address_space(1))) void*)g,
                                     (__attribute__((address_space(3))) void*)l, 16, 0, 0);
}

// ---------------- all weight packing in ONE dispatch (2560 blocks x 256)
__global__ void pack_all_kernel(const float* __restrict__ Wq, const float* __restrict__ Wk,
                                const float* __restrict__ Wv, const float* __restrict__ Wlm,
                                const float* __restrict__ Wproj,
                                const float* __restrict__ W1, const float* __restrict__ W2,
                                bf16* __restrict__ WqkvT, bf16* __restrict__ WlmT,
                                bf16* __restrict__ WprojT, bf16* __restrict__ W1t,
                                u8* __restrict__ W2f8) {
    int blk = blockIdx.x;
    if (blk < 128) {                                   // WqkvT [128,384]
        int n = blk;
        for (int c = threadIdx.x; c < C_EMB; c += 256) {
            float v = 0.f;
            if (n < QKVW) {
                int sel = n / 24, r = n % 24, h = r >> 2, d = r & 3;
                const float* W = (sel == 0) ? Wq : (sel == 1) ? Wk : Wv;
                v = W[(h * C_EMB + c) * HS + d];
            }
            WqkvT[(size_t)n * C_EMB + c] = f2b(v);
        }
    } else if (blk < 256) {                            // WlmT [128,384]
        int n = blk - 128;
        for (int c = threadIdx.x; c < C_EMB; c += 256)
            WlmT[(size_t)n * C_EMB + c] = f2b(n < VOC ? Wlm[(size_t)c * VOC + n] : 0.f);
    } else if (blk < 640) {                            // WprojT [384,32]
        int n = blk - 256;
        int k = threadIdx.x;
        if (k < PROJK)
            WprojT[(size_t)n * PROJK + k] = f2b(k < 24 ? Wproj[(size_t)k * C_EMB + n] : 0.f);
    } else if (blk < 640 + FFDIM) {                    // W1t [1536,384] bf16
        int n = blk - 640;
        for (int k = threadIdx.x; k < C_EMB; k += 256)
            W1t[(size_t)n * C_EMB + k] = f2b(W1[(size_t)k * FFDIM + n]);
    } else {                                           // W2f8 [384,1536] fp8 * W2_SCALE
        int n = blk - 640 - FFDIM;
        for (int k = threadIdx.x; k < FFDIM; k += 256)
            W2f8[(size_t)n * FFDIM + k] = f2fp8(W2[(size_t)k * C_EMB + n] * W2_SCALE);
    }
}

// ---------------- fused embed + QKV GEMM: qkv[token,72] = (tok_emb[idx]+pos_emb) @ WqkvT^T
__global__ __launch_bounds__(256)
void qkv_embed_mfma_kernel(const int* __restrict__ idx,
                           const float* __restrict__ tok_emb,
                           const float* __restrict__ pos_emb,
                           const bf16* __restrict__ Bt,
                           float* __restrict__ outf) {
    __shared__ short As[128][32];
    __shared__ short Bs[128][32];
    __shared__ int ids[128];
    int tid = threadIdx.x, lane = tid & 63, wave = tid >> 6;
    int bm = blockIdx.x * 128;
    int wm = (wave & 1) * 64, wn = (wave >> 1) * 64;
    int lrow = lane & 15, khalf = lane >> 4;
    if (tid < 128) ids[tid] = idx[bm + tid];
    __syncthreads();
    int tbase = bm & (T_SEQ - 1);

    f32x4 acc[4][4] = {};
    for (int k0 = 0; k0 < C_EMB; k0 += 32) {
        #pragma unroll
        for (int h = 0; h < 2; ++h) {
            int c = tid + h * 256;
            int row = c >> 2, colc = k0 + (c & 3) * 8;
            const float* te = tok_emb + (size_t)ids[row] * C_EMB + colc;
            const float* pe = pos_emb + (size_t)(tbase + row) * C_EMB + colc;
            float4 t0 = *(const float4*)te, t1 = *(const float4*)(te + 4);
            float4 p0 = *(const float4*)pe, p1 = *(const float4*)(pe + 4);
            union { short s[8]; uint4 u; } r;
            r.s[0] = f2s(t0.x + p0.x); r.s[1] = f2s(t0.y + p0.y);
            r.s[2] = f2s(t0.z + p0.z); r.s[3] = f2s(t0.w + p0.w);
            r.s[4] = f2s(t1.x + p1.x); r.s[5] = f2s(t1.y + p1.y);
            r.s[6] = f2s(t1.z + p1.z); r.s[7] = f2s(t1.w + p1.w);
            *(uint4*)((short*)As + (size_t)c * 8) = r.u;
        }
        int c = tid;
        glds16(Bt + (size_t)(c >> 2) * C_EMB + k0 + (c & 3) * 8, (short*)Bs + (size_t)c * 8);
        c = tid + 256;
        glds16(Bt + (size_t)(c >> 2) * C_EMB + k0 + (c & 3) * 8, (short*)Bs + (size_t)c * 8);
        __syncthreads();

        bf16x8 af[4], bff[4];
        #pragma unroll
        for (int i = 0; i < 4; ++i) {
            af[i]  = *(const bf16x8*)&As[wm + i * 16 + lrow][khalf * 8];
            bff[i] = *(const bf16x8*)&Bs[wn + i * 16 + lrow][khalf * 8];
        }
        #pragma unroll
        for (int mi = 0; mi < 4; ++mi)
            #pragma unroll
            for (int ni = 0; ni < 4; ++ni)
                acc[mi][ni] = __builtin_amdgcn_mfma_f32_16x16x32_bf16(af[mi], bff[ni], acc[mi][ni], 0, 0, 0);
        __syncthreads();
    }

    #pragma unroll
    for (int ni = 0; ni < 4; ++ni) {
        int col = wn + ni * 16 + lrow;
        if (col >= QKVW) continue;
        #pragma unroll
        for (int mi = 0; mi < 4; ++mi) {
            int row = bm + wm + mi * 16 + khalf * 4;
            #pragma unroll
            for (int r = 0; r < 4; ++r)
                outf[(size_t)(row + r) * QKVW + col] = acc[mi][ni][r];
        }
    }
}

// ---------------- causal softmax attention (single-pass online); writes bf16 attnT[token][32]
__global__ void attn_kernel(const float* __restrict__ qkv,
                            bf16* __restrict__ attnT) {
    int bh = blockIdx.x;
    int b = bh / NH, h = bh % NH;
    int t = threadIdx.x;           // 256 threads
    __shared__ float ks[T_SEQ][HS];
    __shared__ float vs[T_SEQ][HS];
    const float* base = qkv + (size_t)(b * T_SEQ) * QKVW;
    #pragma unroll
    for (int d = 0; d < HS; ++d) {
        ks[t][d] = base[t * QKVW + 24 + h * HS + d];
        vs[t][d] = base[t * QKVW + 48 + h * HS + d];
    }
    __syncthreads();
    const float* qp = base + t * QKVW + h * HS;
    float q0 = qp[0], q1 = qp[1], q2 = qp[2], q3 = qp[3];
    const float scale = 0.05103103630798288f;   // 384^-0.5
    float m = -1e30f, sum = 0.f, o0 = 0.f, o1 = 0.f, o2 = 0.f, o3 = 0.f;
    for (int s = 0; s <= t; ++s) {
        float sc = (q0 * ks[s][0] + q1 * ks[s][1] + q2 * ks[s][2] + q3 * ks[s][3]) * scale;
        float mn = fmaxf(m, sc);
        float alpha = __expf(m - mn);
        float p = __expf(sc - mn);
        sum = sum * alpha + p;
        o0 = o0 * alpha + p * vs[s][0];
        o1 = o1 * alpha + p * vs[s][1];
        o2 = o2 * alpha + p * vs[s][2];
        o3 = o3 * alpha + p * vs[s][3];
        m = mn;
    }
    float inv = 1.f / sum;
    bf16* out = attnT + (size_t)(b * T_SEQ + t) * PROJK + h * HS;
    out[0] = f2b(o0 * inv); out[1] = f2b(o1 * inv); out[2] = f2b(o2 * inv); out[3] = f2b(o3 * inv);
    if (h == 0) {   // zero-pad cols 24..31 once per token
        bf16* pad = attnT + (size_t)(b * T_SEQ + t) * PROJK + 24;
        *(uint4*)pad = uint4{0, 0, 0, 0};
    }
}

// ---------------- MFMA GEMM, BK=32, 256 threads (proj: K=32, 1 iter)
__global__ __launch_bounds__(256)
void gemm_mfma32_kernel(const bf16* __restrict__ A, const bf16* __restrict__ Bt,
                        const float* __restrict__ bias,
                        bf16* __restrict__ outb, float* __restrict__ outf,
                        int M, int Npad, int K, int Nout, int relu) {
    __shared__ short As[128][32];
    __shared__ short Bs[128][32];
    int tid  = threadIdx.x;
    int lane = tid & 63;
    int wave = tid >> 6;
    int bm = blockIdx.y * 128;
    int bn = blockIdx.x * 128;
    int wm = (wave & 1) * 64;
    int wn = (wave >> 1) * 64;
    int lrow  = lane & 15;
    int khalf = lane >> 4;

    f32x4 acc[4][4] = {};
    for (int k0 = 0; k0 < K; k0 += 32) {
        int c = tid;
        glds16(A  + (size_t)(bm + (c >> 2)) * K + k0 + (c & 3) * 8, (short*)As + (size_t)c * 8);
        glds16(Bt + (size_t)(bn + (c >> 2)) * K + k0 + (c & 3) * 8, (short*)Bs + (size_t)c * 8);
        c = tid + 256;
        glds16(A  + (size_t)(bm + (c >> 2)) * K + k0 + (c & 3) * 8, (short*)As + (size_t)c * 8);
        glds16(Bt + (size_t)(bn + (c >> 2)) * K + k0 + (c & 3) * 8, (short*)Bs + (size_t)c * 8);
        __syncthreads();

        bf16x8 af[4], bff[4];
        #pragma unroll
        for (int i = 0; i < 4; ++i) {
            af[i]  = *(const bf16x8*)&As[wm + i * 16 + lrow][khalf * 8];
            bff[i] = *(const bf16x8*)&Bs[wn + i * 16 + lrow][khalf * 8];
        }
        #pragma unroll
        for (int mi = 0; mi < 4; ++mi)
            #pragma unroll
            for (int ni = 0; ni < 4; ++ni)
                acc[mi][ni] = __builtin_amdgcn_mfma_f32_16x16x32_bf16(af[mi], bff[ni], acc[mi][ni], 0, 0, 0);
        __syncthreads();
    }

    #pragma unroll
    for (int ni = 0; ni < 4; ++ni) {
        int col = bn + wn + ni * 16 + lrow;
        if (col >= Nout) continue;
        float bv = bias ? bias[col] : 0.f;
        #pragma unroll
        for (int mi = 0; mi < 4; ++mi) {
            int row = bm + wm + mi * 16 + khalf * 4;
            #pragma unroll
            for (int r = 0; r < 4; ++r) {
                float v = acc[mi][ni][r] + bv;
                if (relu) v = fmaxf(v, 0.f);
                if (outf) outf[(size_t)(row + r) * Nout + col] = v;
                else      outb[(size_t)(row + r) * Nout + col] = f2b(v);
            }
        }
    }
}

// ---------------- MFMA GEMM bf16, BK=64, 512 threads, LDS bank-swizzled.
// Swizzle: row's 64B LDS line is rotated by ((row>>1)&3)*16 bytes (global src shifted to match)
// -> fragment b128 reads go from 8-way to 2-way (free) bank aliasing.
// Output: bf16 (outb) | f32 (outf) | fp8*oscale (outf8). K%64==0.
__global__ __launch_bounds__(512)
void gemm_mfma512_kernel(const bf16* __restrict__ A, const bf16* __restrict__ Bt,
                         const float* __restrict__ bias,
                         bf16* __restrict__ outb, float* __restrict__ outf,
                         u8* __restrict__ outf8, float oscale,
                         int M, int K, int Nout, int relu) {
    __shared__ short As[2][128][32];   // [k-half][row][k32], rows rotated
    __shared__ short Bs[2][128][32];
    int tid  = threadIdx.x;
    int lane = tid & 63;
    int wave = tid >> 6;               // 0..7
    int bm = blockIdx.y * 128;
    int bn = blockIdx.x * 128;
    int wm = (wave & 1) * 64;
    int wn = (wave >> 1) * 32;         // 0,32,64,96
    int lrow  = lane & 15;
    int khalf = lane >> 4;

    f32x4 acc[4][2] = {};
    int row = tid >> 2;                        // 0..127
    int inner = (tid & 3) * 16;                // byte within 64B row line
    int src = (inner - ((row >> 1) & 3) * 16) & 63;   // global byte offset this chunk holds
    int selem = src >> 1;                      // element offset
    int arot = (((lrow >> 1) & 3) * 16);       // read-side rotation (bytes); same for A and B rows

    for (int k0 = 0; k0 < K; k0 += 64) {
        const bf16* Ag = A  + (size_t)(bm + row) * K + k0 + selem;
        const bf16* Bg = Bt + (size_t)(bn + row) * K + k0 + selem;
        glds16(Ag,      (short*)As[0] + (size_t)tid * 8);
        glds16(Ag + 32, (short*)As[1] + (size_t)tid * 8);
        glds16(Bg,      (short*)Bs[0] + (size_t)tid * 8);
        glds16(Bg + 32, (short*)Bs[1] + (size_t)tid * 8);
        __syncthreads();

        int roff = ((khalf * 16 + arot) & 63) >> 1;    // short offset within row
        #pragma unroll
        for (int st = 0; st < 2; ++st) {
            bf16x8 af[4], bff[2];
            #pragma unroll
            for (int i = 0; i < 4; ++i)
                af[i] = *(const bf16x8*)&As[st][wm + i * 16 + lrow][roff];
            #pragma unroll
            for (int i = 0; i < 2; ++i)
                bff[i] = *(const bf16x8*)&Bs[st][wn + i * 16 + lrow][roff];
            #pragma unroll
            for (int mi = 0; mi < 4; ++mi)
                #pragma unroll
                for (int ni = 0; ni < 2; ++ni)
                    acc[mi][ni] = __builtin_amdgcn_mfma_f32_16x16x32_bf16(af[mi], bff[ni], acc[mi][ni], 0, 0, 0);
        }
        __syncthreads();
    }

    #pragma unroll
    for (int ni = 0; ni < 2; ++ni) {
        int col = bn + wn + ni * 16 + lrow;
        if (col >= Nout) continue;
        float bv = bias ? bias[col] : 0.f;
        #pragma unroll
        for (int mi = 0; mi < 4; ++mi) {
            int orow = bm + wm + mi * 16 + khalf * 4;
            float w[4];
            #pragma unroll
            for (int r = 0; r < 4; ++r) {
                w[r] = acc[mi][ni][r] + bv;
                if (relu) w[r] = fmaxf(w[r], 0.f);
            }
            if (outf8) {
                int p01 = __builtin_amdgcn_cvt_pk_fp8_f32(w[0] * oscale, w[1] * oscale, 0, false);
                int p23 = __builtin_amdgcn_cvt_pk_fp8_f32(w[2] * oscale, w[3] * oscale, 0, false);
                outf8[(size_t)(orow + 0) * Nout + col] = (u8)(p01 & 0xff);
                outf8[(size_t)(orow + 1) * Nout + col] = (u8)((p01 >> 8) & 0xff);
                outf8[(size_t)(orow + 2) * Nout + col] = (u8)(p23 & 0xff);
                outf8[(size_t)(orow + 3) * Nout + col] = (u8)((p23 >> 8) & 0xff);
            } else if (outf) {
                #pragma unroll
                for (int r = 0; r < 4; ++r) outf[(size_t)(orow + r) * Nout + col] = w[r];
            } else {
                #pragma unroll
                for (int r = 0; r < 4; ++r) outb[(size_t)(orow + r) * Nout + col] = f2b(w[r]);
            }
        }
    }
}

// ---------------- FF2: fp8 x fp8 MFMA GEMM, BK=128, 512 threads, bank-swizzled.
// A = h1 fp8 [M][K] (pre-scaled by H1_SCALE), Bt = W2 fp8 [Npad][K] (pre-scaled by W2_SCALE).
// out bf16 = acc*descale + bias. Swizzle: 128B row rotated by (row&7)*16 bytes.
__global__ __launch_bounds__(512)
void gemm_ff2_fp8_kernel(const u8* __restrict__ A, const u8* __restrict__ Bt,
                         const float* __restrict__ bias, bf16* __restrict__ outb,
                         float descale, int M, int K, int Nout) {
    __shared__ u8 As[128][128];   // 16 KB, rows rotated by (row&7)*16
    __shared__ u8 Bs[128][128];
    int tid  = threadIdx.x;
    int lane = tid & 63;
    int wave = tid >> 6;
    int bm = blockIdx.y * 128;
    int bn = blockIdx.x * 128;
    int wm = (wave & 1) * 64;
    int wn = (wave >> 1) * 32;
    int lrow  = lane & 15;
    int khalf = lane >> 4;

    f32x4 acc[4][2] = {};
    int r0 = tid >> 3;                          // 0..63 (chunk rows; +64 for second chunk)
    int i0 = (tid & 7) * 16;                    // byte within 128B row line
    int s0 = (i0 - (r0 & 7) * 16) & 127;        // global byte offset ((r0+64)&7 == r0&7)
    int arot = (lrow & 7) * 16;                 // read-side rotation

    for (int k0 = 0; k0 < K; k0 += 128) {
        const u8* Ag = A  + (size_t)(bm + r0) * K + k0 + s0;
        const u8* Bg = Bt + (size_t)(bn + r0) * K + k0 + s0;
        glds16(Ag,                  &As[0][0] + (size_t)tid * 16);
        glds16(Ag + (size_t)64 * K, &As[64][0] + (size_t)tid * 16);
        glds16(Bg,                  &Bs[0][0] + (size_t)tid * 16);
        glds16(Bg + (size_t)64 * K, &Bs[64][0] + (size_t)tid * 16);
        __syncthreads();

        #pragma unroll
        for (int ks = 0; ks < 4; ++ks) {
            int roff = (ks * 32 + khalf * 8 + arot) & 127;
            long a[4], b[2];
            #pragma unroll
            for (int i = 0; i < 4; ++i)
                a[i] = *(const long*)&As[wm + i * 16 + lrow][roff];
            #pragma unroll
            for (int i = 0; i < 2; ++i)
                b[i] = *(const long*)&Bs[wn + i * 16 + lrow][roff];
            #pragma unroll
            for (int mi = 0; mi < 4; ++mi)
                #pragma unroll
                for (int ni = 0; ni < 2; ++ni)
                    acc[mi][ni] = __builtin_amdgcn_mfma_f32_16x16x32_fp8_fp8(a[mi], b[ni], acc[mi][ni], 0, 0, 0);
        }
        __syncthreads();
    }

    #pragma unroll
    for (int ni = 0; ni < 2; ++ni) {
        int col = bn + wn + ni * 16 + lrow;
        if (col >= Nout) continue;
        float bv = bias[col];
        #pragma unroll
        for (int mi = 0; mi < 4; ++mi) {
            int orow = bm + wm + mi * 16 + khalf * 4;
            #pragma unroll
            for (int r = 0; r < 4; ++r)
                outb[(size_t)(orow + r) * Nout + col] = f2b(acc[mi][ni][r] * descale + bv);
        }
    }
}

// ---------------- per-token CE loss: one wave per token, shuffle-only
__global__ __launch_bounds__(256)
void loss_kernel(const float* __restrict__ logits,
                 const int* __restrict__ targets,
                 float* __restrict__ lossbuf) {
    int lane = threadIdx.x & 63;
    int token = blockIdx.x * 4 + (threadIdx.x >> 6);
    const float* lr = logits + (size_t)token * VOC;
    float v0 = lr[lane];
    float v64 = (lane == 0) ? lr[64] : -1e30f;
    float m = fmaxf(v0, v64);
    #pragma unroll
    for (int s = 32; s > 0; s >>= 1) m = fmaxf(m, __shfl_xor(m, s));
    int t = targets[token];
    float sum = __expf(v0 - m) + ((lane == 0) ? __expf(v64 - m) : 0.f);
    float tv  = (lane == t) ? v0 : ((lane == 0 && t == 64) ? v64 : 0.f);
    #pragma unroll
    for (int s = 32; s > 0; s >>= 1) { sum += __shfl_xor(sum, s); tv += __shfl_xor(tv, s); }
    if (lane == 0) lossbuf[token] = m + logf(sum) - tv;
}

__global__ void loss_reduce_kernel(const float* __restrict__ lossbuf, float* __restrict__ out_loss) {
    __shared__ float red[256];
    int tid = threadIdx.x;
    float s = 0.f;
    for (int i = tid; i < NTOK; i += 256) s += lossbuf[i];
    red[tid] = s; __syncthreads();
    for (int st = 128; st > 0; st >>= 1) { if (tid < st) red[tid] += red[tid + st]; __syncthreads(); }
    if (tid == 0) out_loss[0] = red[0] / (float)NTOK;
}

extern "C" void kernel_launch(void* const* d_in, const int* in_sizes, int n_in,
                              void* d_out, int out_size, void* d_ws, size_t ws_size,
                              hipStream_t stream) {
    const int*   idx     = (const int*)  d_in[0];
    const int*   targets = (const int*)  d_in[1];
    const float* tok_emb = (const float*)d_in[2];
    const float* pos_emb = (const float*)d_in[3];
    const float* Wq      = (const float*)d_in[4];
    const float* Wk      = (const float*)d_in[5];
    const float* Wv      = (const float*)d_in[6];
    const float* Wproj   = (const float*)d_in[7];
    const float* bproj   = (const float*)d_in[8];
    const float* W1      = (const float*)d_in[9];
    const float* b1      = (const float*)d_in[10];
    const float* W2      = (const float*)d_in[11];
    const float* b2      = (const float*)d_in[12];
    const float* Wlm     = (const float*)d_in[13];
    const float* blm     = (const float*)d_in[14];

    char* ws = (char*)d_ws;
    bf16*  WprojT = (bf16*) (ws + 0);                       // 24576 B
    float* qkvbuf = (float*)(ws + 25165824);                // 9437184 B
    bf16*  attnT  = (bf16*) (ws + 34603008);                // 2097152 B
    bf16*  x2     = (bf16*) (ws + 37748736);                // 25165824 B
    u8*    h1f8   = (u8*)   (ws + 62914560);                // 32768*1536 fp8 = 50331648 B
    bf16*  x3     = (bf16*) (ws + 163577856);               // 25165824 B
    float* lossbuf= (float*)(ws + 188743680);               // 131072 B
    bf16*  W1t    = (bf16*) (ws + 188874752);               // 1179648 B
    u8*    W2f8   = (u8*)   (ws + 190054400);               // 589824 B
    bf16*  WqkvT  = (bf16*) (ws + 191234048);               // 98304 B
    bf16*  WlmT   = (bf16*) (ws + 191332352);               // 98304 B

    float* out_logits = (float*)d_out;                      // [32768*65] f32
    float* out_loss   = out_logits + (size_t)NTOK * VOC;    // [1]

    // all weight packing in one dispatch
    pack_all_kernel<<<640 + FFDIM + C_EMB, 256, 0, stream>>>(Wq, Wk, Wv, Wlm, Wproj, W1, W2,
                                                             WqkvT, WlmT, WprojT, W1t, W2f8);

    // fused embed + QKV: -> qkvbuf f32 [32768,72]
    qkv_embed_mfma_kernel<<<NTOK / 128, 256, 0, stream>>>(idx, tok_emb, pos_emb, WqkvT, qkvbuf);
    attn_kernel<<<NB * NH, T_SEQ, 0, stream>>>(qkvbuf, attnT);

    // proj: [32768,32] @ [32,384pad] + bproj -> x2 (bf16), 1 K-iter MFMA
    gemm_mfma32_kernel<<<dim3(C_EMB / 128, NTOK / 128), 256, 0, stream>>>(attnT, WprojT, bproj,
                                                                          x2, nullptr,
                                                                          NTOK, C_EMB, PROJK, C_EMB, 0);
    // FF1: [32768,384] @ [384,1536] + b1, relu -> h1 fp8 (scaled)
    gemm_mfma512_kernel<<<dim3(FFDIM / 128, NTOK / 128), 512, 0, stream>>>(x2, W1t, b1,
                                                                           nullptr, nullptr, h1f8, H1_SCALE,
                                                                           NTOK, C_EMB, FFDIM, 1);
    // FF2: fp8 [32768,1536] @ fp8 [1536,384] -> x3 bf16 (descaled + b2)
    gemm_ff2_fp8_kernel<<<dim3(C_EMB / 128, NTOK / 128), 512, 0, stream>>>(h1f8, W2f8, b2, x3,
                                                                           FF2_DESCALE, NTOK, FFDIM, C_EMB);
    // LM head: [32768,384] @ [384,65pad128] + blm -> f32 logits into d_out
    gemm_mfma512_kernel<<<dim3(1, NTOK / 128), 512, 0, stream>>>(x3, WlmT, blm,
                                                                 nullptr, out_logits, nullptr, 1.0f,
                                                                 NTOK, C_EMB, VOC, 0);

    loss_kernel<<<NTOK / 4, 256, 0, stream>>>(out_logits, targets, lossbuf);
    loss_reduce_kernel<<<1, 256, 0, stream>>>(lossbuf, out_loss);
}

// Round 9
// 276.408 us; speedup vs baseline: 8.0799x; 1.0752x over previous
//
#include <hip/hip_runtime.h>
#include <hip/hip_bf16.h>
#include <math.h>

typedef __hip_bfloat16 bf16;
typedef __attribute__((ext_vector_type(8))) short bf16x8;
typedef __attribute__((ext_vector_type(4))) float f32x4;
typedef unsigned char u8;

#define T_SEQ   256
#define C_EMB   384
#define NH      6
#define HS      4
#define NB      128
#define NTOK    (NB * T_SEQ)   // 32768
#define VOC     65
#define FFDIM   1536
#define QKVW    72             // 3*NH*HS packed width
#define PROJK   32             // 24 padded to 32

#define X2_SCALE    128.0f     // x2 fp8 scale (|x2|~0.007 -> ~0.9)
#define W1_SCALE    128.0f     // W1 fp8 scale (max |W1|~0.1 -> ~13)
#define FF1_DESCALE (1.0f / (128.0f * 128.0f))
#define H1_SCALE    512.0f     // h1 fp8 scale (|h1|~0.003 -> ~1.5; max << 448)
#define W2_SCALE    128.0f
#define FF2_DESCALE (1.0f / (512.0f * 128.0f))

__device__ __forceinline__ float b2f(bf16 x) { return __bfloat162float(x); }
__device__ __forceinline__ bf16  f2b(float x) { return __float2bfloat16(x); }
__device__ __forceinline__ short f2s(float x) { bf16 b = __float2bfloat16(x); return *reinterpret_cast<short*>(&b); }
__device__ __forceinline__ u8 f2fp8(float x) {
    return (u8)(__builtin_amdgcn_cvt_pk_fp8_f32(x, x, 0, false) & 0xff);
}

// async 16B global->LDS (m97 path). Per-lane lds ptr = wave base + lane*16 (contiguous).
__device__ __forceinline__ void glds16(const void* g, void* l) {
    __builtin_amdgcn_global_load_lds((const __attribute__((address_space(1))) void*)g,
                                     (__attribute__((address_space(3))) void*)l, 16, 0, 0);
}

// ---------------- all weight packing in ONE dispatch
__global__ void pack_all_kernel(const float* __restrict__ Wq, const float* __restrict__ Wk,
                                const float* __restrict__ Wv, const float* __restrict__ Wlm,
                                const float* __restrict__ Wproj,
                                const float* __restrict__ W1, const float* __restrict__ W2,
                                bf16* __restrict__ WqkvT, bf16* __restrict__ WlmT,
                                bf16* __restrict__ WprojT, u8* __restrict__ W1f8,
                                u8* __restrict__ W2f8) {
    int blk = blockIdx.x;
    if (blk < 128) {                                   // WqkvT [128,384]
        int n = blk;
        for (int c = threadIdx.x; c < C_EMB; c += 256) {
            float v = 0.f;
            if (n < QKVW) {
                int sel = n / 24, r = n % 24, h = r >> 2, d = r & 3;
                const float* W = (sel == 0) ? Wq : (sel == 1) ? Wk : Wv;
                v = W[(h * C_EMB + c) * HS + d];
            }
            WqkvT[(size_t)n * C_EMB + c] = f2b(v);
        }
    } else if (blk < 256) {                            // WlmT [128,384]
        int n = blk - 128;
        for (int c = threadIdx.x; c < C_EMB; c += 256)
            WlmT[(size_t)n * C_EMB + c] = f2b(n < VOC ? Wlm[(size_t)c * VOC + n] : 0.f);
    } else if (blk < 640) {                            // WprojT [384,32]
        int n = blk - 256;
        int k = threadIdx.x;
        if (k < PROJK)
            WprojT[(size_t)n * PROJK + k] = f2b(k < 24 ? Wproj[(size_t)k * C_EMB + n] : 0.f);
    } else if (blk < 640 + FFDIM) {                    // W1f8 [1536,384] fp8 * W1_SCALE
        int n = blk - 640;
        for (int k = threadIdx.x; k < C_EMB; k += 256)
            W1f8[(size_t)n * C_EMB + k] = f2fp8(W1[(size_t)k * FFDIM + n] * W1_SCALE);
    } else {                                           // W2f8 [384,1536] fp8 * W2_SCALE
        int n = blk - 640 - FFDIM;
        for (int k = threadIdx.x; k < FFDIM; k += 256)
            W2f8[(size_t)n * FFDIM + k] = f2fp8(W2[(size_t)k * C_EMB + n] * W2_SCALE);
    }
}

// ---------------- fused embed + QKV GEMM: qkv[token,72] = (tok_emb[idx]+pos_emb) @ WqkvT^T
__global__ __launch_bounds__(256)
void qkv_embed_mfma_kernel(const int* __restrict__ idx,
                           const float* __restrict__ tok_emb,
                           const float* __restrict__ pos_emb,
                           const bf16* __restrict__ Bt,
                           float* __restrict__ outf) {
    __shared__ short As[128][32];
    __shared__ short Bs[128][32];
    __shared__ int ids[128];
    int tid = threadIdx.x, lane = tid & 63, wave = tid >> 6;
    int bm = blockIdx.x * 128;
    int wm = (wave & 1) * 64, wn = (wave >> 1) * 64;
    int lrow = lane & 15, khalf = lane >> 4;
    if (tid < 128) ids[tid] = idx[bm + tid];
    __syncthreads();
    int tbase = bm & (T_SEQ - 1);

    f32x4 acc[4][4] = {};
    for (int k0 = 0; k0 < C_EMB; k0 += 32) {
        #pragma unroll
        for (int h = 0; h < 2; ++h) {
            int c = tid + h * 256;
            int row = c >> 2, colc = k0 + (c & 3) * 8;
            const float* te = tok_emb + (size_t)ids[row] * C_EMB + colc;
            const float* pe = pos_emb + (size_t)(tbase + row) * C_EMB + colc;
            float4 t0 = *(const float4*)te, t1 = *(const float4*)(te + 4);
            float4 p0 = *(const float4*)pe, p1 = *(const float4*)(pe + 4);
            union { short s[8]; uint4 u; } r;
            r.s[0] = f2s(t0.x + p0.x); r.s[1] = f2s(t0.y + p0.y);
            r.s[2] = f2s(t0.z + p0.z); r.s[3] = f2s(t0.w + p0.w);
            r.s[4] = f2s(t1.x + p1.x); r.s[5] = f2s(t1.y + p1.y);
            r.s[6] = f2s(t1.z + p1.z); r.s[7] = f2s(t1.w + p1.w);
            *(uint4*)((short*)As + (size_t)c * 8) = r.u;
        }
        int c = tid;
        glds16(Bt + (size_t)(c >> 2) * C_EMB + k0 + (c & 3) * 8, (short*)Bs + (size_t)c * 8);
        c = tid + 256;
        glds16(Bt + (size_t)(c >> 2) * C_EMB + k0 + (c & 3) * 8, (short*)Bs + (size_t)c * 8);
        __syncthreads();

        bf16x8 af[4], bff[4];
        #pragma unroll
        for (int i = 0; i < 4; ++i) {
            af[i]  = *(const bf16x8*)&As[wm + i * 16 + lrow][khalf * 8];
            bff[i] = *(const bf16x8*)&Bs[wn + i * 16 + lrow][khalf * 8];
        }
        #pragma unroll
        for (int mi = 0; mi < 4; ++mi)
            #pragma unroll
            for (int ni = 0; ni < 4; ++ni)
                acc[mi][ni] = __builtin_amdgcn_mfma_f32_16x16x32_bf16(af[mi], bff[ni], acc[mi][ni], 0, 0, 0);
        __syncthreads();
    }

    #pragma unroll
    for (int ni = 0; ni < 4; ++ni) {
        int col = wn + ni * 16 + lrow;
        if (col >= QKVW) continue;
        #pragma unroll
        for (int mi = 0; mi < 4; ++mi) {
            int row = bm + wm + mi * 16 + khalf * 4;
            #pragma unroll
            for (int r = 0; r < 4; ++r)
                outf[(size_t)(row + r) * QKVW + col] = acc[mi][ni][r];
        }
    }
}

// ---------------- causal softmax attention (single-pass online); writes bf16 attnT[token][32]
__global__ void attn_kernel(const float* __restrict__ qkv,
                            bf16* __restrict__ attnT) {
    int bh = blockIdx.x;
    int b = bh / NH, h = bh % NH;
    int t = threadIdx.x;           // 256 threads
    __shared__ float ks[T_SEQ][HS];
    __shared__ float vs[T_SEQ][HS];
    const float* base = qkv + (size_t)(b * T_SEQ) * QKVW;
    #pragma unroll
    for (int d = 0; d < HS; ++d) {
        ks[t][d] = base[t * QKVW + 24 + h * HS + d];
        vs[t][d] = base[t * QKVW + 48 + h * HS + d];
    }
    __syncthreads();
    const float* qp = base + t * QKVW + h * HS;
    float q0 = qp[0], q1 = qp[1], q2 = qp[2], q3 = qp[3];
    const float scale = 0.05103103630798288f;   // 384^-0.5
    float m = -1e30f, sum = 0.f, o0 = 0.f, o1 = 0.f, o2 = 0.f, o3 = 0.f;
    for (int s = 0; s <= t; ++s) {
        float sc = (q0 * ks[s][0] + q1 * ks[s][1] + q2 * ks[s][2] + q3 * ks[s][3]) * scale;
        float mn = fmaxf(m, sc);
        float alpha = __expf(m - mn);
        float p = __expf(sc - mn);
        sum = sum * alpha + p;
        o0 = o0 * alpha + p * vs[s][0];
        o1 = o1 * alpha + p * vs[s][1];
        o2 = o2 * alpha + p * vs[s][2];
        o3 = o3 * alpha + p * vs[s][3];
        m = mn;
    }
    float inv = 1.f / sum;
    bf16* out = attnT + (size_t)(b * T_SEQ + t) * PROJK + h * HS;
    out[0] = f2b(o0 * inv); out[1] = f2b(o1 * inv); out[2] = f2b(o2 * inv); out[3] = f2b(o3 * inv);
    if (h == 0) {   // zero-pad cols 24..31 once per token
        bf16* pad = attnT + (size_t)(b * T_SEQ + t) * PROJK + 24;
        *(uint4*)pad = uint4{0, 0, 0, 0};
    }
}

// ---------------- proj: MFMA bf16, BK=32, 256 threads; fp8 output (x2f8 = x2 * oscale)
__global__ __launch_bounds__(256)
void gemm_mfma32_kernel(const bf16* __restrict__ A, const bf16* __restrict__ Bt,
                        const float* __restrict__ bias,
                        u8* __restrict__ outf8, float oscale,
                        int M, int K, int Nout) {
    __shared__ short As[128][32];
    __shared__ short Bs[128][32];
    int tid  = threadIdx.x;
    int lane = tid & 63;
    int wave = tid >> 6;
    int bm = blockIdx.y * 128;
    int bn = blockIdx.x * 128;
    int wm = (wave & 1) * 64;
    int wn = (wave >> 1) * 64;
    int lrow  = lane & 15;
    int khalf = lane >> 4;

    f32x4 acc[4][4] = {};
    for (int k0 = 0; k0 < K; k0 += 32) {
        int c = tid;
        glds16(A  + (size_t)(bm + (c >> 2)) * K + k0 + (c & 3) * 8, (short*)As + (size_t)c * 8);
        glds16(Bt + (size_t)(bn + (c >> 2)) * K + k0 + (c & 3) * 8, (short*)Bs + (size_t)c * 8);
        c = tid + 256;
        glds16(A  + (size_t)(bm + (c >> 2)) * K + k0 + (c & 3) * 8, (short*)As + (size_t)c * 8);
        glds16(Bt + (size_t)(bn + (c >> 2)) * K + k0 + (c & 3) * 8, (short*)Bs + (size_t)c * 8);
        __syncthreads();

        bf16x8 af[4], bff[4];
        #pragma unroll
        for (int i = 0; i < 4; ++i) {
            af[i]  = *(const bf16x8*)&As[wm + i * 16 + lrow][khalf * 8];
            bff[i] = *(const bf16x8*)&Bs[wn + i * 16 + lrow][khalf * 8];
        }
        #pragma unroll
        for (int mi = 0; mi < 4; ++mi)
            #pragma unroll
            for (int ni = 0; ni < 4; ++ni)
                acc[mi][ni] = __builtin_amdgcn_mfma_f32_16x16x32_bf16(af[mi], bff[ni], acc[mi][ni], 0, 0, 0);
        __syncthreads();
    }

    #pragma unroll
    for (int ni = 0; ni < 4; ++ni) {
        int col = bn + wn + ni * 16 + lrow;
        float bv = bias[col];
        #pragma unroll
        for (int mi = 0; mi < 4; ++mi) {
            int row = bm + wm + mi * 16 + khalf * 4;
            float w[4];
            #pragma unroll
            for (int r = 0; r < 4; ++r) w[r] = (acc[mi][ni][r] + bv) * oscale;
            int p01 = __builtin_amdgcn_cvt_pk_fp8_f32(w[0], w[1], 0, false);
            int p23 = __builtin_amdgcn_cvt_pk_fp8_f32(w[2], w[3], 0, false);
            outf8[(size_t)(row + 0) * Nout + col] = (u8)(p01 & 0xff);
            outf8[(size_t)(row + 1) * Nout + col] = (u8)((p01 >> 8) & 0xff);
            outf8[(size_t)(row + 2) * Nout + col] = (u8)(p23 & 0xff);
            outf8[(size_t)(row + 3) * Nout + col] = (u8)((p23 >> 8) & 0xff);
        }
    }
}

// ---------------- unified fp8 x fp8 MFMA GEMM, BK=128, 512 threads, bank-swizzled,
// XCD-aware block swizzle: lin&7 -> xcd chunk of m-tiles; n fastest within m (A-tile L2 reuse).
// out = [relu](acc*descale + bias); written bf16 (outb) or fp8*oscale (outf8). K%128==0, M/128 % 8 == 0.
__global__ __launch_bounds__(512)
void gemm_fp8_kernel(const u8* __restrict__ A, const u8* __restrict__ Bt,
                     const float* __restrict__ bias,
                     bf16* __restrict__ outb, u8* __restrict__ outf8,
                     float descale, float oscale,
                     int M, int K, int Nout, int NT, int relu) {
    __shared__ u8 As[128][128];   // rows rotated by (row&7)*16 bytes
    __shared__ u8 Bs[128][128];
    int lin  = blockIdx.x;
    int xcd  = lin & 7;
    int loc  = lin >> 3;
    int nt   = loc % NT;
    int mloc = loc / NT;
    int MPX  = (M / 128) >> 3;         // m-tiles per xcd chunk
    int bm = (xcd * MPX + mloc) * 128;
    int bn = nt * 128;

    int tid  = threadIdx.x;
    int lane = tid & 63;
    int wave = tid >> 6;
    int wm = (wave & 1) * 64;
    int wn = (wave >> 1) * 32;
    int lrow  = lane & 15;
    int khalf = lane >> 4;

    f32x4 acc[4][2] = {};
    int r0 = tid >> 3;                          // 0..63 (+64 second chunk)
    int i0 = (tid & 7) * 16;                    // byte within 128B row line
    int s0 = (i0 - (r0 & 7) * 16) & 127;        // global byte offset ((r0+64)&7 == r0&7)
    int arot = (lrow & 7) * 16;                 // read-side rotation

    for (int k0 = 0; k0 < K; k0 += 128) {
        const u8* Ag = A  + (size_t)(bm + r0) * K + k0 + s0;
        const u8* Bg = Bt + (size_t)(bn + r0) * K + k0 + s0;
        glds16(Ag,                  &As[0][0]  + (size_t)tid * 16);
        glds16(Ag + (size_t)64 * K, &As[64][0] + (size_t)tid * 16);
        glds16(Bg,                  &Bs[0][0]  + (size_t)tid * 16);
        glds16(Bg + (size_t)64 * K, &Bs[64][0] + (size_t)tid * 16);
        __syncthreads();

        #pragma unroll
        for (int ks = 0; ks < 4; ++ks) {
            int roff = (ks * 32 + khalf * 8 + arot) & 127;
            long a[4], b[2];
            #pragma unroll
            for (int i = 0; i < 4; ++i)
                a[i] = *(const long*)&As[wm + i * 16 + lrow][roff];
            #pragma unroll
            for (int i = 0; i < 2; ++i)
                b[i] = *(const long*)&Bs[wn + i * 16 + lrow][roff];
            #pragma unroll
            for (int mi = 0; mi < 4; ++mi)
                #pragma unroll
                for (int ni = 0; ni < 2; ++ni)
                    acc[mi][ni] = __builtin_amdgcn_mfma_f32_16x16x32_fp8_fp8(a[mi], b[ni], acc[mi][ni], 0, 0, 0);
        }
        __syncthreads();
    }

    #pragma unroll
    for (int ni = 0; ni < 2; ++ni) {
        int col = bn + wn + ni * 16 + lrow;
        float bv = bias[col];
        #pragma unroll
        for (int mi = 0; mi < 4; ++mi) {
            int orow = bm + wm + mi * 16 + khalf * 4;
            float w[4];
            #pragma unroll
            for (int r = 0; r < 4; ++r) {
                w[r] = acc[mi][ni][r] * descale + bv;
                if (relu) w[r] = fmaxf(w[r], 0.f);
            }
            if (outf8) {
                int p01 = __builtin_amdgcn_cvt_pk_fp8_f32(w[0] * oscale, w[1] * oscale, 0, false);
                int p23 = __builtin_amdgcn_cvt_pk_fp8_f32(w[2] * oscale, w[3] * oscale, 0, false);
                outf8[(size_t)(orow + 0) * Nout + col] = (u8)(p01 & 0xff);
                outf8[(size_t)(orow + 1) * Nout + col] = (u8)((p01 >> 8) & 0xff);
                outf8[(size_t)(orow + 2) * Nout + col] = (u8)(p23 & 0xff);
                outf8[(size_t)(orow + 3) * Nout + col] = (u8)((p23 >> 8) & 0xff);
            } else {
                #pragma unroll
                for (int r = 0; r < 4; ++r) outb[(size_t)(orow + r) * Nout + col] = f2b(w[r]);
            }
        }
    }
}

// ---------------- LM head: MFMA bf16, BK=64, 512 threads, bank-swizzled (f32 out)
__global__ __launch_bounds__(512)
void gemm_mfma512_kernel(const bf16* __restrict__ A, const bf16* __restrict__ Bt,
                         const float* __restrict__ bias, float* __restrict__ outf,
                         int M, int K, int Nout) {
    __shared__ short As[2][128][32];
    __shared__ short Bs[2][128][32];
    int tid  = threadIdx.x;
    int lane = tid & 63;
    int wave = tid >> 6;
    int bm = blockIdx.y * 128;
    int bn = blockIdx.x * 128;
    int wm = (wave & 1) * 64;
    int wn = (wave >> 1) * 32;
    int lrow  = lane & 15;
    int khalf = lane >> 4;

    f32x4 acc[4][2] = {};
    int row = tid >> 2;
    int inner = (tid & 3) * 16;
    int src = (inner - ((row >> 1) & 3) * 16) & 63;
    int selem = src >> 1;
    int arot = (((lrow >> 1) & 3) * 16);

    for (int k0 = 0; k0 < K; k0 += 64) {
        const bf16* Ag = A  + (size_t)(bm + row) * K + k0 + selem;
        const bf16* Bg = Bt + (size_t)(bn + row) * K + k0 + selem;
        glds16(Ag,      (short*)As[0] + (size_t)tid * 8);
        glds16(Ag + 32, (short*)As[1] + (size_t)tid * 8);
        glds16(Bg,      (short*)Bs[0] + (size_t)tid * 8);
        glds16(Bg + 32, (short*)Bs[1] + (size_t)tid * 8);
        __syncthreads();

        int roff = ((khalf * 16 + arot) & 63) >> 1;
        #pragma unroll
        for (int st = 0; st < 2; ++st) {
            bf16x8 af[4], bff[2];
            #pragma unroll
            for (int i = 0; i < 4; ++i)
                af[i] = *(const bf16x8*)&As[st][wm + i * 16 + lrow][roff];
            #pragma unroll
            for (int i = 0; i < 2; ++i)
                bff[i] = *(const bf16x8*)&Bs[st][wn + i * 16 + lrow][roff];
            #pragma unroll
            for (int mi = 0; mi < 4; ++mi)
                #pragma unroll
                for (int ni = 0; ni < 2; ++ni)
                    acc[mi][ni] = __builtin_amdgcn_mfma_f32_16x16x32_bf16(af[mi], bff[ni], acc[mi][ni], 0, 0, 0);
        }
        __syncthreads();
    }

    #pragma unroll
    for (int ni = 0; ni < 2; ++ni) {
        int col = bn + wn + ni * 16 + lrow;
        if (col >= Nout) continue;
        float bv = bias[col];
        #pragma unroll
        for (int mi = 0; mi < 4; ++mi) {
            int orow = bm + wm + mi * 16 + khalf * 4;
            #pragma unroll
            for (int r = 0; r < 4; ++r)
                outf[(size_t)(orow + r) * Nout + col] = acc[mi][ni][r] + bv;
        }
    }
}

// ---------------- per-token CE loss: one wave per token, shuffle-only
__global__ __launch_bounds__(256)
void loss_kernel(const float* __restrict__ logits,
                 const int* __restrict__ targets,
                 float* __restrict__ lossbuf) {
    int lane = threadIdx.x & 63;
    int token = blockIdx.x * 4 + (threadIdx.x >> 6);
    const float* lr = logits + (size_t)token * VOC;
    float v0 = lr[lane];
    float v64 = (lane == 0) ? lr[64] : -1e30f;
    float m = fmaxf(v0, v64);
    #pragma unroll
    for (int s = 32; s > 0; s >>= 1) m = fmaxf(m, __shfl_xor(m, s));
    int t = targets[token];
    float sum = __expf(v0 - m) + ((lane == 0) ? __expf(v64 - m) : 0.f);
    float tv  = (lane == t) ? v0 : ((lane == 0 && t == 64) ? v64 : 0.f);
    #pragma unroll
    for (int s = 32; s > 0; s >>= 1) { sum += __shfl_xor(sum, s); tv += __shfl_xor(tv, s); }
    if (lane == 0) lossbuf[token] = m + logf(sum) - tv;
}

__global__ void loss_reduce_kernel(const float* __restrict__ lossbuf, float* __restrict__ out_loss) {
    __shared__ float red[256];
    int tid = threadIdx.x;
    float s = 0.f;
    for (int i = tid; i < NTOK; i += 256) s += lossbuf[i];
    red[tid] = s; __syncthreads();
    for (int st = 128; st > 0; st >>= 1) { if (tid < st) red[tid] += red[tid + st]; __syncthreads(); }
    if (tid == 0) out_loss[0] = red[0] / (float)NTOK;
}

extern "C" void kernel_launch(void* const* d_in, const int* in_sizes, int n_in,
                              void* d_out, int out_size, void* d_ws, size_t ws_size,
                              hipStream_t stream) {
    const int*   idx     = (const int*)  d_in[0];
    const int*   targets = (const int*)  d_in[1];
    const float* tok_emb = (const float*)d_in[2];
    const float* pos_emb = (const float*)d_in[3];
    const float* Wq      = (const float*)d_in[4];
    const float* Wk      = (const float*)d_in[5];
    const float* Wv      = (const float*)d_in[6];
    const float* Wproj   = (const float*)d_in[7];
    const float* bproj   = (const float*)d_in[8];
    const float* W1      = (const float*)d_in[9];
    const float* b1      = (const float*)d_in[10];
    const float* W2      = (const float*)d_in[11];
    const float* b2      = (const float*)d_in[12];
    const float* Wlm     = (const float*)d_in[13];
    const float* blm     = (const float*)d_in[14];

    char* ws = (char*)d_ws;
    bf16*  WprojT = (bf16*) (ws + 0);                       // 24576 B
    float* qkvbuf = (float*)(ws + 25165824);                // 9437184 B
    bf16*  attnT  = (bf16*) (ws + 34603008);                // 2097152 B
    u8*    x2f8   = (u8*)   (ws + 37748736);                // 32768*384 fp8 = 12582912 B
    u8*    h1f8   = (u8*)   (ws + 62914560);                // 32768*1536 fp8 = 50331648 B
    bf16*  x3     = (bf16*) (ws + 163577856);               // 25165824 B
    float* lossbuf= (float*)(ws + 188743680);               // 131072 B
    u8*    W1f8   = (u8*)   (ws + 188874752);               // 589824 B
    u8*    W2f8   = (u8*)   (ws + 190054400);               // 589824 B
    bf16*  WqkvT  = (bf16*) (ws + 191234048);               // 98304 B
    bf16*  WlmT   = (bf16*) (ws + 191332352);               // 98304 B

    float* out_logits = (float*)d_out;                      // [32768*65] f32
    float* out_loss   = out_logits + (size_t)NTOK * VOC;    // [1]

    // all weight packing in one dispatch
    pack_all_kernel<<<640 + FFDIM + C_EMB, 256, 0, stream>>>(Wq, Wk, Wv, Wlm, Wproj, W1, W2,
                                                             WqkvT, WlmT, WprojT, W1f8, W2f8);

    // fused embed + QKV: -> qkvbuf f32 [32768,72]
    qkv_embed_mfma_kernel<<<NTOK / 128, 256, 0, stream>>>(idx, tok_emb, pos_emb, WqkvT, qkvbuf);
    attn_kernel<<<NB * NH, T_SEQ, 0, stream>>>(qkvbuf, attnT);

    // proj: [32768,32] @ [32,384] + bproj -> x2 fp8 (* X2_SCALE)
    gemm_mfma32_kernel<<<dim3(C_EMB / 128, NTOK / 128), 256, 0, stream>>>(attnT, WprojT, bproj,
                                                                          x2f8, X2_SCALE,
                                                                          NTOK, PROJK, C_EMB);
    // FF1: fp8 [32768,384] @ fp8 [384->1536] + b1, relu -> h1 fp8 (* H1_SCALE). NT=12.
    gemm_fp8_kernel<<<(NTOK / 128) * (FFDIM / 128), 512, 0, stream>>>(x2f8, W1f8, b1,
                                                                      nullptr, h1f8,
                                                                      FF1_DESCALE, H1_SCALE,
                                                                      NTOK, C_EMB, FFDIM, FFDIM / 128, 1);
    // FF2: fp8 [32768,1536] @ fp8 [1536->384] + b2 -> x3 bf16. NT=3.
    gemm_fp8_kernel<<<(NTOK / 128) * (C_EMB / 128), 512, 0, stream>>>(h1f8, W2f8, b2,
                                                                      x3, nullptr,
                                                                      FF2_DESCALE, 1.0f,
                                                                      NTOK, FFDIM, C_EMB, C_EMB / 128, 0);
    // LM head: [32768,384] @ [384,65pad128] + blm -> f32 logits into d_out
    gemm_mfma512_kernel<<<dim3(1, NTOK / 128), 512, 0, stream>>>(x3, WlmT, blm, out_logits,
                                                                 NTOK, C_EMB, VOC);

    loss_kernel<<<NTOK / 4, 256, 0, stream>>>(out_logits, targets, lossbuf);
    loss_reduce_kernel<<<1, 256, 0, stream>>>(lossbuf, out_loss);
}

// Round 10
// 274.897 us; speedup vs baseline: 8.1243x; 1.0055x over previous
//
#include <hip/hip_runtime.h>
#include <hip/hip_bf16.h>
#include <math.h>

typedef __hip_bfloat16 bf16;
typedef __attribute__((ext_vector_type(8))) short bf16x8;
typedef __attribute__((ext_vector_type(4))) float f32x4;
typedef __attribute__((ext_vector_type(8))) int i32x8;
typedef __attribute__((ext_vector_type(4))) int i32x4;
typedef unsigned char u8;

#define T_SEQ   256
#define C_EMB   384
#define NH      6
#define HS      4
#define NB      128
#define NTOK    (NB * T_SEQ)   // 32768
#define VOC     65
#define FFDIM   1536
#define QKVW    72             // 3*NH*HS packed width
#define PROJK   32             // 24 padded to 32

#define X2_SCALE    128.0f
#define W1_SCALE    128.0f
#define FF1_DESCALE (1.0f / (128.0f * 128.0f))
#define H1_SCALE    512.0f
#define W2_SCALE    128.0f
#define FF2_DESCALE (1.0f / (512.0f * 128.0f))

__device__ __forceinline__ float b2f(bf16 x) { return __bfloat162float(x); }
__device__ __forceinline__ bf16  f2b(float x) { return __float2bfloat16(x); }
__device__ __forceinline__ short f2s(float x) { bf16 b = __float2bfloat16(x); return *reinterpret_cast<short*>(&b); }
__device__ __forceinline__ u8 f2fp8(float x) {
    return (u8)(__builtin_amdgcn_cvt_pk_fp8_f32(x, x, 0, false) & 0xff);
}

// async 16B global->LDS. LDS dst = wave-uniform base + lane*16.
__device__ __forceinline__ void glds16(const void* g, void* l) {
    __builtin_amdgcn_global_load_lds((const __attribute__((address_space(1))) void*)g,
                                     (__attribute__((address_space(3))) void*)l, 16, 0, 0);
}

// ---------------- all weight packing in ONE dispatch
__global__ void pack_all_kernel(const float* __restrict__ Wq, const float* __restrict__ Wk,
                                const float* __restrict__ Wv, const float* __restrict__ Wlm,
                                const float* __restrict__ Wproj,
                                const float* __restrict__ W1, const float* __restrict__ W2,
                                bf16* __restrict__ WqkvT, bf16* __restrict__ WlmT,
                                bf16* __restrict__ WprojT, u8* __restrict__ W1f8,
                                u8* __restrict__ W2f8) {
    int blk = blockIdx.x;
    if (blk < 128) {                                   // WqkvT [128,384]
        int n = blk;
        for (int c = threadIdx.x; c < C_EMB; c += 256) {
            float v = 0.f;
            if (n < QKVW) {
                int sel = n / 24, r = n % 24, h = r >> 2, d = r & 3;
                const float* W = (sel == 0) ? Wq : (sel == 1) ? Wk : Wv;
                v = W[(h * C_EMB + c) * HS + d];
            }
            WqkvT[(size_t)n * C_EMB + c] = f2b(v);
        }
    } else if (blk < 256) {                            // WlmT [128,384]
        int n = blk - 128;
        for (int c = threadIdx.x; c < C_EMB; c += 256)
            WlmT[(size_t)n * C_EMB + c] = f2b(n < VOC ? Wlm[(size_t)c * VOC + n] : 0.f);
    } else if (blk < 640) {                            // WprojT [384,32]
        int n = blk - 256;
        int k = threadIdx.x;
        if (k < PROJK)
            WprojT[(size_t)n * PROJK + k] = f2b(k < 24 ? Wproj[(size_t)k * C_EMB + n] : 0.f);
    } else if (blk < 640 + FFDIM) {                    // W1f8 [1536,384] fp8 * W1_SCALE
        int n = blk - 640;
        for (int k = threadIdx.x; k < C_EMB; k += 256)
            W1f8[(size_t)n * C_EMB + k] = f2fp8(W1[(size_t)k * FFDIM + n] * W1_SCALE);
    } else {                                           // W2f8 [384,1536] fp8 * W2_SCALE
        int n = blk - 640 - FFDIM;
        for (int k = threadIdx.x; k < FFDIM; k += 256)
            W2f8[(size_t)n * FFDIM + k] = f2fp8(W2[(size_t)k * C_EMB + n] * W2_SCALE);
    }
}

// ---------------- fused embed + QKV GEMM: qkv[token,72] = (tok_emb[idx]+pos_emb) @ WqkvT^T
__global__ __launch_bounds__(256)
void qkv_embed_mfma_kernel(const int* __restrict__ idx,
                           const float* __restrict__ tok_emb,
                           const float* __restrict__ pos_emb,
                           const bf16* __restrict__ Bt,
                           float* __restrict__ outf) {
    __shared__ short As[128][32];
    __shared__ short Bs[128][32];
    __shared__ int ids[128];
    int tid = threadIdx.x, lane = tid & 63, wave = tid >> 6;
    int bm = blockIdx.x * 128;
    int wm = (wave & 1) * 64, wn = (wave >> 1) * 64;
    int lrow = lane & 15, khalf = lane >> 4;
    if (tid < 128) ids[tid] = idx[bm + tid];
    __syncthreads();
    int tbase = bm & (T_SEQ - 1);

    f32x4 acc[4][4] = {};
    for (int k0 = 0; k0 < C_EMB; k0 += 32) {
        #pragma unroll
        for (int h = 0; h < 2; ++h) {
            int c = tid + h * 256;
            int row = c >> 2, colc = k0 + (c & 3) * 8;
            const float* te = tok_emb + (size_t)ids[row] * C_EMB + colc;
            const float* pe = pos_emb + (size_t)(tbase + row) * C_EMB + colc;
            float4 t0 = *(const float4*)te, t1 = *(const float4*)(te + 4);
            float4 p0 = *(const float4*)pe, p1 = *(const float4*)(pe + 4);
            union { short s[8]; uint4 u; } r;
            r.s[0] = f2s(t0.x + p0.x); r.s[1] = f2s(t0.y + p0.y);
            r.s[2] = f2s(t0.z + p0.z); r.s[3] = f2s(t0.w + p0.w);
            r.s[4] = f2s(t1.x + p1.x); r.s[5] = f2s(t1.y + p1.y);
            r.s[6] = f2s(t1.z + p1.z); r.s[7] = f2s(t1.w + p1.w);
            *(uint4*)((short*)As + (size_t)c * 8) = r.u;
        }
        int c = tid;
        glds16(Bt + (size_t)(c >> 2) * C_EMB + k0 + (c & 3) * 8, (short*)Bs + (size_t)c * 8);
        c = tid + 256;
        glds16(Bt + (size_t)(c >> 2) * C_EMB + k0 + (c & 3) * 8, (short*)Bs + (size_t)c * 8);
        __syncthreads();

        bf16x8 af[4], bff[4];
        #pragma unroll
        for (int i = 0; i < 4; ++i) {
            af[i]  = *(const bf16x8*)&As[wm + i * 16 + lrow][khalf * 8];
            bff[i] = *(const bf16x8*)&Bs[wn + i * 16 + lrow][khalf * 8];
        }
        #pragma unroll
        for (int mi = 0; mi < 4; ++mi)
            #pragma unroll
            for (int ni = 0; ni < 4; ++ni)
                acc[mi][ni] = __builtin_amdgcn_mfma_f32_16x16x32_bf16(af[mi], bff[ni], acc[mi][ni], 0, 0, 0);
        __syncthreads();
    }

    #pragma unroll
    for (int ni = 0; ni < 4; ++ni) {
        int col = wn + ni * 16 + lrow;
        if (col >= QKVW) continue;
        #pragma unroll
        for (int mi = 0; mi < 4; ++mi) {
            int row = bm + wm + mi * 16 + khalf * 4;
            #pragma unroll
            for (int r = 0; r < 4; ++r)
                outf[(size_t)(row + r) * QKVW + col] = acc[mi][ni][r];
        }
    }
}

// ---------------- causal softmax attention (single-pass online); writes bf16 attnT[token][32]
__global__ void attn_kernel(const float* __restrict__ qkv,
                            bf16* __restrict__ attnT) {
    int bh = blockIdx.x;
    int b = bh / NH, h = bh % NH;
    int t = threadIdx.x;           // 256 threads
    __shared__ float ks[T_SEQ][HS];
    __shared__ float vs[T_SEQ][HS];
    const float* base = qkv + (size_t)(b * T_SEQ) * QKVW;
    #pragma unroll
    for (int d = 0; d < HS; ++d) {
        ks[t][d] = base[t * QKVW + 24 + h * HS + d];
        vs[t][d] = base[t * QKVW + 48 + h * HS + d];
    }
    __syncthreads();
    const float* qp = base + t * QKVW + h * HS;
    float q0 = qp[0], q1 = qp[1], q2 = qp[2], q3 = qp[3];
    const float scale = 0.05103103630798288f;   // 384^-0.5
    float m = -1e30f, sum = 0.f, o0 = 0.f, o1 = 0.f, o2 = 0.f, o3 = 0.f;
    for (int s = 0; s <= t; ++s) {
        float sc = (q0 * ks[s][0] + q1 * ks[s][1] + q2 * ks[s][2] + q3 * ks[s][3]) * scale;
        float mn = fmaxf(m, sc);
        float alpha = __expf(m - mn);
        float p = __expf(sc - mn);
        sum = sum * alpha + p;
        o0 = o0 * alpha + p * vs[s][0];
        o1 = o1 * alpha + p * vs[s][1];
        o2 = o2 * alpha + p * vs[s][2];
        o3 = o3 * alpha + p * vs[s][3];
        m = mn;
    }
    float inv = 1.f / sum;
    bf16* out = attnT + (size_t)(b * T_SEQ + t) * PROJK + h * HS;
    out[0] = f2b(o0 * inv); out[1] = f2b(o1 * inv); out[2] = f2b(o2 * inv); out[3] = f2b(o3 * inv);
    if (h == 0) {   // zero-pad cols 24..31 once per token
        bf16* pad = attnT + (size_t)(b * T_SEQ + t) * PROJK + 24;
        *(uint4*)pad = uint4{0, 0, 0, 0};
    }
}

// ---------------- proj: MFMA bf16, BK=32, 256 threads, bank-swizzled; fp8 output (* oscale)
__global__ __launch_bounds__(256)
void gemm_mfma32_kernel(const bf16* __restrict__ A, const bf16* __restrict__ Bt,
                        const float* __restrict__ bias,
                        u8* __restrict__ outf8, float oscale,
                        int M, int K, int Nout) {
    __shared__ short As[128][32];
    __shared__ short Bs[128][32];
    int tid  = threadIdx.x;
    int lane = tid & 63;
    int wave = tid >> 6;
    int bm = blockIdx.y * 128;
    int bn = blockIdx.x * 128;
    int wm = (wave & 1) * 64;
    int wn = (wave >> 1) * 64;
    int lrow  = lane & 15;
    int khalf = lane >> 4;
    int arot = ((lrow >> 1) & 3) * 16;            // read-side rotation (bytes)
    int roff = ((khalf * 16 + arot) & 63) >> 1;   // short offset

    f32x4 acc[4][4] = {};
    for (int k0 = 0; k0 < K; k0 += 32) {
        #pragma unroll
        for (int h = 0; h < 2; ++h) {
            int c = tid + h * 256;
            int row = c >> 2;
            int i0 = (c & 3) * 16;
            int selem = ((i0 - ((row >> 1) & 3) * 16) & 63) >> 1;
            glds16(A  + (size_t)(bm + row) * K + k0 + selem, (short*)As + (size_t)c * 8);
            glds16(Bt + (size_t)(bn + row) * K + k0 + selem, (short*)Bs + (size_t)c * 8);
        }
        __syncthreads();

        bf16x8 af[4], bff[4];
        #pragma unroll
        for (int i = 0; i < 4; ++i) {
            af[i]  = *(const bf16x8*)&As[wm + i * 16 + lrow][roff];
            bff[i] = *(const bf16x8*)&Bs[wn + i * 16 + lrow][roff];
        }
        #pragma unroll
        for (int mi = 0; mi < 4; ++mi)
            #pragma unroll
            for (int ni = 0; ni < 4; ++ni)
                acc[mi][ni] = __builtin_amdgcn_mfma_f32_16x16x32_bf16(af[mi], bff[ni], acc[mi][ni], 0, 0, 0);
        __syncthreads();
    }

    #pragma unroll
    for (int ni = 0; ni < 4; ++ni) {
        int col = bn + wn + ni * 16 + lrow;
        float bv = bias[col];
        #pragma unroll
        for (int mi = 0; mi < 4; ++mi) {
            int row = bm + wm + mi * 16 + khalf * 4;
            float w[4];
            #pragma unroll
            for (int r = 0; r < 4; ++r) w[r] = (acc[mi][ni][r] + bv) * oscale;
            int p01 = __builtin_amdgcn_cvt_pk_fp8_f32(w[0], w[1], 0, false);
            int p23 = __builtin_amdgcn_cvt_pk_fp8_f32(w[2], w[3], 0, false);
            outf8[(size_t)(row + 0) * Nout + col] = (u8)(p01 & 0xff);
            outf8[(size_t)(row + 1) * Nout + col] = (u8)((p01 >> 8) & 0xff);
            outf8[(size_t)(row + 2) * Nout + col] = (u8)(p23 & 0xff);
            outf8[(size_t)(row + 3) * Nout + col] = (u8)((p23 >> 8) & 0xff);
        }
    }
}

// ---------------- unified fp8 MX-scaled MFMA GEMM (16x16x128, unity scales), BK=128,
// 512 threads, bank-swizzled, XCD-aware block swizzle. K%128==0, M/128 % 8 == 0.
__global__ __launch_bounds__(512)
void gemm_fp8_kernel(const u8* __restrict__ A, const u8* __restrict__ Bt,
                     const float* __restrict__ bias,
                     bf16* __restrict__ outb, u8* __restrict__ outf8,
                     float descale, float oscale,
                     int M, int K, int Nout, int NT, int relu) {
    __shared__ u8 As[128][128];   // LDS pos p of row r holds global byte (p - (r&7)*16)&127
    __shared__ u8 Bs[128][128];
    int lin  = blockIdx.x;
    int xcd  = lin & 7;
    int loc  = lin >> 3;
    int nt   = loc % NT;
    int mloc = loc / NT;
    int MPX  = (M / 128) >> 3;
    int bm = (xcd * MPX + mloc) * 128;
    int bn = nt * 128;

    int tid  = threadIdx.x;
    int lane = tid & 63;
    int wave = tid >> 6;
    int wm = (wave & 1) * 64;
    int wn = (wave >> 1) * 32;
    int lrow  = lane & 15;
    int khalf = lane >> 4;

    f32x4 acc[4][2] = {};
    int r0 = tid >> 3;
    int i0 = (tid & 7) * 16;
    int s0 = (i0 - (r0 & 7) * 16) & 127;
    int arot = (lrow & 7) * 16;
    int off0 = (khalf * 32 + arot) & 127;     // lane's 32 contiguous k-bytes start here
    int off1 = (off0 + 16) & 127;

    for (int k0 = 0; k0 < K; k0 += 128) {
        const u8* Ag = A  + (size_t)(bm + r0) * K + k0 + s0;
        const u8* Bg = Bt + (size_t)(bn + r0) * K + k0 + s0;
        glds16(Ag,                  &As[0][0]  + (size_t)tid * 16);
        glds16(Ag + (size_t)64 * K, &As[64][0] + (size_t)tid * 16);
        glds16(Bg,                  &Bs[0][0]  + (size_t)tid * 16);
        glds16(Bg + (size_t)64 * K, &Bs[64][0] + (size_t)tid * 16);
        __syncthreads();

        i32x8 a[4], b[2];
        #pragma unroll
        for (int i = 0; i < 4; ++i) {
            const u8* rp = &As[wm + i * 16 + lrow][0];
            i32x4 lo = *(const i32x4*)(rp + off0);
            i32x4 hi = *(const i32x4*)(rp + off1);
            a[i][0]=lo[0]; a[i][1]=lo[1]; a[i][2]=lo[2]; a[i][3]=lo[3];
            a[i][4]=hi[0]; a[i][5]=hi[1]; a[i][6]=hi[2]; a[i][7]=hi[3];
        }
        #pragma unroll
        for (int i = 0; i < 2; ++i) {
            const u8* rp = &Bs[wn + i * 16 + lrow][0];
            i32x4 lo = *(const i32x4*)(rp + off0);
            i32x4 hi = *(const i32x4*)(rp + off1);
            b[i][0]=lo[0]; b[i][1]=lo[1]; b[i][2]=lo[2]; b[i][3]=lo[3];
            b[i][4]=hi[0]; b[i][5]=hi[1]; b[i][6]=hi[2]; b[i][7]=hi[3];
        }
        #pragma unroll
        for (int mi = 0; mi < 4; ++mi)
            #pragma unroll
            for (int ni = 0; ni < 2; ++ni)
                acc[mi][ni] = __builtin_amdgcn_mfma_scale_f32_16x16x128_f8f6f4(
                    a[mi], b[ni], acc[mi][ni], 0, 0,
                    0, 0x7f7f7f7f, 0, 0x7f7f7f7f);   // fp8/fp8, unity E8M0 scales
        __syncthreads();
    }

    #pragma unroll
    for (int ni = 0; ni < 2; ++ni) {
        int col = bn + wn + ni * 16 + lrow;
        float bv = bias[col];
        #pragma unroll
        for (int mi = 0; mi < 4; ++mi) {
            int orow = bm + wm + mi * 16 + khalf * 4;
            float w[4];
            #pragma unroll
            for (int r = 0; r < 4; ++r) {
                w[r] = acc[mi][ni][r] * descale + bv;
                if (relu) w[r] = fmaxf(w[r], 0.f);
            }
            if (outf8) {
                int p01 = __builtin_amdgcn_cvt_pk_fp8_f32(w[0] * oscale, w[1] * oscale, 0, false);
                int p23 = __builtin_amdgcn_cvt_pk_fp8_f32(w[2] * oscale, w[3] * oscale, 0, false);
                outf8[(size_t)(orow + 0) * Nout + col] = (u8)(p01 & 0xff);
                outf8[(size_t)(orow + 1) * Nout + col] = (u8)((p01 >> 8) & 0xff);
                outf8[(size_t)(orow + 2) * Nout + col] = (u8)(p23 & 0xff);
                outf8[(size_t)(orow + 3) * Nout + col] = (u8)((p23 >> 8) & 0xff);
            } else {
                #pragma unroll
                for (int r = 0; r < 4; ++r) outb[(size_t)(orow + r) * Nout + col] = f2b(w[r]);
            }
        }
    }
}

// ---------------- LM head: MFMA bf16, BK=64, 512 threads, bank-swizzled (f32 out)
__global__ __launch_bounds__(512)
void gemm_mfma512_kernel(const bf16* __restrict__ A, const bf16* __restrict__ Bt,
                         const float* __restrict__ bias, float* __restrict__ outf,
                         int M, int K, int Nout) {
    __shared__ short As[2][128][32];
    __shared__ short Bs[2][128][32];
    int tid  = threadIdx.x;
    int lane = tid & 63;
    int wave = tid >> 6;
    int bm = blockIdx.y * 128;
    int bn = blockIdx.x * 128;
    int wm = (wave & 1) * 64;
    int wn = (wave >> 1) * 32;
    int lrow  = lane & 15;
    int khalf = lane >> 4;

    f32x4 acc[4][2] = {};
    int row = tid >> 2;
    int inner = (tid & 3) * 16;
    int src = (inner - ((row >> 1) & 3) * 16) & 63;
    int selem = src >> 1;
    int arot = (((lrow >> 1) & 3) * 16);

    for (int k0 = 0; k0 < K; k0 += 64) {
        const bf16* Ag = A  + (size_t)(bm + row) * K + k0 + selem;
        const bf16* Bg = Bt + (size_t)(bn + row) * K + k0 + selem;
        glds16(Ag,      (short*)As[0] + (size_t)tid * 8);
        glds16(Ag + 32, (short*)As[1] + (size_t)tid * 8);
        glds16(Bg,      (short*)Bs[0] + (size_t)tid * 8);
        glds16(Bg + 32, (short*)Bs[1] + (size_t)tid * 8);
        __syncthreads();

        int roff = ((khalf * 16 + arot) & 63) >> 1;
        #pragma unroll
        for (int st = 0; st < 2; ++st) {
            bf16x8 af[4], bff[2];
            #pragma unroll
            for (int i = 0; i < 4; ++i)
                af[i] = *(const bf16x8*)&As[st][wm + i * 16 + lrow][roff];
            #pragma unroll
            for (int i = 0; i < 2; ++i)
                bff[i] = *(const bf16x8*)&Bs[st][wn + i * 16 + lrow][roff];
            #pragma unroll
            for (int mi = 0; mi < 4; ++mi)
                #pragma unroll
                for (int ni = 0; ni < 2; ++ni)
                    acc[mi][ni] = __builtin_amdgcn_mfma_f32_16x16x32_bf16(af[mi], bff[ni], acc[mi][ni], 0, 0, 0);
        }
        __syncthreads();
    }

    #pragma unroll
    for (int ni = 0; ni < 2; ++ni) {
        int col = bn + wn + ni * 16 + lrow;
        if (col >= Nout) continue;
        float bv = bias[col];
        #pragma unroll
        for (int mi = 0; mi < 4; ++mi) {
            int orow = bm + wm + mi * 16 + khalf * 4;
            #pragma unroll
            for (int r = 0; r < 4; ++r)
                outf[(size_t)(orow + r) * Nout + col] = acc[mi][ni][r] + bv;
        }
    }
}

// ---------------- per-token CE loss: one wave per token, shuffle-only
__global__ __launch_bounds__(256)
void loss_kernel(const float* __restrict__ logits,
                 const int* __restrict__ targets,
                 float* __restrict__ lossbuf) {
    int lane = threadIdx.x & 63;
    int token = blockIdx.x * 4 + (threadIdx.x >> 6);
    const float* lr = logits + (size_t)token * VOC;
    float v0 = lr[lane];
    float v64 = (lane == 0) ? lr[64] : -1e30f;
    float m = fmaxf(v0, v64);
    #pragma unroll
    for (int s = 32; s > 0; s >>= 1) m = fmaxf(m, __shfl_xor(m, s));
    int t = targets[token];
    float sum = __expf(v0 - m) + ((lane == 0) ? __expf(v64 - m) : 0.f);
    float tv  = (lane == t) ? v0 : ((lane == 0 && t == 64) ? v64 : 0.f);
    #pragma unroll
    for (int s = 32; s > 0; s >>= 1) { sum += __shfl_xor(sum, s); tv += __shfl_xor(tv, s); }
    if (lane == 0) lossbuf[token] = m + logf(sum) - tv;
}

__global__ void loss_reduce_kernel(const float* __restrict__ lossbuf, float* __restrict__ out_loss) {
    __shared__ float red[256];
    int tid = threadIdx.x;
    float s = 0.f;
    for (int i = tid; i < NTOK; i += 256) s += lossbuf[i];
    red[tid] = s; __syncthreads();
    for (int st = 128; st > 0; st >>= 1) { if (tid < st) red[tid] += red[tid + st]; __syncthreads(); }
    if (tid == 0) out_loss[0] = red[0] / (float)NTOK;
}

extern "C" void kernel_launch(void* const* d_in, const int* in_sizes, int n_in,
                              void* d_out, int out_size, void* d_ws, size_t ws_size,
                              hipStream_t stream) {
    const int*   idx     = (const int*)  d_in[0];
    const int*   targets = (const int*)  d_in[1];
    const float* tok_emb = (const float*)d_in[2];
    const float* pos_emb = (const float*)d_in[3];
    const float* Wq      = (const float*)d_in[4];
    const float* Wk      = (const float*)d_in[5];
    const float* Wv      = (const float*)d_in[6];
    const float* Wproj   = (const float*)d_in[7];
    const float* bproj   = (const float*)d_in[8];
    const float* W1      = (const float*)d_in[9];
    const float* b1      = (const float*)d_in[10];
    const float* W2      = (const float*)d_in[11];
    const float* b2      = (const float*)d_in[12];
    const float* Wlm     = (const float*)d_in[13];
    const float* blm     = (const float*)d_in[14];

    char* ws = (char*)d_ws;
    bf16*  WprojT = (bf16*) (ws + 0);                       // 24576 B
    float* qkvbuf = (float*)(ws + 25165824);                // 9437184 B
    bf16*  attnT  = (bf16*) (ws + 34603008);                // 2097152 B
    u8*    x2f8   = (u8*)   (ws + 37748736);                // 12582912 B
    u8*    h1f8   = (u8*)   (ws + 62914560);                // 50331648 B
    bf16*  x3     = (bf16*) (ws + 163577856);               // 25165824 B
    float* lossbuf= (float*)(ws + 188743680);               // 131072 B
    u8*    W1f8   = (u8*)   (ws + 188874752);               // 589824 B
    u8*    W2f8   = (u8*)   (ws + 190054400);               // 589824 B
    bf16*  WqkvT  = (bf16*) (ws + 191234048);               // 98304 B
    bf16*  WlmT   = (bf16*) (ws + 191332352);               // 98304 B

    float* out_logits = (float*)d_out;                      // [32768*65] f32
    float* out_loss   = out_logits + (size_t)NTOK * VOC;    // [1]

    // all weight packing in one dispatch
    pack_all_kernel<<<640 + FFDIM + C_EMB, 256, 0, stream>>>(Wq, Wk, Wv, Wlm, Wproj, W1, W2,
                                                             WqkvT, WlmT, WprojT, W1f8, W2f8);

    // fused embed + QKV: -> qkvbuf f32 [32768,72]
    qkv_embed_mfma_kernel<<<NTOK / 128, 256, 0, stream>>>(idx, tok_emb, pos_emb, WqkvT, qkvbuf);
    attn_kernel<<<NB * NH, T_SEQ, 0, stream>>>(qkvbuf, attnT);

    // proj: [32768,32] @ [32,384] + bproj -> x2 fp8 (* X2_SCALE)
    gemm_mfma32_kernel<<<dim3(C_EMB / 128, NTOK / 128), 256, 0, stream>>>(attnT, WprojT, bproj,
                                                                          x2f8, X2_SCALE,
                                                                          NTOK, PROJK, C_EMB);
    // FF1: fp8 [32768,384] @ fp8 [384->1536] + b1, relu -> h1 fp8 (* H1_SCALE). NT=12.
    gemm_fp8_kernel<<<(NTOK / 128) * (FFDIM / 128), 512, 0, stream>>>(x2f8, W1f8, b1,
                                                                      nullptr, h1f8,
                                                                      FF1_DESCALE, H1_SCALE,
                                                                      NTOK, C_EMB, FFDIM, FFDIM / 128, 1);
    // FF2: fp8 [32768,1536] @ fp8 [1536->384] + b2 -> x3 bf16. NT=3.
    gemm_fp8_kernel<<<(NTOK / 128) * (C_EMB / 128), 512, 0, stream>>>(h1f8, W2f8, b2,
                                                                      x3, nullptr,
                                                                      FF2_DESCALE, 1.0f,
                                                                      NTOK, FFDIM, C_EMB, C_EMB / 128, 0);
    // LM head: [32768,384] @ [384,65pad128] + blm -> f32 logits into d_out
    gemm_mfma512_kernel<<<dim3(1, NTOK / 128), 512, 0, stream>>>(x3, WlmT, blm, out_logits,
                                                                 NTOK, C_EMB, VOC);

    loss_kernel<<<NTOK / 4, 256, 0, stream>>>(out_logits, targets, lossbuf);
    loss_reduce_kernel<<<1, 256, 0, stream>>>(lossbuf, out_loss);
}

// Round 11
// 272.617 us; speedup vs baseline: 8.1923x; 1.0084x over previous
//
#include <hip/hip_runtime.h>
#include <hip/hip_bf16.h>
#include <math.h>

typedef __hip_bfloat16 bf16;
typedef __attribute__((ext_vector_type(8))) short bf16x8;
typedef __attribute__((ext_vector_type(4))) float f32x4;
typedef __attribute__((ext_vector_type(8))) int i32x8;
typedef __attribute__((ext_vector_type(4))) int i32x4;
typedef unsigned char u8;

#define T_SEQ   256
#define C_EMB   384
#define NH      6
#define HS      4
#define NB      128
#define NTOK    (NB * T_SEQ)   // 32768
#define VOC     65
#define FFDIM   1536
#define QKVW    72             // 3*NH*HS packed width
#define PROJK   32             // 24 padded to 32
#define XROWS   (VOC * T_SEQ)  // 16640 distinct (id,t) embedding rows

#define X2_SCALE    128.0f
#define W1_SCALE    128.0f
#define FF1_DESCALE (1.0f / (128.0f * 128.0f))
#define H1_SCALE    512.0f
#define W2_SCALE    128.0f
#define FF2_DESCALE (1.0f / (512.0f * 128.0f))

__device__ __forceinline__ float b2f(bf16 x) { return __bfloat162float(x); }
__device__ __forceinline__ bf16  f2b(float x) { return __float2bfloat16(x); }
__device__ __forceinline__ u8 f2fp8(float x) {
    return (u8)(__builtin_amdgcn_cvt_pk_fp8_f32(x, x, 0, false) & 0xff);
}

// async 16B global->LDS. LDS dst = wave-uniform base + lane*16; global addr is per-lane (gather ok).
__device__ __forceinline__ void glds16(const void* g, void* l) {
    __builtin_amdgcn_global_load_lds((const __attribute__((address_space(1))) void*)g,
                                     (__attribute__((address_space(3))) void*)l, 16, 0, 0);
}

// ---------------- all weight packing + embedding table in ONE dispatch
__global__ void pack_all_kernel(const float* __restrict__ Wq, const float* __restrict__ Wk,
                                const float* __restrict__ Wv, const float* __restrict__ Wlm,
                                const float* __restrict__ Wproj,
                                const float* __restrict__ W1, const float* __restrict__ W2,
                                const float* __restrict__ tok_emb, const float* __restrict__ pos_emb,
                                bf16* __restrict__ WqkvT, bf16* __restrict__ WlmT,
                                bf16* __restrict__ WprojT, u8* __restrict__ W1f8,
                                u8* __restrict__ W2f8, bf16* __restrict__ xtab) {
    int blk = blockIdx.x;
    if (blk < 128) {                                   // WqkvT [128,384]
        int n = blk;
        for (int c = threadIdx.x; c < C_EMB; c += 256) {
            float v = 0.f;
            if (n < QKVW) {
                int sel = n / 24, r = n % 24, h = r >> 2, d = r & 3;
                const float* W = (sel == 0) ? Wq : (sel == 1) ? Wk : Wv;
                v = W[(h * C_EMB + c) * HS + d];
            }
            WqkvT[(size_t)n * C_EMB + c] = f2b(v);
        }
    } else if (blk < 256) {                            // WlmT [128,384]
        int n = blk - 128;
        for (int c = threadIdx.x; c < C_EMB; c += 256)
            WlmT[(size_t)n * C_EMB + c] = f2b(n < VOC ? Wlm[(size_t)c * VOC + n] : 0.f);
    } else if (blk < 640) {                            // WprojT [384,32]
        int n = blk - 256;
        int k = threadIdx.x;
        if (k < PROJK)
            WprojT[(size_t)n * PROJK + k] = f2b(k < 24 ? Wproj[(size_t)k * C_EMB + n] : 0.f);
    } else if (blk < 640 + FFDIM) {                    // W1f8 [1536,384] fp8 * W1_SCALE
        int n = blk - 640;
        for (int k = threadIdx.x; k < C_EMB; k += 256)
            W1f8[(size_t)n * C_EMB + k] = f2fp8(W1[(size_t)k * FFDIM + n] * W1_SCALE);
    } else if (blk < 640 + FFDIM + C_EMB) {            // W2f8 [384,1536] fp8 * W2_SCALE
        int n = blk - 640 - FFDIM;
        for (int k = threadIdx.x; k < FFDIM; k += 256)
            W2f8[(size_t)n * FFDIM + k] = f2fp8(W2[(size_t)k * C_EMB + n] * W2_SCALE);
    } else {                                           // xtab [65*256, 384] bf16: tok_emb[id]+pos_emb[t]
        int base = (blk - (640 + FFDIM + C_EMB)) * 4;
        for (int r = 0; r < 4; ++r) {
            int row = base + r;
            int id = row >> 8, t = row & 255;
            const float* te = tok_emb + (size_t)id * C_EMB;
            const float* pe = pos_emb + (size_t)t * C_EMB;
            bf16* dst = xtab + (size_t)row * C_EMB;
            for (int c = threadIdx.x; c < C_EMB; c += 256)
                dst[c] = f2b(te[c] + pe[c]);
        }
    }
}

// ---------------- QKV as gather-GEMM: qkv[token,72] = xtab[idx[token]*256+t] @ WqkvT^T
// 256 threads, [128][32] swizzled tiles, all staging via global_load_lds (A rows gathered).
__global__ __launch_bounds__(256)
void qkv_gather_kernel(const int* __restrict__ idx, const bf16* __restrict__ xtab,
                       const bf16* __restrict__ Bt, float* __restrict__ outf) {
    __shared__ short As[128][32];
    __shared__ short Bs[128][32];
    __shared__ int rowid[128];
    int tid = threadIdx.x, lane = tid & 63, wave = tid >> 6;
    int bm = blockIdx.x * 128;
    int wm = (wave & 1) * 64, wn = (wave >> 1) * 64;
    int lrow = lane & 15, khalf = lane >> 4;
    if (tid < 128) { int token = bm + tid; rowid[tid] = idx[token] * T_SEQ + (token & (T_SEQ - 1)); }
    __syncthreads();

    int ra = tid >> 2;                       // A/B row for chunk c=tid
    int rb = 64 + ra;                        // chunk c=tid+256 ((rb>>1)&3 == (ra>>1)&3)
    int i0 = (tid & 3) * 16;
    int selem = ((i0 - ((ra >> 1) & 3) * 16) & 63) >> 1;
    long ga = (long)rowid[ra] * C_EMB;
    long gb = (long)rowid[rb] * C_EMB;
    int arot = ((lrow >> 1) & 3) * 16;
    int roff = ((khalf * 16 + arot) & 63) >> 1;

    f32x4 acc[4][4] = {};
    for (int k0 = 0; k0 < C_EMB; k0 += 32) {
        glds16(xtab + ga + k0 + selem,                   (short*)As + (size_t)tid * 8);
        glds16(xtab + gb + k0 + selem,                   (short*)As + (size_t)(tid + 256) * 8);
        glds16(Bt + (size_t)ra * C_EMB + k0 + selem,     (short*)Bs + (size_t)tid * 8);
        glds16(Bt + (size_t)rb * C_EMB + k0 + selem,     (short*)Bs + (size_t)(tid + 256) * 8);
        __syncthreads();

        bf16x8 af[4], bff[4];
        #pragma unroll
        for (int i = 0; i < 4; ++i) {
            af[i]  = *(const bf16x8*)&As[wm + i * 16 + lrow][roff];
            bff[i] = *(const bf16x8*)&Bs[wn + i * 16 + lrow][roff];
        }
        #pragma unroll
        for (int mi = 0; mi < 4; ++mi)
            #pragma unroll
            for (int ni = 0; ni < 4; ++ni)
                acc[mi][ni] = __builtin_amdgcn_mfma_f32_16x16x32_bf16(af[mi], bff[ni], acc[mi][ni], 0, 0, 0);
        __syncthreads();
    }

    #pragma unroll
    for (int ni = 0; ni < 4; ++ni) {
        int col = wn + ni * 16 + lrow;
        if (col >= QKVW) continue;
        #pragma unroll
        for (int mi = 0; mi < 4; ++mi) {
            int row = bm + wm + mi * 16 + khalf * 4;
            #pragma unroll
            for (int r = 0; r < 4; ++r)
                outf[(size_t)(row + r) * QKVW + col] = acc[mi][ni][r];
        }
    }
}

// ---------------- causal softmax attention (single-pass online); writes bf16 attnT[token][32]
__global__ void attn_kernel(const float* __restrict__ qkv,
                            bf16* __restrict__ attnT) {
    int bh = blockIdx.x;
    int b = bh / NH, h = bh % NH;
    int t = threadIdx.x;           // 256 threads
    __shared__ float ks[T_SEQ][HS];
    __shared__ float vs[T_SEQ][HS];
    const float* base = qkv + (size_t)(b * T_SEQ) * QKVW;
    #pragma unroll
    for (int d = 0; d < HS; ++d) {
        ks[t][d] = base[t * QKVW + 24 + h * HS + d];
        vs[t][d] = base[t * QKVW + 48 + h * HS + d];
    }
    __syncthreads();
    const float* qp = base + t * QKVW + h * HS;
    float q0 = qp[0], q1 = qp[1], q2 = qp[2], q3 = qp[3];
    const float scale = 0.05103103630798288f;   // 384^-0.5
    float m = -1e30f, sum = 0.f, o0 = 0.f, o1 = 0.f, o2 = 0.f, o3 = 0.f;
    for (int s = 0; s <= t; ++s) {
        float sc = (q0 * ks[s][0] + q1 * ks[s][1] + q2 * ks[s][2] + q3 * ks[s][3]) * scale;
        float mn = fmaxf(m, sc);
        float alpha = __expf(m - mn);
        float p = __expf(sc - mn);
        sum = sum * alpha + p;
        o0 = o0 * alpha + p * vs[s][0];
        o1 = o1 * alpha + p * vs[s][1];
        o2 = o2 * alpha + p * vs[s][2];
        o3 = o3 * alpha + p * vs[s][3];
        m = mn;
    }
    float inv = 1.f / sum;
    bf16* out = attnT + (size_t)(b * T_SEQ + t) * PROJK + h * HS;
    out[0] = f2b(o0 * inv); out[1] = f2b(o1 * inv); out[2] = f2b(o2 * inv); out[3] = f2b(o3 * inv);
    if (h == 0) {   // zero-pad cols 24..31 once per token
        bf16* pad = attnT + (size_t)(b * T_SEQ + t) * PROJK + 24;
        *(uint4*)pad = uint4{0, 0, 0, 0};
    }
}

// ---------------- proj: MFMA bf16, BK=32, 256 threads, bank-swizzled; fp8 output (* oscale)
__global__ __launch_bounds__(256)
void gemm_mfma32_kernel(const bf16* __restrict__ A, const bf16* __restrict__ Bt,
                        const float* __restrict__ bias,
                        u8* __restrict__ outf8, float oscale,
                        int M, int K, int Nout) {
    __shared__ short As[128][32];
    __shared__ short Bs[128][32];
    int tid  = threadIdx.x;
    int lane = tid & 63;
    int wave = tid >> 6;
    int bm = blockIdx.y * 128;
    int bn = blockIdx.x * 128;
    int wm = (wave & 1) * 64;
    int wn = (wave >> 1) * 64;
    int lrow  = lane & 15;
    int khalf = lane >> 4;
    int arot = ((lrow >> 1) & 3) * 16;
    int roff = ((khalf * 16 + arot) & 63) >> 1;

    f32x4 acc[4][4] = {};
    for (int k0 = 0; k0 < K; k0 += 32) {
        #pragma unroll
        for (int h = 0; h < 2; ++h) {
            int c = tid + h * 256;
            int row = c >> 2;
            int i0 = (c & 3) * 16;
            int selem = ((i0 - ((row >> 1) & 3) * 16) & 63) >> 1;
            glds16(A  + (size_t)(bm + row) * K + k0 + selem, (short*)As + (size_t)c * 8);
            glds16(Bt + (size_t)(bn + row) * K + k0 + selem, (short*)Bs + (size_t)c * 8);
        }
        __syncthreads();

        bf16x8 af[4], bff[4];
        #pragma unroll
        for (int i = 0; i < 4; ++i) {
            af[i]  = *(const bf16x8*)&As[wm + i * 16 + lrow][roff];
            bff[i] = *(const bf16x8*)&Bs[wn + i * 16 + lrow][roff];
        }
        #pragma unroll
        for (int mi = 0; mi < 4; ++mi)
            #pragma unroll
            for (int ni = 0; ni < 4; ++ni)
                acc[mi][ni] = __builtin_amdgcn_mfma_f32_16x16x32_bf16(af[mi], bff[ni], acc[mi][ni], 0, 0, 0);
        __syncthreads();
    }

    #pragma unroll
    for (int ni = 0; ni < 4; ++ni) {
        int col = bn + wn + ni * 16 + lrow;
        float bv = bias[col];
        #pragma unroll
        for (int mi = 0; mi < 4; ++mi) {
            int row = bm + wm + mi * 16 + khalf * 4;
            float w[4];
            #pragma unroll
            for (int r = 0; r < 4; ++r) w[r] = (acc[mi][ni][r] + bv) * oscale;
            int p01 = __builtin_amdgcn_cvt_pk_fp8_f32(w[0], w[1], 0, false);
            int p23 = __builtin_amdgcn_cvt_pk_fp8_f32(w[2], w[3], 0, false);
            outf8[(size_t)(row + 0) * Nout + col] = (u8)(p01 & 0xff);
            outf8[(size_t)(row + 1) * Nout + col] = (u8)((p01 >> 8) & 0xff);
            outf8[(size_t)(row + 2) * Nout + col] = (u8)(p23 & 0xff);
            outf8[(size_t)(row + 3) * Nout + col] = (u8)((p23 >> 8) & 0xff);
        }
    }
}

// ---------------- unified fp8 MX-scaled MFMA GEMM (16x16x128, unity scales), BK=128,
// 512 threads, bank-swizzled, XCD-aware block swizzle. K%128==0, M/128 % 8 == 0.
__global__ __launch_bounds__(512)
void gemm_fp8_kernel(const u8* __restrict__ A, const u8* __restrict__ Bt,
                     const float* __restrict__ bias,
                     bf16* __restrict__ outb, u8* __restrict__ outf8,
                     float descale, float oscale,
                     int M, int K, int Nout, int NT, int relu) {
    __shared__ u8 As[128][128];   // LDS pos p of row r holds global byte (p - (r&7)*16)&127
    __shared__ u8 Bs[128][128];
    int lin  = blockIdx.x;
    int xcd  = lin & 7;
    int loc  = lin >> 3;
    int nt   = loc % NT;
    int mloc = loc / NT;
    int MPX  = (M / 128) >> 3;
    int bm = (xcd * MPX + mloc) * 128;
    int bn = nt * 128;

    int tid  = threadIdx.x;
    int lane = tid & 63;
    int wave = tid >> 6;
    int wm = (wave & 1) * 64;
    int wn = (wave >> 1) * 32;
    int lrow  = lane & 15;
    int khalf = lane >> 4;

    f32x4 acc[4][2] = {};
    int r0 = tid >> 3;
    int i0 = (tid & 7) * 16;
    int s0 = (i0 - (r0 & 7) * 16) & 127;
    int arot = (lrow & 7) * 16;
    int off0 = (khalf * 32 + arot) & 127;
    int off1 = (off0 + 16) & 127;

    for (int k0 = 0; k0 < K; k0 += 128) {
        const u8* Ag = A  + (size_t)(bm + r0) * K + k0 + s0;
        const u8* Bg = Bt + (size_t)(bn + r0) * K + k0 + s0;
        glds16(Ag,                  &As[0][0]  + (size_t)tid * 16);
        glds16(Ag + (size_t)64 * K, &As[64][0] + (size_t)tid * 16);
        glds16(Bg,                  &Bs[0][0]  + (size_t)tid * 16);
        glds16(Bg + (size_t)64 * K, &Bs[64][0] + (size_t)tid * 16);
        __syncthreads();

        i32x8 a[4], b[2];
        #pragma unroll
        for (int i = 0; i < 4; ++i) {
            const u8* rp = &As[wm + i * 16 + lrow][0];
            i32x4 lo = *(const i32x4*)(rp + off0);
            i32x4 hi = *(const i32x4*)(rp + off1);
            a[i][0]=lo[0]; a[i][1]=lo[1]; a[i][2]=lo[2]; a[i][3]=lo[3];
            a[i][4]=hi[0]; a[i][5]=hi[1]; a[i][6]=hi[2]; a[i][7]=hi[3];
        }
        #pragma unroll
        for (int i = 0; i < 2; ++i) {
            const u8* rp = &Bs[wn + i * 16 + lrow][0];
            i32x4 lo = *(const i32x4*)(rp + off0);
            i32x4 hi = *(const i32x4*)(rp + off1);
            b[i][0]=lo[0]; b[i][1]=lo[1]; b[i][2]=lo[2]; b[i][3]=lo[3];
            b[i][4]=hi[0]; b[i][5]=hi[1]; b[i][6]=hi[2]; b[i][7]=hi[3];
        }
        #pragma unroll
        for (int mi = 0; mi < 4; ++mi)
            #pragma unroll
            for (int ni = 0; ni < 2; ++ni)
                acc[mi][ni] = __builtin_amdgcn_mfma_scale_f32_16x16x128_f8f6f4(
                    a[mi], b[ni], acc[mi][ni], 0, 0,
                    0, 0x7f7f7f7f, 0, 0x7f7f7f7f);   // fp8/fp8, unity E8M0 scales
        __syncthreads();
    }

    #pragma unroll
    for (int ni = 0; ni < 2; ++ni) {
        int col = bn + wn + ni * 16 + lrow;
        float bv = bias[col];
        #pragma unroll
        for (int mi = 0; mi < 4; ++mi) {
            int orow = bm + wm + mi * 16 + khalf * 4;
            float w[4];
            #pragma unroll
            for (int r = 0; r < 4; ++r) {
                w[r] = acc[mi][ni][r] * descale + bv;
                if (relu) w[r] = fmaxf(w[r], 0.f);
            }
            if (outf8) {
                int p01 = __builtin_amdgcn_cvt_pk_fp8_f32(w[0] * oscale, w[1] * oscale, 0, false);
                int p23 = __builtin_amdgcn_cvt_pk_fp8_f32(w[2] * oscale, w[3] * oscale, 0, false);
                outf8[(size_t)(orow + 0) * Nout + col] = (u8)(p01 & 0xff);
                outf8[(size_t)(orow + 1) * Nout + col] = (u8)((p01 >> 8) & 0xff);
                outf8[(size_t)(orow + 2) * Nout + col] = (u8)(p23 & 0xff);
                outf8[(size_t)(orow + 3) * Nout + col] = (u8)((p23 >> 8) & 0xff);
            } else {
                #pragma unroll
                for (int r = 0; r < 4; ++r) outb[(size_t)(orow + r) * Nout + col] = f2b(w[r]);
            }
        }
    }
}

// ---------------- LM head: MFMA bf16, BK=64, 512 threads, bank-swizzled (f32 out)
__global__ __launch_bounds__(512)
void gemm_mfma512_kernel(const bf16* __restrict__ A, const bf16* __restrict__ Bt,
                         const float* __restrict__ bias, float* __restrict__ outf,
                         int M, int K, int Nout) {
    __shared__ short As[2][128][32];
    __shared__ short Bs[2][128][32];
    int tid  = threadIdx.x;
    int lane = tid & 63;
    int wave = tid >> 6;
    int bm = blockIdx.y * 128;
    int bn = blockIdx.x * 128;
    int wm = (wave & 1) * 64;
    int wn = (wave >> 1) * 32;
    int lrow  = lane & 15;
    int khalf = lane >> 4;

    f32x4 acc[4][2] = {};
    int row = tid >> 2;
    int inner = (tid & 3) * 16;
    int src = (inner - ((row >> 1) & 3) * 16) & 63;
    int selem = src >> 1;
    int arot = (((lrow >> 1) & 3) * 16);

    for (int k0 = 0; k0 < K; k0 += 64) {
        const bf16* Ag = A  + (size_t)(bm + row) * K + k0 + selem;
        const bf16* Bg = Bt + (size_t)(bn + row) * K + k0 + selem;
        glds16(Ag,      (short*)As[0] + (size_t)tid * 8);
        glds16(Ag + 32, (short*)As[1] + (size_t)tid * 8);
        glds16(Bg,      (short*)Bs[0] + (size_t)tid * 8);
        glds16(Bg + 32, (short*)Bs[1] + (size_t)tid * 8);
        __syncthreads();

        int roff = ((khalf * 16 + arot) & 63) >> 1;
        #pragma unroll
        for (int st = 0; st < 2; ++st) {
            bf16x8 af[4], bff[2];
            #pragma unroll
            for (int i = 0; i < 4; ++i)
                af[i] = *(const bf16x8*)&As[st][wm + i * 16 + lrow][roff];
            #pragma unroll
            for (int i = 0; i < 2; ++i)
                bff[i] = *(const bf16x8*)&Bs[st][wn + i * 16 + lrow][roff];
            #pragma unroll
            for (int mi = 0; mi < 4; ++mi)
                #pragma unroll
                for (int ni = 0; ni < 2; ++ni)
                    acc[mi][ni] = __builtin_amdgcn_mfma_f32_16x16x32_bf16(af[mi], bff[ni], acc[mi][ni], 0, 0, 0);
        }
        __syncthreads();
    }

    #pragma unroll
    for (int ni = 0; ni < 2; ++ni) {
        int col = bn + wn + ni * 16 + lrow;
        if (col >= Nout) continue;
        float bv = bias[col];
        #pragma unroll
        for (int mi = 0; mi < 4; ++mi) {
            int orow = bm + wm + mi * 16 + khalf * 4;
            #pragma unroll
            for (int r = 0; r < 4; ++r)
                outf[(size_t)(orow + r) * Nout + col] = acc[mi][ni][r] + bv;
        }
    }
}

// ---------------- per-token CE loss: one wave per token, shuffle-only
__global__ __launch_bounds__(256)
void loss_kernel(const float* __restrict__ logits,
                 const int* __restrict__ targets,
                 float* __restrict__ lossbuf) {
    int lane = threadIdx.x & 63;
    int token = blockIdx.x * 4 + (threadIdx.x >> 6);
    const float* lr = logits + (size_t)token * VOC;
    float v0 = lr[lane];
    float v64 = (lane == 0) ? lr[64] : -1e30f;
    float m = fmaxf(v0, v64);
    #pragma unroll
    for (int s = 32; s > 0; s >>= 1) m = fmaxf(m, __shfl_xor(m, s));
    int t = targets[token];
    float sum = __expf(v0 - m) + ((lane == 0) ? __expf(v64 - m) : 0.f);
    float tv  = (lane == t) ? v0 : ((lane == 0 && t == 64) ? v64 : 0.f);
    #pragma unroll
    for (int s = 32; s > 0; s >>= 1) { sum += __shfl_xor(sum, s); tv += __shfl_xor(tv, s); }
    if (lane == 0) lossbuf[token] = m + logf(sum) - tv;
}

__global__ void loss_reduce_kernel(const float* __restrict__ lossbuf, float* __restrict__ out_loss) {
    __shared__ float red[256];
    int tid = threadIdx.x;
    float s = 0.f;
    for (int i = tid; i < NTOK; i += 256) s += lossbuf[i];
    red[tid] = s; __syncthreads();
    for (int st = 128; st > 0; st >>= 1) { if (tid < st) red[tid] += red[tid + st]; __syncthreads(); }
    if (tid == 0) out_loss[0] = red[0] / (float)NTOK;
}

extern "C" void kernel_launch(void* const* d_in, const int* in_sizes, int n_in,
                              void* d_out, int out_size, void* d_ws, size_t ws_size,
                              hipStream_t stream) {
    const int*   idx     = (const int*)  d_in[0];
    const int*   targets = (const int*)  d_in[1];
    const float* tok_emb = (const float*)d_in[2];
    const float* pos_emb = (const float*)d_in[3];
    const float* Wq      = (const float*)d_in[4];
    const float* Wk      = (const float*)d_in[5];
    const float* Wv      = (const float*)d_in[6];
    const float* Wproj   = (const float*)d_in[7];
    const float* bproj   = (const float*)d_in[8];
    const float* W1      = (const float*)d_in[9];
    const float* b1      = (const float*)d_in[10];
    const float* W2      = (const float*)d_in[11];
    const float* b2      = (const float*)d_in[12];
    const float* Wlm     = (const float*)d_in[13];
    const float* blm     = (const float*)d_in[14];

    char* ws = (char*)d_ws;
    bf16*  WprojT = (bf16*) (ws + 0);                       // 24576 B
    float* qkvbuf = (float*)(ws + 25165824);                // 9437184 B
    bf16*  attnT  = (bf16*) (ws + 34603008);                // 2097152 B
    bf16*  xtab   = (bf16*) (ws + 37748736);                // 16640*384 bf16 = 12779520 B
    u8*    h1f8   = (u8*)   (ws + 62914560);                // 50331648 B
    u8*    x2f8   = (u8*)   (ws + 113246208);               // 12582912 B
    bf16*  x3     = (bf16*) (ws + 163577856);               // 25165824 B
    float* lossbuf= (float*)(ws + 188743680);               // 131072 B
    u8*    W1f8   = (u8*)   (ws + 188874752);               // 589824 B
    u8*    W2f8   = (u8*)   (ws + 190054400);               // 589824 B
    bf16*  WqkvT  = (bf16*) (ws + 191234048);               // 98304 B
    bf16*  WlmT   = (bf16*) (ws + 191332352);               // 98304 B

    float* out_logits = (float*)d_out;                      // [32768*65] f32
    float* out_loss   = out_logits + (size_t)NTOK * VOC;    // [1]

    // weights + embedding table in one dispatch (2560 + 4160 blocks)
    pack_all_kernel<<<640 + FFDIM + C_EMB + XROWS / 4, 256, 0, stream>>>(
        Wq, Wk, Wv, Wlm, Wproj, W1, W2, tok_emb, pos_emb,
        WqkvT, WlmT, WprojT, W1f8, W2f8, xtab);

    // QKV gather-GEMM: -> qkvbuf f32 [32768,72]
    qkv_gather_kernel<<<NTOK / 128, 256, 0, stream>>>(idx, xtab, WqkvT, qkvbuf);
    attn_kernel<<<NB * NH, T_SEQ, 0, stream>>>(qkvbuf, attnT);

    // proj: [32768,32] @ [32,384] + bproj -> x2 fp8 (* X2_SCALE)
    gemm_mfma32_kernel<<<dim3(C_EMB / 128, NTOK / 128), 256, 0, stream>>>(attnT, WprojT, bproj,
                                                                          x2f8, X2_SCALE,
                                                                          NTOK, PROJK, C_EMB);
    // FF1: fp8 [32768,384] @ fp8 [384->1536] + b1, relu -> h1 fp8 (* H1_SCALE). NT=12.
    gemm_fp8_kernel<<<(NTOK / 128) * (FFDIM / 128), 512, 0, stream>>>(x2f8, W1f8, b1,
                                                                      nullptr, h1f8,
                                                                      FF1_DESCALE, H1_SCALE,
                                                                      NTOK, C_EMB, FFDIM, FFDIM / 128, 1);
    // FF2: fp8 [32768,1536] @ fp8 [1536->384] + b2 -> x3 bf16. NT=3.
    gemm_fp8_kernel<<<(NTOK / 128) * (C_EMB / 128), 512, 0, stream>>>(h1f8, W2f8, b2,
                                                                      x3, nullptr,
                                                                      FF2_DESCALE, 1.0f,
                                                                      NTOK, FFDIM, C_EMB, C_EMB / 128, 0);
    // LM head: [32768,384] @ [384,65pad128] + blm -> f32 logits into d_out
    gemm_mfma512_kernel<<<dim3(1, NTOK / 128), 512, 0, stream>>>(x3, WlmT, blm, out_logits,
                                                                 NTOK, C_EMB, VOC);

    loss_kernel<<<NTOK / 4, 256, 0, stream>>>(out_logits, targets, lossbuf);
    loss_reduce_kernel<<<1, 256, 0, stream>>>(lossbuf, out_loss);
}